// Round 1
// baseline (356.914 us; speedup 1.0000x reference)
//
#include <hip/hip_runtime.h>

typedef _Float16 f16;
typedef _Float16 f16x8 __attribute__((ext_vector_type(8)));
typedef _Float16 f16x4 __attribute__((ext_vector_type(4)));
typedef float   f32x4 __attribute__((ext_vector_type(4)));
typedef short   s16x8 __attribute__((ext_vector_type(8)));
typedef unsigned short u16x8 __attribute__((ext_vector_type(8)));
typedef unsigned short u16x4 __attribute__((ext_vector_type(4)));

#define LOG2E 1.44269504088896340736f

__device__ __forceinline__ unsigned short f2bf(float x){
  union { float f; unsigned u; } v; v.f = x;
  v.u += 0x7fffu + ((v.u >> 16) & 1u);
  return (unsigned short)(v.u >> 16);
}
__device__ __forceinline__ float bf2f(unsigned short h){
  union { unsigned u; float f; } v; v.u = ((unsigned)h) << 16; return v.f;
}

__device__ __forceinline__ f32x4 mfma_f16(f16x8 a, f16x8 b, f32x4 c){
  return __builtin_amdgcn_mfma_f32_16x16x32_f16(a, b, c, 0, 0, 0);
}
__device__ __forceinline__ f32x4 mfma_bf16(s16x8 a, s16x8 b, f32x4 c){
  return __builtin_amdgcn_mfma_f32_16x16x32_bf16(a, b, c, 0, 0, 0);
}

// ---------------------------------------------------------------------------
// k_prep_g: BT[n][e] = sum_x Wk[n][x]*Wq[e][x]  (= G^T, G = Wq*Wk^T), n<512.
// fp32 VALU, outputs bf16 hi/lo split. Tile 64x64 per block, grid (8,8).
// ---------------------------------------------------------------------------
__global__ __launch_bounds__(256) void k_prep_g(const float* __restrict__ Wq,
                                                const float* __restrict__ Wk,
                                                unsigned short* __restrict__ BhiT,
                                                unsigned short* __restrict__ BloT){
  __shared__ float ak[64][68]; // Wk rows (n)
  __shared__ float aq[64][68]; // Wq rows (e)
  const int n0 = blockIdx.y * 64, e0 = blockIdx.x * 64;
  const int u = threadIdx.x;
  const int ty = u >> 4, tx = u & 15;
  float acc[4][4] = {};
  for (int x0 = 0; x0 < 512; x0 += 64){
    __syncthreads();
#pragma unroll
    for (int k = 0; k < 4; ++k){
      int idx = u + k * 256; int r = idx >> 4, c4 = (idx & 15) * 4;
      *(float4*)&ak[r][c4] = *(const float4*)&Wk[(n0 + r) * 512 + x0 + c4];
      *(float4*)&aq[r][c4] = *(const float4*)&Wq[(e0 + r) * 512 + x0 + c4];
    }
    __syncthreads();
    for (int xx = 0; xx < 64; xx += 4){
      float4 wq[4], wk[4];
#pragma unroll
      for (int j = 0; j < 4; ++j) wq[j] = *(const float4*)&aq[tx * 4 + j][xx];
#pragma unroll
      for (int i = 0; i < 4; ++i) wk[i] = *(const float4*)&ak[ty * 4 + i][xx];
#pragma unroll
      for (int i = 0; i < 4; ++i)
#pragma unroll
        for (int j = 0; j < 4; ++j)
          acc[i][j] += wk[i].x * wq[j].x + wk[i].y * wq[j].y +
                       wk[i].z * wq[j].z + wk[i].w * wq[j].w;
    }
  }
#pragma unroll
  for (int i = 0; i < 4; ++i)
#pragma unroll
    for (int j = 0; j < 4; ++j){
      int n = n0 + ty * 4 + i, e = e0 + tx * 4 + j;
      float v = acc[i][j];
      unsigned short hi = f2bf(v);
      BhiT[n * 512 + e] = hi;
      BloT[n * 512 + e] = f2bf(v - bf2f(hi));
    }
}

// ---------------------------------------------------------------------------
// k_prep_wv: BT[512+h][e] = Wv[e][h]  (transpose + bf16 hi/lo split)
// ---------------------------------------------------------------------------
__global__ __launch_bounds__(256) void k_prep_wv(const float* __restrict__ Wv,
                                                 unsigned short* __restrict__ BhiT,
                                                 unsigned short* __restrict__ BloT){
  __shared__ float t[64][68];
  const int e0 = blockIdx.x * 64, h0 = blockIdx.y * 64;
  const int u = threadIdx.x;
#pragma unroll
  for (int k = 0; k < 4; ++k){
    int idx = u + k * 256; int r = idx >> 4, c4 = (idx & 15) * 4;
    *(float4*)&t[r][c4] = *(const float4*)&Wv[(e0 + r) * 512 + h0 + c4];
  }
  __syncthreads();
#pragma unroll
  for (int k = 0; k < 4; ++k){
    int idx = u + k * 256; int j = idx >> 4, i4 = (idx & 15) * 4;
#pragma unroll
    for (int c = 0; c < 4; ++c){
      float v = t[i4 + c][j];
      unsigned short hi = f2bf(v);
      BhiT[(512 + h0 + j) * 512 + e0 + i4 + c] = hi;
      BloT[(512 + h0 + j) * 512 + e0 + i4 + c] = f2bf(v - bf2f(hi));
    }
  }
}

// ---------------------------------------------------------------------------
// k_cast: tokens fp32 -> fp16 (T16), vectorized 8/thread. grid 4096x256 exact.
// ---------------------------------------------------------------------------
__global__ __launch_bounds__(256) void k_cast(const float* __restrict__ tok,
                                              f16* __restrict__ T16){
  int i = blockIdx.x * 256 + threadIdx.x;
  const float4* p = (const float4*)tok + (size_t)i * 2;
  float4 a = p[0], b = p[1];
  f16x8 h;
  h[0] = (f16)a.x; h[1] = (f16)a.y; h[2] = (f16)a.z; h[3] = (f16)a.w;
  h[4] = (f16)b.x; h[5] = (f16)b.y; h[6] = (f16)b.z; h[7] = (f16)b.w;
  *((f16x8*)T16 + i) = h;
}

// ---------------------------------------------------------------------------
// k_gemm: C[t][n] = sum_e tokens[t][e] * BT[n][e],  M=16384, N=1024, K=512.
// tokens split hi/lo bf16 on the fly; 3-term MFMA (hi*hi + hi*lo + lo*hi).
// n<512 -> QG[t][n] fp16 row-major;  n>=512 -> VT[b][h][s] fp16 (transposed).
// Tiles 128x128xBK64, 4 waves (wave-tile 64x64, acc 4x4). grid (128 tb, 8 nb):
// the 8 nb-blocks of one tb share an XCD (linear id % 8 == tb%8) -> tokens
// tile is fetched once per XCD.
// ---------------------------------------------------------------------------
__global__ __launch_bounds__(256) void k_gemm(const float* __restrict__ tok,
                                              const unsigned short* __restrict__ BhiT,
                                              const unsigned short* __restrict__ BloT,
                                              f16* __restrict__ QG,
                                              f16* __restrict__ VT){
  __shared__ unsigned short smem[4 * 128 * 64]; // ahi, alo, bhi, blo (16KB each)
  unsigned short* ahi = smem;
  unsigned short* alo = smem + 128 * 64;
  unsigned short* bhi = smem + 2 * 128 * 64;
  unsigned short* blo = smem + 3 * 128 * 64;
  const int tb = blockIdx.x, nb = blockIdx.y;
  const int u = threadIdx.x;
  const int w = u >> 6, l = u & 63, lr = l & 15, lq = l >> 4;
  const int wm = (w & 1) * 64, wn = (w >> 1) * 64;
  f32x4 acc[4][4] = {};
  for (int k0 = 0; k0 < 512; k0 += 64){
    __syncthreads();
    // stage A (tokens fp32 -> bf16 hi/lo), 128 rows x 16 float4
#pragma unroll
    for (int rep = 0; rep < 8; ++rep){
      int c = u + rep * 256;
      int row = c >> 4, q4 = c & 15;
      float4 v = *(const float4*)&tok[(tb * 128 + row) * 512 + k0 + q4 * 4];
      unsigned short h0 = f2bf(v.x), h1 = f2bf(v.y), h2 = f2bf(v.z), h3 = f2bf(v.w);
      u16x4 vh; vh[0] = h0; vh[1] = h1; vh[2] = h2; vh[3] = h3;
      u16x4 vl;
      vl[0] = f2bf(v.x - bf2f(h0)); vl[1] = f2bf(v.y - bf2f(h1));
      vl[2] = f2bf(v.z - bf2f(h2)); vl[3] = f2bf(v.w - bf2f(h3));
      int slot = (q4 >> 1) ^ (row & 7);
      int off = row * 128 + slot * 16 + (q4 & 1) * 8;
      *(u16x4*)((char*)ahi + off) = vh;
      *(u16x4*)((char*)alo + off) = vl;
    }
    // stage B (pre-split bf16), 128 rows x 8 slots of 16B
#pragma unroll
    for (int rep = 0; rep < 4; ++rep){
      int c = u + rep * 256;
      int row = c >> 3, q = c & 7;
      int gs = (nb * 128 + row) * 512 + k0 + q * 8;
      u16x8 vh = *(const u16x8*)&BhiT[gs];
      u16x8 vl = *(const u16x8*)&BloT[gs];
      int off = row * 128 + ((q ^ (row & 7)) * 16);
      *(u16x8*)((char*)bhi + off) = vh;
      *(u16x8*)((char*)blo + off) = vl;
    }
    __syncthreads();
#pragma unroll
    for (int es = 0; es < 2; ++es){
      s16x8 afh[4], afl[4], bfh[4], bfl[4];
#pragma unroll
      for (int mt = 0; mt < 4; ++mt){
        int row = wm + mt * 16 + lr;
        int off = row * 128 + (((es * 4 + lq) ^ (row & 7)) * 16);
        afh[mt] = *(const s16x8*)((const char*)ahi + off);
        afl[mt] = *(const s16x8*)((const char*)alo + off);
      }
#pragma unroll
      for (int nt = 0; nt < 4; ++nt){
        int row = wn + nt * 16 + lr;
        int off = row * 128 + (((es * 4 + lq) ^ (row & 7)) * 16);
        bfh[nt] = *(const s16x8*)((const char*)bhi + off);
        bfl[nt] = *(const s16x8*)((const char*)blo + off);
      }
#pragma unroll
      for (int mt = 0; mt < 4; ++mt)
#pragma unroll
        for (int nt = 0; nt < 4; ++nt){
          f32x4 c = acc[mt][nt];
          c = mfma_bf16(afl[mt], bfh[nt], c);
          c = mfma_bf16(afh[mt], bfl[nt], c);
          c = mfma_bf16(afh[mt], bfh[nt], c);
          acc[mt][nt] = c;
        }
    }
  }
  // epilogue
  if (nb < 4){
#pragma unroll
    for (int mt = 0; mt < 4; ++mt)
#pragma unroll
      for (int nt = 0; nt < 4; ++nt){
        int n = nb * 128 + wn + nt * 16 + lr;
        int r0 = tb * 128 + wm + mt * 16 + lq * 4;
#pragma unroll
        for (int j = 0; j < 4; ++j)
          QG[(r0 + j) * 512 + n] = (f16)acc[mt][nt][j];
      }
  } else {
#pragma unroll
    for (int mt = 0; mt < 4; ++mt)
#pragma unroll
      for (int nt = 0; nt < 4; ++nt){
        int h = (nb - 4) * 128 + wn + nt * 16 + lr;
        int r0 = tb * 128 + wm + mt * 16 + lq * 4; // global token row = b*2048+s
        int bq = r0 >> 11, s = r0 & 2047;
        f16x4 hv;
#pragma unroll
        for (int j = 0; j < 4; ++j) hv[j] = (f16)acc[mt][nt][j];
        *(f16x4*)&VT[(bq * 512 + h) * 2048 + s] = hv;
      }
  }
}

// ---------------------------------------------------------------------------
// k_pass1: column stats of S over t. block = (b, s-block 128, t-chunk 1024).
// S[s][t] tiles via fp16 MFMA (A = T16 s-rows, B = QG t-rows), per-lane
// online (m,d) in base-2 domain, xor-shuffle merge over the 16 col-lanes,
// LDS merge over the 4 t-quarter waves. grid 256 (b = id&7 -> XCD locality).
// ---------------------------------------------------------------------------
__global__ __launch_bounds__(512) void k_pass1(const f16* __restrict__ T16,
                                               const f16* __restrict__ QG,
                                               float* __restrict__ pm_m,
                                               float* __restrict__ pm_d){
  const int gid = blockIdx.x;
  const int b = gid & 7;
  const int sb = (gid >> 3) & 15;
  const int tc = gid >> 7;
  const int s0 = sb * 128;
  const int u = threadIdx.x;
  const int w = u >> 6, l = u & 63, lr = l & 15, lq = l >> 4;
  const int sw = (w & 1) * 64, tw = (w >> 1) * 32;
  __shared__ f16 At[128 * 64];
  __shared__ f16 Bt[128 * 64];
  __shared__ float red[4 * 128 * 2];
  float m_[4][4], d_[4][4];
#pragma unroll
  for (int i = 0; i < 4; ++i)
#pragma unroll
    for (int j = 0; j < 4; ++j){ m_[i][j] = -1e30f; d_[i][j] = 0.f; }

  for (int ti = 0; ti < 8; ++ti){
    const int t0 = tc * 1024 + ti * 128;
    f32x4 acc[4][2] = {};
    for (int e0 = 0; e0 < 512; e0 += 64){
      __syncthreads();
#pragma unroll
      for (int rep = 0; rep < 2; ++rep){
        int c = u + rep * 512; int row = c >> 3, q = c & 7;
        int off = row * 128 + ((q ^ (row & 7)) * 16);
        *(u16x8*)((char*)At + off) = *(const u16x8*)&T16[(b * 2048 + s0 + row) * 512 + e0 + q * 8];
        *(u16x8*)((char*)Bt + off) = *(const u16x8*)&QG[(b * 2048 + t0 + row) * 512 + e0 + q * 8];
      }
      __syncthreads();
#pragma unroll
      for (int es = 0; es < 2; ++es){
        f16x8 af[4], bf[2];
#pragma unroll
        for (int mt = 0; mt < 4; ++mt){
          int row = sw + mt * 16 + lr;
          int off = row * 128 + (((es * 4 + lq) ^ (row & 7)) * 16);
          af[mt] = *(const f16x8*)((const char*)At + off);
        }
#pragma unroll
        for (int nt = 0; nt < 2; ++nt){
          int row = tw + nt * 16 + lr;
          int off = row * 128 + (((es * 4 + lq) ^ (row & 7)) * 16);
          bf[nt] = *(const f16x8*)((const char*)Bt + off);
        }
#pragma unroll
        for (int mt = 0; mt < 4; ++mt)
#pragma unroll
          for (int nt = 0; nt < 2; ++nt)
            acc[mt][nt] = mfma_f16(af[mt], bf[nt], acc[mt][nt]);
      }
    }
    // online update: s = s0+sw+mt*16+lq*4+j  (per-lane, col t fixed per value)
#pragma unroll
    for (int mt = 0; mt < 4; ++mt)
#pragma unroll
      for (int nt = 0; nt < 2; ++nt)
#pragma unroll
        for (int j = 0; j < 4; ++j){
          float x = acc[mt][nt][j] * LOG2E;
          float m = m_[mt][j], d = d_[mt][j];
          if (x <= m){
            d += exp2f(x - m);
          } else {
            d = d * exp2f(m - x) + 1.f;
            m = x;
          }
          m_[mt][j] = m; d_[mt][j] = d;
        }
  }
  // merge across the 16 col-lanes (xor 1,2,4,8 within lq group)
#pragma unroll
  for (int mt = 0; mt < 4; ++mt)
#pragma unroll
    for (int j = 0; j < 4; ++j){
      float m = m_[mt][j], d = d_[mt][j];
#pragma unroll
      for (int off = 1; off <= 8; off <<= 1){
        float om = __shfl_xor(m, off, 64);
        float od = __shfl_xor(d, off, 64);
        float nm = fmaxf(m, om);
        d = d * exp2f(m - nm) + od * exp2f(om - nm);
        m = nm;
      }
      m_[mt][j] = m; d_[mt][j] = d;
    }
  __syncthreads();
  if (lr == 0){
#pragma unroll
    for (int mt = 0; mt < 4; ++mt)
#pragma unroll
      for (int j = 0; j < 4; ++j){
        int sl = sw + mt * 16 + lq * 4 + j;
        red[((w >> 1) * 128 + sl) * 2 + 0] = m_[mt][j];
        red[((w >> 1) * 128 + sl) * 2 + 1] = d_[mt][j];
      }
  }
  __syncthreads();
  if (u < 128){
    float m = red[u * 2], d = red[u * 2 + 1];
#pragma unroll
    for (int g = 1; g < 4; ++g){
      float om = red[(g * 128 + u) * 2], od = red[(g * 128 + u) * 2 + 1];
      float nm = fmaxf(m, om);
      d = d * exp2f(m - nm) + od * exp2f(om - nm);
      m = nm;
    }
    int sg = b * 2048 + s0 + u;
    pm_m[tc * 16384 + sg] = m;
    pm_d[tc * 16384 + sg] = d;
  }
}

// ---------------------------------------------------------------------------
// k_merge: combine the 2 t-chunk partials -> m2[s], rr[s]=1/denom
// ---------------------------------------------------------------------------
__global__ __launch_bounds__(256) void k_merge(const float* __restrict__ pm_m,
                                               const float* __restrict__ pm_d,
                                               float* __restrict__ m2,
                                               float* __restrict__ rr){
  int i = blockIdx.x * 256 + threadIdx.x;
  float m0 = pm_m[i], d0 = pm_d[i];
  float m1 = pm_m[16384 + i], d1 = pm_d[16384 + i];
  float nm = fmaxf(m0, m1);
  float d = d0 * exp2f(m0 - nm) + d1 * exp2f(m1 - nm);
  m2[i] = nm;
  rr[i] = 1.0f / d;
}

// ---------------------------------------------------------------------------
// k_pass2: ctx^T[h][t] = sum_s V^T[h][s] * P[t][s],
// P[t][s] = exp2(S[t][s]*log2e - m2[s]) * rr[s].
// block = (b, t-tile 128, h-half 256). Per s-iter(128): recompute S-tile
// (identical MFMA chain as pass1 -> x-m2<=0 exactly), exp -> Pl LDS,
// then PV MFMA out of LDS (A = VT rows h, B = Pl rows t).
// grid 256 (b = id&7 -> XCD locality). LDS = 32+32+64 = 128KB.
// ---------------------------------------------------------------------------
__global__ __launch_bounds__(512) void k_pass2(const f16* __restrict__ T16,
                                               const f16* __restrict__ QG,
                                               const f16* __restrict__ VT,
                                               const float* __restrict__ m2,
                                               const float* __restrict__ rr,
                                               float* __restrict__ out){
  const int gid = blockIdx.x;
  const int b = gid & 7;
  const int tb = (gid >> 3) & 15;
  const int hh = gid >> 7;
  const int t0 = tb * 128;
  const int u = threadIdx.x;
  const int w = u >> 6, l = u & 63, lr = l & 15, lq = l >> 4;
  const int sw = (w & 1) * 64, tw = (w >> 1) * 32; // S roles
  const int wh = (w >> 1) * 64, wt = (w & 1) * 64; // PV roles
  __shared__ f16 At[128 * 64];   // T16 [128 s][64 e]
  __shared__ f16 Bt[128 * 64];   // QG  [128 t][64 e]
  __shared__ f16 Pl[128 * 128];  // P   [128 t][128 s], rows 256B, swizzled
  __shared__ f16 Vt[256 * 128];  // V^T [256 h][128 s], rows 256B, swizzled
  f32x4 acc[4][4] = {};
  for (int si = 0; si < 16; ++si){
    const int s0 = si * 128;
    f32x4 sacc[4][2] = {};
    for (int e0 = 0; e0 < 512; e0 += 64){
      __syncthreads();
#pragma unroll
      for (int rep = 0; rep < 2; ++rep){
        int c = u + rep * 512; int row = c >> 3, q = c & 7;
        int off = row * 128 + ((q ^ (row & 7)) * 16);
        *(u16x8*)((char*)At + off) = *(const u16x8*)&T16[(b * 2048 + s0 + row) * 512 + e0 + q * 8];
        *(u16x8*)((char*)Bt + off) = *(const u16x8*)&QG[(b * 2048 + t0 + row) * 512 + e0 + q * 8];
      }
      __syncthreads();
#pragma unroll
      for (int es = 0; es < 2; ++es){
        f16x8 af[4], bf[2];
#pragma unroll
        for (int mt = 0; mt < 4; ++mt){
          int row = sw + mt * 16 + lr;
          int off = row * 128 + (((es * 4 + lq) ^ (row & 7)) * 16);
          af[mt] = *(const f16x8*)((const char*)At + off);
        }
#pragma unroll
        for (int nt = 0; nt < 2; ++nt){
          int row = tw + nt * 16 + lr;
          int off = row * 128 + (((es * 4 + lq) ^ (row & 7)) * 16);
          bf[nt] = *(const f16x8*)((const char*)Bt + off);
        }
#pragma unroll
        for (int mt = 0; mt < 4; ++mt)
#pragma unroll
          for (int nt = 0; nt < 2; ++nt)
            sacc[mt][nt] = mfma_f16(af[mt], bf[nt], sacc[mt][nt]);
      }
    }
    __syncthreads(); // prior PV reads of Pl/Vt are done
    // exp -> Pl. C-frag: row s = sw+mt*16+lq*4+j, col t = tw+nt*16+lr
#pragma unroll
    for (int mt = 0; mt < 4; ++mt)
#pragma unroll
      for (int nt = 0; nt < 2; ++nt){
        int tl = tw + nt * 16 + lr;
        int sl = sw + mt * 16 + lq * 4;
        f16x4 pv;
#pragma unroll
        for (int j = 0; j < 4; ++j){
          int sg = b * 2048 + s0 + sl + j;
          float x = sacc[mt][nt][j] * LOG2E - m2[sg];
          pv[j] = (f16)(exp2f(x) * rr[sg]);
        }
        int sbyte = sl * 2;
        int off = tl * 256 + (((sbyte >> 4) ^ (tl & 7)) << 4) + (sbyte & 15);
        *(f16x4*)((char*)Pl + off) = pv;
      }
    // stage Vt: [256 h][128 s]
#pragma unroll
    for (int rep = 0; rep < 8; ++rep){
      int c = u + rep * 512; int row = c >> 4, q = c & 15;
      int off = row * 256 + ((q ^ (row & 7)) * 16);
      *(u16x8*)((char*)Vt + off) = *(const u16x8*)&VT[(b * 512 + hh * 256 + row) * 2048 + s0 + q * 8];
    }
    __syncthreads();
    // PV: 4 k-steps of 32 s
#pragma unroll
    for (int ks = 0; ks < 4; ++ks){
      f16x8 vf[4], pf[4];
#pragma unroll
      for (int ht = 0; ht < 4; ++ht){
        int row = wh + ht * 16 + lr;
        int off = row * 256 + (((ks * 4 + lq) ^ (row & 7)) * 16);
        vf[ht] = *(const f16x8*)((const char*)Vt + off);
      }
#pragma unroll
      for (int nt = 0; nt < 4; ++nt){
        int row = wt + nt * 16 + lr;
        int off = row * 256 + (((ks * 4 + lq) ^ (row & 7)) * 16);
        pf[nt] = *(const f16x8*)((const char*)Pl + off);
      }
#pragma unroll
      for (int ht = 0; ht < 4; ++ht)
#pragma unroll
        for (int nt = 0; nt < 4; ++nt)
          acc[ht][nt] = mfma_f16(vf[ht], pf[nt], acc[ht][nt]);
    }
  }
  // epilogue: C = ctx^T: row h = hh*256+wh+ht*16+lq*4+j, col t = t0+wt+nt*16+lr
#pragma unroll
  for (int ht = 0; ht < 4; ++ht)
#pragma unroll
    for (int nt = 0; nt < 4; ++nt){
      int t = t0 + wt + nt * 16 + lr;
      int h0 = hh * 256 + wh + ht * 16 + lq * 4;
      float4 v;
      v.x = acc[ht][nt][0]; v.y = acc[ht][nt][1];
      v.z = acc[ht][nt][2]; v.w = acc[ht][nt][3];
      *(float4*)&out[(b * 2048 + t) * 512 + h0] = v;
    }
}

// ---------------------------------------------------------------------------
extern "C" void kernel_launch(void* const* d_in, const int* in_sizes, int n_in,
                              void* d_out, int out_size, void* d_ws, size_t ws_size,
                              hipStream_t stream){
  (void)in_sizes; (void)n_in; (void)out_size; (void)ws_size;
  const float* tokens = (const float*)d_in[0];
  const float* Wq = (const float*)d_in[1];
  const float* Wk = (const float*)d_in[2];
  const float* Wv = (const float*)d_in[3];
  char* ws = (char*)d_ws;
  f16* T16 = (f16*)(ws);                                   // 16 MiB
  f16* QG  = (f16*)(ws + 16777216);                        // 16 MiB
  f16* VT  = (f16*)(ws + 33554432);                        // 16 MiB
  unsigned short* BhiT = (unsigned short*)(ws + 50331648); // 1 MiB
  unsigned short* BloT = (unsigned short*)(ws + 51380224); // 1 MiB
  float* pm_m = (float*)(ws + 52428800);                   // 128 KiB
  float* pm_d = (float*)(ws + 52559872);                   // 128 KiB
  float* m2   = (float*)(ws + 52690944);                   // 64 KiB
  float* rr   = (float*)(ws + 52756480);                   // 64 KiB
  float* out = (float*)d_out;

  k_prep_g <<<dim3(8, 8),   dim3(256), 0, stream>>>(Wq, Wk, BhiT, BloT);
  k_prep_wv<<<dim3(8, 8),   dim3(256), 0, stream>>>(Wv, BhiT, BloT);
  k_cast   <<<dim3(4096),   dim3(256), 0, stream>>>(tokens, T16);
  k_gemm   <<<dim3(128, 8), dim3(256), 0, stream>>>(tokens, BhiT, BloT, QG, VT);
  k_pass1  <<<dim3(256),    dim3(512), 0, stream>>>(T16, QG, pm_m, pm_d);
  k_merge  <<<dim3(64),     dim3(256), 0, stream>>>(pm_m, pm_d, m2, rr);
  k_pass2  <<<dim3(256),    dim3(512), 0, stream>>>(T16, QG, VT, m2, rr, out);
}

// Round 3
// 267.860 us; speedup vs baseline: 1.3325x; 1.3325x over previous
//
#include <hip/hip_runtime.h>

typedef _Float16 f16;
typedef _Float16 f16x8 __attribute__((ext_vector_type(8)));
typedef _Float16 f16x4 __attribute__((ext_vector_type(4)));
typedef float   f32x4 __attribute__((ext_vector_type(4)));

#define LOG2E 1.44269504088896340736f

__device__ __forceinline__ f32x4 mfma_f16(f16x8 a, f16x8 b, f32x4 c){
  return __builtin_amdgcn_mfma_f32_16x16x32_f16(a, b, c, 0, 0, 0);
}

// global -> LDS direct DMA, 16B per lane. lds must be wave-uniform base;
// HW writes base + lane*16. Source address is per-lane (pre-swizzled).
__device__ __forceinline__ void gld16(void* lds, const void* g){
  __builtin_amdgcn_global_load_lds(
      (const __attribute__((address_space(1))) unsigned int*)g,
      (__attribute__((address_space(3))) unsigned int*)lds,
      16, 0, 0);
}

// ---------------------------------------------------------------------------
// k_prep_g: B16[n][e] = sum_x Wk[n][x]*Wq[e][x]  (= (Wq Wk^T)^T), n<512.
// ---------------------------------------------------------------------------
__global__ __launch_bounds__(256) void k_prep_g(const float* __restrict__ Wq,
                                                const float* __restrict__ Wk,
                                                f16* __restrict__ B16){
  __shared__ float ak[32][36];
  __shared__ float aq[32][36];
  const int n0 = blockIdx.y * 32, e0 = blockIdx.x * 32;
  const int u = threadIdx.x;
  const int ty = u >> 4, tx = u & 15;
  float acc[2][2] = {};
  for (int x0 = 0; x0 < 512; x0 += 32){
    __syncthreads();
    {
      int r = u >> 3, c4 = (u & 7) * 4;
      *(float4*)&ak[r][c4] = *(const float4*)&Wk[(n0 + r) * 512 + x0 + c4];
      *(float4*)&aq[r][c4] = *(const float4*)&Wq[(e0 + r) * 512 + x0 + c4];
    }
    __syncthreads();
#pragma unroll 8
    for (int x = 0; x < 32; ++x){
      float k0 = ak[ty * 2 + 0][x], k1 = ak[ty * 2 + 1][x];
      float q0 = aq[tx * 2 + 0][x], q1 = aq[tx * 2 + 1][x];
      acc[0][0] += k0 * q0; acc[0][1] += k0 * q1;
      acc[1][0] += k1 * q0; acc[1][1] += k1 * q1;
    }
  }
#pragma unroll
  for (int i = 0; i < 2; ++i)
#pragma unroll
    for (int j = 0; j < 2; ++j)
      B16[(size_t)(n0 + ty * 2 + i) * 512 + e0 + tx * 2 + j] = (f16)acc[i][j];
}

// ---------------------------------------------------------------------------
// k_prep_wv: B16[512+d][e] = Wv[e][d]  (transpose + fp16 cast)
// ---------------------------------------------------------------------------
__global__ __launch_bounds__(256) void k_prep_wv(const float* __restrict__ Wv,
                                                 f16* __restrict__ B16){
  __shared__ float t[64][72];
  const int e0 = blockIdx.x * 64, h0 = blockIdx.y * 64;
  const int u = threadIdx.x;
#pragma unroll
  for (int k = 0; k < 4; ++k){
    int idx = u + k * 256; int r = idx >> 4, c4 = (idx & 15) * 4;
    *(float4*)&t[r][c4] = *(const float4*)&Wv[(e0 + r) * 512 + h0 + c4];
  }
  __syncthreads();
#pragma unroll
  for (int k = 0; k < 4; ++k){
    int idx = u + k * 256; int j = idx >> 4, i4 = (idx & 15) * 4;
#pragma unroll
    for (int c = 0; c < 4; ++c)
      B16[(size_t)(512 + h0 + j) * 512 + e0 + i4 + c] = (f16)t[i4 + c][j];
  }
}

// ---------------------------------------------------------------------------
// k_cast: tokens fp32 -> fp16, 8/thread.
// ---------------------------------------------------------------------------
__global__ __launch_bounds__(256) void k_cast(const float* __restrict__ tok,
                                              f16* __restrict__ T16){
  int i = blockIdx.x * 256 + threadIdx.x;
  const float4* p = (const float4*)tok + (size_t)i * 2;
  float4 a = p[0], b = p[1];
  f16x8 h;
  h[0] = (f16)a.x; h[1] = (f16)a.y; h[2] = (f16)a.z; h[3] = (f16)a.w;
  h[4] = (f16)b.x; h[5] = (f16)b.y; h[6] = (f16)b.z; h[7] = (f16)b.w;
  *((f16x8*)T16 + i) = h;
}

// ---------------------------------------------------------------------------
// k_gemm: C[t][n] = sum_e T16[t][e]*B16[n][e]; n<512 -> QG[t][n],
// n>=512 -> VT[b][d][s]. 128x128 tile, BK=64, dbuf, global_load_lds.
// ---------------------------------------------------------------------------
__global__ __launch_bounds__(256, 2) void k_gemm(const f16* __restrict__ T16,
                                                 const f16* __restrict__ B16,
                                                 f16* __restrict__ QG,
                                                 f16* __restrict__ VT){
  __shared__ __align__(16) f16 Abuf[2][128 * 64];
  __shared__ __align__(16) f16 Bbuf[2][128 * 64];
  const int tb = blockIdx.x, nb = blockIdx.y;
  const int u = threadIdx.x;
  const int w = u >> 6, l = u & 63, lr = l & 15, lq = l >> 4;
  const int lo8 = l & 7, hi8 = l >> 3;
  const int wm = (w & 1) * 64, wn = (w >> 1) * 64;
  f32x4 acc[4][4] = {};
  auto stage = [&](int c, int buf){
    const f16* sa = T16 + (size_t)tb * 128 * 512 + c * 64;
    const f16* sb = B16 + (size_t)nb * 128 * 512 + c * 64;
#pragma unroll
    for (int k = 0; k < 4; ++k){
      int i = w * 4 + k;
      int row = i * 8 + hi8;
      gld16((char*)&Abuf[buf][0] + i * 1024, sa + (size_t)row * 512 + ((lo8 ^ (row & 7)) * 8));
      gld16((char*)&Bbuf[buf][0] + i * 1024, sb + (size_t)row * 512 + ((lo8 ^ (row & 7)) * 8));
    }
  };
  stage(0, 0);
  for (int c = 0; c < 8; ++c){
    __syncthreads();
    if (c < 7) stage(c + 1, (c + 1) & 1);
    const f16* A = &Abuf[c & 1][0];
    const f16* B = &Bbuf[c & 1][0];
#pragma unroll
    for (int es = 0; es < 2; ++es){
      f16x8 af[4], bf[4];
#pragma unroll
      for (int mt = 0; mt < 4; ++mt){
        int row = wm + mt * 16 + lr;
        af[mt] = *(const f16x8*)((const char*)A + row * 128 + (((es * 4 + lq) ^ (row & 7)) << 4));
      }
#pragma unroll
      for (int nt = 0; nt < 4; ++nt){
        int row = wn + nt * 16 + lr;
        bf[nt] = *(const f16x8*)((const char*)B + row * 128 + (((es * 4 + lq) ^ (row & 7)) << 4));
      }
#pragma unroll
      for (int mt = 0; mt < 4; ++mt)
#pragma unroll
        for (int nt = 0; nt < 4; ++nt)
          acc[mt][nt] = mfma_f16(af[mt], bf[nt], acc[mt][nt]);
    }
  }
  if (nb < 4){
#pragma unroll
    for (int mt = 0; mt < 4; ++mt)
#pragma unroll
      for (int nt = 0; nt < 4; ++nt){
        int n = nb * 128 + wn + nt * 16 + lr;
        int r0 = tb * 128 + wm + mt * 16 + lq * 4;
#pragma unroll
        for (int j = 0; j < 4; ++j)
          QG[(size_t)(r0 + j) * 512 + n] = (f16)acc[mt][nt][j];
      }
  } else {
#pragma unroll
    for (int mt = 0; mt < 4; ++mt)
#pragma unroll
      for (int nt = 0; nt < 4; ++nt){
        int h = (nb - 4) * 128 + wn + nt * 16 + lr;
        int r0 = tb * 128 + wm + mt * 16 + lq * 4;
        int bq = r0 >> 11, s = r0 & 2047;
        f16x4 hv;
#pragma unroll
        for (int j = 0; j < 4; ++j) hv[j] = (f16)acc[mt][nt][j];
        *(f16x4*)&VT[(size_t)(bq * 512 + h) * 2048 + s] = hv;
      }
  }
}

// ---------------------------------------------------------------------------
// k_pass1: column stats of S over t (softmax axis). Block = (b, s-block 64),
// all t. A (T16 s-rows, full K) persisted in LDS; B (QG t-rows) streamed dbuf
// (stage-once / read-once, global chunk counter). Writes MR[s]=(m,1/denom).
// ---------------------------------------------------------------------------
__global__ __launch_bounds__(512, 2) void k_pass1(const f16* __restrict__ T16,
                                                  const f16* __restrict__ QG,
                                                  float2* __restrict__ MR){
  const int gid = blockIdx.x;
  const int b = gid & 7;
  const int sb = gid >> 3;
  const int s0 = sb * 64;
  const int u = threadIdx.x;
  const int w = u >> 6, l = u & 63, lr = l & 15, lq = l >> 4;
  const int lo8 = l & 7, hi8 = l >> 3;

  __shared__ __align__(16) f16 At[64 * 512];       // 64KB, 1024B rows
  __shared__ __align__(16) f16 Bbuf[2][256 * 64];  // 2*32KB
  __shared__ float2 red[8 * 64];

  { // stage At once: 1 row per instr (64 slots)
    const f16* src = T16 + (size_t)(b * 2048 + s0) * 512;
#pragma unroll
    for (int k = 0; k < 8; ++k){
      int row = w * 8 + k;
      gld16((char*)At + row * 1024, src + (size_t)row * 512 + ((l ^ (row & 7)) * 8));
    }
  }
  auto stageB = [&](int ti, int c, int buf){
    const f16* src = QG + ((size_t)(b * 2048 + ti * 256) * 512 + c * 64);
#pragma unroll
    for (int k = 0; k < 4; ++k){
      int i = w * 4 + k;
      int row = i * 8 + hi8;
      gld16((char*)&Bbuf[buf][0] + i * 1024, src + (size_t)row * 512 + ((lo8 ^ (row & 7)) * 8));
    }
  };
  stageB(0, 0, 0);

  float m_[4][4], d_[4][4];
#pragma unroll
  for (int i = 0; i < 4; ++i)
#pragma unroll
    for (int j = 0; j < 4; ++j){ m_[i][j] = -1e30f; d_[i][j] = 0.f; }

  for (int ti = 0; ti < 8; ++ti){
    f32x4 sacc[4][2] = {};
    for (int c = 0; c < 8; ++c){
      __syncthreads();
      int n = ti * 8 + c + 1;
      if (n < 64) stageB(n >> 3, n & 7, n & 1);
      const f16* B = &Bbuf[(ti * 8 + c) & 1][0];
#pragma unroll
      for (int es = 0; es < 2; ++es){
        f16x8 af[4], bf[2];
#pragma unroll
        for (int mt = 0; mt < 4; ++mt){
          int row = mt * 16 + lr;
          int slot = c * 8 + es * 4 + lq;
          af[mt] = *(const f16x8*)((const char*)At + row * 1024 + ((slot ^ (row & 7)) << 4));
        }
#pragma unroll
        for (int nt = 0; nt < 2; ++nt){
          int row = w * 32 + nt * 16 + lr;
          bf[nt] = *(const f16x8*)((const char*)B + row * 128 + (((es * 4 + lq) ^ (row & 7)) << 4));
        }
#pragma unroll
        for (int mt = 0; mt < 4; ++mt)
#pragma unroll
          for (int nt = 0; nt < 2; ++nt)
            sacc[mt][nt] = mfma_f16(af[mt], bf[nt], sacc[mt][nt]);
      }
    }
#pragma unroll
    for (int mt = 0; mt < 4; ++mt)
#pragma unroll
      for (int nt = 0; nt < 2; ++nt)
#pragma unroll
        for (int j = 0; j < 4; ++j){
          float x = sacc[mt][nt][j] * LOG2E;
          float nm = fmaxf(m_[mt][j], x);
          d_[mt][j] = d_[mt][j] * exp2f(m_[mt][j] - nm) + exp2f(x - nm);
          m_[mt][j] = nm;
        }
  }
  // merge the 16 t-col lanes, then the 8 waves
#pragma unroll
  for (int mt = 0; mt < 4; ++mt)
#pragma unroll
    for (int j = 0; j < 4; ++j){
      float m = m_[mt][j], d = d_[mt][j];
#pragma unroll
      for (int off = 1; off <= 8; off <<= 1){
        float om = __shfl_xor(m, off, 64);
        float od = __shfl_xor(d, off, 64);
        float nm = fmaxf(m, om);
        d = d * exp2f(m - nm) + od * exp2f(om - nm);
        m = nm;
      }
      m_[mt][j] = m; d_[mt][j] = d;
    }
  __syncthreads();
  if (lr == 0){
#pragma unroll
    for (int mt = 0; mt < 4; ++mt)
#pragma unroll
      for (int j = 0; j < 4; ++j)
        red[w * 64 + mt * 16 + lq * 4 + j] = make_float2(m_[mt][j], d_[mt][j]);
  }
  __syncthreads();
  if (u < 64){
    float2 v = red[u];
    float m = v.x, d = v.y;
#pragma unroll
    for (int g = 1; g < 8; ++g){
      float2 o = red[g * 64 + u];
      float nm = fmaxf(m, o.x);
      d = d * exp2f(m - nm) + o.y * exp2f(o.x - nm);
      m = nm;
    }
    MR[b * 2048 + s0 + u] = make_float2(m, 1.0f / d);
  }
}

// ---------------------------------------------------------------------------
// k_pass2: block = (b, t-tile 64), full h=512. Per si (s-tile 256):
// recompute S (bit-identical chain to pass1), P = exp2(min(x-m,0))*rr -> Pl,
// then PV over 4 h-chunks x 4 s-subchunks with dbuf'd V staging.
// FIX vs r2: B (QG) chunk restaged EVERY (si,c) — it does not fit in 16KB.
// ---------------------------------------------------------------------------
__global__ __launch_bounds__(512, 2) void k_pass2(const f16* __restrict__ T16,
                                                  const f16* __restrict__ QG,
                                                  const f16* __restrict__ VT,
                                                  const float2* __restrict__ MR,
                                                  float* __restrict__ out){
  const int gid = blockIdx.x;
  const int b = gid & 7;
  const int tb = gid >> 3;
  const int t0 = tb * 64;
  const int u = threadIdx.x;
  const int w = u >> 6, l = u & 63, lr = l & 15, lq = l >> 4;
  const int lo8 = l & 7, hi8 = l >> 3;
  const int ws = w >> 1, wt = w & 1;   // S roles: 64s x 32t per wave
  const int ph = w >> 1, pt = w & 1;   // PV roles: 32h x 32t per wave (per 128h chunk)

  __shared__ __align__(16) f16 Abuf[2][256 * 64];  // 2*32KB  (T16 s-rows)
  __shared__ __align__(16) f16 Bbuf[2][64 * 64];   // 2*8KB   (QG t-rows, streamed)
  __shared__ __align__(16) f16 Pl[64 * 256];       // 32KB    (P[t][s])
  __shared__ __align__(16) f16 Vbuf[2][128 * 64];  // 2*16KB  (V^T chunk)

  f32x4 acc[4][2][2] = {};  // [hc][ht][nt]

  auto stageA = [&](int si, int c, int buf){
    const f16* src = T16 + ((size_t)(b * 2048 + si * 256) * 512 + c * 64);
#pragma unroll
    for (int k = 0; k < 4; ++k){
      int i = w * 4 + k;
      int row = i * 8 + hi8;
      gld16((char*)&Abuf[buf][0] + i * 1024, src + (size_t)row * 512 + ((lo8 ^ (row & 7)) * 8));
    }
  };
  auto stageB = [&](int c, int buf){
    const f16* src = QG + ((size_t)(b * 2048 + t0) * 512 + c * 64);
    int row = w * 8 + hi8;
    gld16((char*)&Bbuf[buf][0] + w * 1024, src + (size_t)row * 512 + ((lo8 ^ (row & 7)) * 8));
  };
  auto stageV = [&](int si, int hc, int sc, int buf){
    const f16* src = VT + ((size_t)(b * 512 + hc * 128) * 2048 + si * 256 + sc * 64);
#pragma unroll
    for (int k = 0; k < 2; ++k){
      int i = w * 2 + k;
      int row = i * 8 + hi8;
      gld16((char*)&Vbuf[buf][0] + i * 1024, src + (size_t)row * 2048 + ((lo8 ^ (row & 7)) * 8));
    }
  };

  stageA(0, 0, 0);
  stageB(0, 0);

  for (int si = 0; si < 8; ++si){
    // ---- S phase: 8 e-chunks, dbuf (A and B restaged every chunk) ----
    f32x4 sacc[4][2] = {};
    for (int c = 0; c < 8; ++c){
      __syncthreads();
      if (c < 7){
        stageA(si, c + 1, (c + 1) & 1);
        stageB(c + 1, (c + 1) & 1);
      } else {
        stageV(si, 0, 0, 0);
      }
      const f16* A = &Abuf[c & 1][0];
      const f16* B = &Bbuf[c & 1][0];
#pragma unroll
      for (int es = 0; es < 2; ++es){
        f16x8 af[4], bf[2];
#pragma unroll
        for (int mt = 0; mt < 4; ++mt){
          int row = ws * 64 + mt * 16 + lr;
          af[mt] = *(const f16x8*)((const char*)A + row * 128 + (((es * 4 + lq) ^ (row & 7)) << 4));
        }
#pragma unroll
        for (int nt = 0; nt < 2; ++nt){
          int row = wt * 32 + nt * 16 + lr;
          bf[nt] = *(const f16x8*)((const char*)B + row * 128 + (((es * 4 + lq) ^ (row & 7)) << 4));
        }
#pragma unroll
        for (int mt = 0; mt < 4; ++mt)
#pragma unroll
          for (int nt = 0; nt < 2; ++nt)
            sacc[mt][nt] = mfma_f16(af[mt], bf[nt], sacc[mt][nt]);
      }
    }
    // ---- P phase: exp -> Pl ----
    {
      float2 mr[4][4];
#pragma unroll
      for (int mt = 0; mt < 4; ++mt)
#pragma unroll
        for (int j = 0; j < 4; ++j)
          mr[mt][j] = MR[b * 2048 + si * 256 + ws * 64 + mt * 16 + lq * 4 + j];
#pragma unroll
      for (int mt = 0; mt < 4; ++mt)
#pragma unroll
        for (int nt = 0; nt < 2; ++nt){
          int t = wt * 32 + nt * 16 + lr;
          f16x4 pv;
#pragma unroll
          for (int j = 0; j < 4; ++j){
            float x = fminf(sacc[mt][nt][j] * LOG2E - mr[mt][j].x, 0.0f);
            pv[j] = (f16)(exp2f(x) * mr[mt][j].y);
          }
          int slot = ws * 8 + mt * 2 + (lq >> 1);
          int off = t * 512 + ((slot ^ (t & 7)) << 4) + (lq & 1) * 8;
          *(f16x4*)((char*)Pl + off) = pv;
        }
    }
    // ---- PV phase: 4 h-chunks x 4 s-subchunks, V dbuf ----
#pragma unroll
    for (int hc = 0; hc < 4; ++hc){
#pragma unroll
      for (int sc = 0; sc < 4; ++sc){
        const int step = hc * 4 + sc;
        __syncthreads();
        if (step < 15) stageV(si, (step + 1) >> 2, (step + 1) & 3, (step + 1) & 1);
        else if (si < 7){ stageA(si + 1, 0, 0); stageB(0, 0); }
        const f16* V = &Vbuf[step & 1][0];
#pragma unroll
        for (int es = 0; es < 2; ++es){
          f16x8 vf[2], pf[2];
#pragma unroll
          for (int ht = 0; ht < 2; ++ht){
            int row = ph * 32 + ht * 16 + lr;
            vf[ht] = *(const f16x8*)((const char*)V + row * 128 + (((es * 4 + lq) ^ (row & 7)) << 4));
          }
#pragma unroll
          for (int nt = 0; nt < 2; ++nt){
            int row = pt * 32 + nt * 16 + lr;
            int slot = sc * 8 + es * 4 + lq;
            pf[nt] = *(const f16x8*)((const char*)Pl + row * 512 + ((slot ^ (row & 7)) << 4));
          }
#pragma unroll
          for (int ht = 0; ht < 2; ++ht)
#pragma unroll
            for (int nt = 0; nt < 2; ++nt)
              acc[hc][ht][nt] = mfma_f16(vf[ht], pf[nt], acc[hc][ht][nt]);
        }
      }
    }
  }
  // ---- epilogue: ctx^T frag -> out[b][t][h] ----
#pragma unroll
  for (int hc = 0; hc < 4; ++hc)
#pragma unroll
    for (int ht = 0; ht < 2; ++ht)
#pragma unroll
      for (int nt = 0; nt < 2; ++nt){
        int t = t0 + pt * 32 + nt * 16 + lr;
        int h = hc * 128 + ph * 32 + ht * 16 + lq * 4;
        float4 v;
        v.x = acc[hc][ht][nt][0]; v.y = acc[hc][ht][nt][1];
        v.z = acc[hc][ht][nt][2]; v.w = acc[hc][ht][nt][3];
        *(float4*)&out[(size_t)(b * 2048 + t) * 512 + h] = v;
      }
}

// ---------------------------------------------------------------------------
extern "C" void kernel_launch(void* const* d_in, const int* in_sizes, int n_in,
                              void* d_out, int out_size, void* d_ws, size_t ws_size,
                              hipStream_t stream){
  (void)in_sizes; (void)n_in; (void)out_size; (void)ws_size;
  const float* tokens = (const float*)d_in[0];
  const float* Wq = (const float*)d_in[1];
  const float* Wk = (const float*)d_in[2];
  const float* Wv = (const float*)d_in[3];
  char* ws = (char*)d_ws;
  f16*    T16 = (f16*)(ws);                       // 16 MiB
  f16*    QG  = (f16*)(ws + 16777216);            // 16 MiB
  f16*    VT  = (f16*)(ws + 33554432);            // 16 MiB
  f16*    B16 = (f16*)(ws + 50331648);            // 1 MiB
  float2* MR  = (float2*)(ws + 51380224);         // 128 KiB
  float* out = (float*)d_out;

  k_prep_g <<<dim3(16, 16), dim3(256), 0, stream>>>(Wq, Wk, B16);
  k_prep_wv<<<dim3(8, 8),   dim3(256), 0, stream>>>(Wv, B16);
  k_cast   <<<dim3(4096),   dim3(256), 0, stream>>>(tokens, T16);
  k_gemm   <<<dim3(128, 8), dim3(256), 0, stream>>>(T16, B16, QG, VT);
  k_pass1  <<<dim3(256),    dim3(512), 0, stream>>>(T16, QG, MR);
  k_pass2  <<<dim3(256),    dim3(512), 0, stream>>>(T16, QG, VT, MR, out);
}

// Round 4
// 238.532 us; speedup vs baseline: 1.4963x; 1.1230x over previous
//
#include <hip/hip_runtime.h>

typedef _Float16 f16;
typedef _Float16 f16x8 __attribute__((ext_vector_type(8)));
typedef _Float16 f16x4 __attribute__((ext_vector_type(4)));
typedef float   f32x4 __attribute__((ext_vector_type(4)));

#define LOG2E 1.44269504088896340736f

__device__ __forceinline__ f32x4 mfma_f16(f16x8 a, f16x8 b, f32x4 c){
  return __builtin_amdgcn_mfma_f32_16x16x32_f16(a, b, c, 0, 0, 0);
}

// global -> LDS direct DMA, 16B per lane. lds must be wave-uniform base;
// HW writes base + lane*16. Source address is per-lane (pre-swizzled).
__device__ __forceinline__ void gld16(void* lds, const void* g){
  __builtin_amdgcn_global_load_lds(
      (const __attribute__((address_space(1))) unsigned int*)g,
      (__attribute__((address_space(3))) unsigned int*)lds,
      16, 0, 0);
}

// ---------------------------------------------------------------------------
// k_prep_g: B16[n][e] = sum_x Wk[n][x]*Wq[e][x]  (= (Wq Wk^T)^T), n<512.
// ---------------------------------------------------------------------------
__global__ __launch_bounds__(256) void k_prep_g(const float* __restrict__ Wq,
                                                const float* __restrict__ Wk,
                                                f16* __restrict__ B16){
  __shared__ float ak[32][36];
  __shared__ float aq[32][36];
  const int n0 = blockIdx.y * 32, e0 = blockIdx.x * 32;
  const int u = threadIdx.x;
  const int ty = u >> 4, tx = u & 15;
  float acc[2][2] = {};
  for (int x0 = 0; x0 < 512; x0 += 32){
    __syncthreads();
    {
      int r = u >> 3, c4 = (u & 7) * 4;
      *(float4*)&ak[r][c4] = *(const float4*)&Wk[(n0 + r) * 512 + x0 + c4];
      *(float4*)&aq[r][c4] = *(const float4*)&Wq[(e0 + r) * 512 + x0 + c4];
    }
    __syncthreads();
#pragma unroll 8
    for (int x = 0; x < 32; ++x){
      float k0 = ak[ty * 2 + 0][x], k1 = ak[ty * 2 + 1][x];
      float q0 = aq[tx * 2 + 0][x], q1 = aq[tx * 2 + 1][x];
      acc[0][0] += k0 * q0; acc[0][1] += k0 * q1;
      acc[1][0] += k1 * q0; acc[1][1] += k1 * q1;
    }
  }
#pragma unroll
  for (int i = 0; i < 2; ++i)
#pragma unroll
    for (int j = 0; j < 2; ++j)
      B16[(size_t)(n0 + ty * 2 + i) * 512 + e0 + tx * 2 + j] = (f16)acc[i][j];
}

// ---------------------------------------------------------------------------
// k_prep_wv: B16[512+d][e] = Wv[e][d]  (transpose + fp16 cast)
// ---------------------------------------------------------------------------
__global__ __launch_bounds__(256) void k_prep_wv(const float* __restrict__ Wv,
                                                 f16* __restrict__ B16){
  __shared__ float t[64][72];
  const int e0 = blockIdx.x * 64, h0 = blockIdx.y * 64;
  const int u = threadIdx.x;
#pragma unroll
  for (int k = 0; k < 4; ++k){
    int idx = u + k * 256; int r = idx >> 4, c4 = (idx & 15) * 4;
    *(float4*)&t[r][c4] = *(const float4*)&Wv[(e0 + r) * 512 + h0 + c4];
  }
  __syncthreads();
#pragma unroll
  for (int k = 0; k < 4; ++k){
    int idx = u + k * 256; int j = idx >> 4, i4 = (idx & 15) * 4;
#pragma unroll
    for (int c = 0; c < 4; ++c)
      B16[(size_t)(512 + h0 + j) * 512 + e0 + i4 + c] = (f16)t[i4 + c][j];
  }
}

// ---------------------------------------------------------------------------
// k_cast: tokens fp32 -> fp16, 8/thread.
// ---------------------------------------------------------------------------
__global__ __launch_bounds__(256) void k_cast(const float* __restrict__ tok,
                                              f16* __restrict__ T16){
  int i = blockIdx.x * 256 + threadIdx.x;
  const float4* p = (const float4*)tok + (size_t)i * 2;
  float4 a = p[0], b = p[1];
  f16x8 h;
  h[0] = (f16)a.x; h[1] = (f16)a.y; h[2] = (f16)a.z; h[3] = (f16)a.w;
  h[4] = (f16)b.x; h[5] = (f16)b.y; h[6] = (f16)b.z; h[7] = (f16)b.w;
  *((f16x8*)T16 + i) = h;
}

// ---------------------------------------------------------------------------
// k_gemm: C[t][n] = sum_e T16[t][e]*B16[n][e]; n<512 -> QG[t][n],
// n>=512 -> VT[b][d][s]. 128x128 tile, BK=64, dbuf, global_load_lds.
// ---------------------------------------------------------------------------
__global__ __launch_bounds__(256, 2) void k_gemm(const f16* __restrict__ T16,
                                                 const f16* __restrict__ B16,
                                                 f16* __restrict__ QG,
                                                 f16* __restrict__ VT){
  __shared__ __align__(16) f16 Abuf[2][128 * 64];
  __shared__ __align__(16) f16 Bbuf[2][128 * 64];
  const int tb = blockIdx.x, nb = blockIdx.y;
  const int u = threadIdx.x;
  const int w = u >> 6, l = u & 63, lr = l & 15, lq = l >> 4;
  const int lo8 = l & 7, hi8 = l >> 3;
  const int wm = (w & 1) * 64, wn = (w >> 1) * 64;
  f32x4 acc[4][4] = {};
  auto stage = [&](int c, int buf){
    const f16* sa = T16 + (size_t)tb * 128 * 512 + c * 64;
    const f16* sb = B16 + (size_t)nb * 128 * 512 + c * 64;
#pragma unroll
    for (int k = 0; k < 4; ++k){
      int i = w * 4 + k;
      int row = i * 8 + hi8;
      gld16((char*)&Abuf[buf][0] + i * 1024, sa + (size_t)row * 512 + ((lo8 ^ (row & 7)) * 8));
      gld16((char*)&Bbuf[buf][0] + i * 1024, sb + (size_t)row * 512 + ((lo8 ^ (row & 7)) * 8));
    }
  };
  stage(0, 0);
  for (int c = 0; c < 8; ++c){
    __syncthreads();
    if (c < 7) stage(c + 1, (c + 1) & 1);
    const f16* A = &Abuf[c & 1][0];
    const f16* B = &Bbuf[c & 1][0];
#pragma unroll
    for (int es = 0; es < 2; ++es){
      f16x8 af[4], bf[4];
#pragma unroll
      for (int mt = 0; mt < 4; ++mt){
        int row = wm + mt * 16 + lr;
        af[mt] = *(const f16x8*)((const char*)A + row * 128 + (((es * 4 + lq) ^ (row & 7)) << 4));
      }
#pragma unroll
      for (int nt = 0; nt < 4; ++nt){
        int row = wn + nt * 16 + lr;
        bf[nt] = *(const f16x8*)((const char*)B + row * 128 + (((es * 4 + lq) ^ (row & 7)) << 4));
      }
#pragma unroll
      for (int mt = 0; mt < 4; ++mt)
#pragma unroll
        for (int nt = 0; nt < 4; ++nt)
          acc[mt][nt] = mfma_f16(af[mt], bf[nt], acc[mt][nt]);
    }
  }
  if (nb < 4){
#pragma unroll
    for (int mt = 0; mt < 4; ++mt)
#pragma unroll
      for (int nt = 0; nt < 4; ++nt){
        int n = nb * 128 + wn + nt * 16 + lr;
        int r0 = tb * 128 + wm + mt * 16 + lq * 4;
#pragma unroll
        for (int j = 0; j < 4; ++j)
          QG[(size_t)(r0 + j) * 512 + n] = (f16)acc[mt][nt][j];
      }
  } else {
#pragma unroll
    for (int mt = 0; mt < 4; ++mt)
#pragma unroll
      for (int nt = 0; nt < 4; ++nt){
        int h = (nb - 4) * 128 + wn + nt * 16 + lr;
        int r0 = tb * 128 + wm + mt * 16 + lq * 4;
        int bq = r0 >> 11, s = r0 & 2047;
        f16x4 hv;
#pragma unroll
        for (int j = 0; j < 4; ++j) hv[j] = (f16)acc[mt][nt][j];
        *(f16x4*)&VT[(size_t)(bq * 512 + h) * 2048 + s] = hv;
      }
  }
}

// ===========================================================================
// NEW PATH: pass1p stores P' tiles + per-tile scale table; pass2p is PV-only.
// ===========================================================================

// ---------------------------------------------------------------------------
// k_pass1p: block = (b, s-block 64). Per t-tile ti (256 t):
//  S-tile via MFMA (At persisted, B streamed dbuf), tile-local col max M[s,ti]
//  (shuffle + LDS reduce), P' = exp2(x - M) -> fp16 store to Pp[b][t][s],
//  D[s,ti] = col-sum of P'. End: SC[ti][s] = exp2(M-mfin)/denom.
// ---------------------------------------------------------------------------
__global__ __launch_bounds__(512, 2) void k_pass1p(const f16* __restrict__ T16,
                                                   const f16* __restrict__ QG,
                                                   f16* __restrict__ Pp,
                                                   float* __restrict__ SC){
  const int gid = blockIdx.x;
  const int b = gid & 7;
  const int sb = gid >> 3;
  const int s0 = sb * 64;
  const int u = threadIdx.x;
  const int w = u >> 6, l = u & 63, lr = l & 15, lq = l >> 4;
  const int lo8 = l & 7, hi8 = l >> 3;

  __shared__ __align__(16) f16 At[64 * 512];       // 64KB
  __shared__ __align__(16) f16 Bbuf[2][256 * 64];  // 2*32KB
  __shared__ float red[8 * 64];
  __shared__ float Ms[64];
  __shared__ float Ml[8 * 64];
  __shared__ float Dl[8 * 64];

  { // stage At once
    const f16* src = T16 + (size_t)(b * 2048 + s0) * 512;
#pragma unroll
    for (int k = 0; k < 8; ++k){
      int row = w * 8 + k;
      gld16((char*)At + row * 1024, src + (size_t)row * 512 + ((l ^ (row & 7)) * 8));
    }
  }
  auto stageB = [&](int ti, int c, int buf){
    const f16* src = QG + ((size_t)(b * 2048 + ti * 256) * 512 + c * 64);
#pragma unroll
    for (int k = 0; k < 4; ++k){
      int i = w * 4 + k;
      int row = i * 8 + hi8;
      gld16((char*)&Bbuf[buf][0] + i * 1024, src + (size_t)row * 512 + ((lo8 ^ (row & 7)) * 8));
    }
  };
  stageB(0, 0, 0);

  for (int ti = 0; ti < 8; ++ti){
    f32x4 sacc[4][2] = {};
    for (int c = 0; c < 8; ++c){
      __syncthreads();
      int n = ti * 8 + c + 1;
      if (n < 64) stageB(n >> 3, n & 7, n & 1);
      const f16* B = &Bbuf[(ti * 8 + c) & 1][0];
#pragma unroll
      for (int es = 0; es < 2; ++es){
        f16x8 af[4], bf[2];
#pragma unroll
        for (int mt = 0; mt < 4; ++mt){
          int row = mt * 16 + lr;
          int slot = c * 8 + es * 4 + lq;
          af[mt] = *(const f16x8*)((const char*)At + row * 1024 + ((slot ^ (row & 7)) << 4));
        }
#pragma unroll
        for (int nt = 0; nt < 2; ++nt){
          int row = w * 32 + nt * 16 + lr;
          bf[nt] = *(const f16x8*)((const char*)B + row * 128 + (((es * 4 + lq) ^ (row & 7)) << 4));
        }
#pragma unroll
        for (int mt = 0; mt < 4; ++mt)
#pragma unroll
          for (int nt = 0; nt < 2; ++nt)
            sacc[mt][nt] = mfma_f16(af[mt], bf[nt], sacc[mt][nt]);
      }
    }
    // ---- x = S*log2e; tile-local column max over the 256 t of this tile ----
    float xv[4][2][4];
#pragma unroll
    for (int mt = 0; mt < 4; ++mt)
#pragma unroll
      for (int nt = 0; nt < 2; ++nt)
#pragma unroll
        for (int j = 0; j < 4; ++j)
          xv[mt][nt][j] = sacc[mt][nt][j] * LOG2E;
#pragma unroll
    for (int mt = 0; mt < 4; ++mt)
#pragma unroll
      for (int j = 0; j < 4; ++j){
        float m2 = fmaxf(xv[mt][0][j], xv[mt][1][j]);
#pragma unroll
        for (int off = 1; off <= 8; off <<= 1)
          m2 = fmaxf(m2, __shfl_xor(m2, off, 64));
        if (lr == 0) red[w * 64 + mt * 16 + lq * 4 + j] = m2;
      }
    __syncthreads();
    if (u < 64){
      float M = red[u];
#pragma unroll
      for (int g = 1; g < 8; ++g) M = fmaxf(M, red[g * 64 + u]);
      Ms[u] = M;
      Ml[ti * 64 + u] = M;
    }
    __syncthreads();
    // ---- P' = exp2(x - M), store fp16, accumulate column sums ----
#pragma unroll
    for (int mt = 0; mt < 4; ++mt)
#pragma unroll
      for (int nt = 0; nt < 2; ++nt)
#pragma unroll
        for (int j = 0; j < 4; ++j)
          xv[mt][nt][j] = exp2f(xv[mt][nt][j] - Ms[mt * 16 + lq * 4 + j]);
#pragma unroll
    for (int mt = 0; mt < 4; ++mt)
#pragma unroll
      for (int nt = 0; nt < 2; ++nt){
        int t = ti * 256 + w * 32 + nt * 16 + lr;
        f16x4 h4;
#pragma unroll
        for (int j = 0; j < 4; ++j) h4[j] = (f16)xv[mt][nt][j];
        *(f16x4*)&Pp[(size_t)(b * 2048 + t) * 2048 + s0 + mt * 16 + lq * 4] = h4;
      }
#pragma unroll
    for (int mt = 0; mt < 4; ++mt)
#pragma unroll
      for (int j = 0; j < 4; ++j){
        float sd = xv[mt][0][j] + xv[mt][1][j];
#pragma unroll
        for (int off = 1; off <= 8; off <<= 1)
          sd += __shfl_xor(sd, off, 64);
        if (lr == 0) red[w * 64 + mt * 16 + lq * 4 + j] = sd;
      }
    __syncthreads();
    if (u < 64){
      float D = red[u];
#pragma unroll
      for (int g = 1; g < 8; ++g) D += red[g * 64 + u];
      Dl[ti * 64 + u] = D;
    }
    // next ti's first chunk __syncthreads orders red/Ms reuse
  }
  if (u < 64){
    float mf = Ml[u];
#pragma unroll
    for (int ti = 1; ti < 8; ++ti) mf = fmaxf(mf, Ml[ti * 64 + u]);
    float d = 0.f;
#pragma unroll
    for (int ti = 0; ti < 8; ++ti) d += Dl[ti * 64 + u] * exp2f(Ml[ti * 64 + u] - mf);
    float rd = 1.0f / d;
#pragma unroll
    for (int ti = 0; ti < 8; ++ti)
      SC[ti * 16384 + b * 2048 + s0 + u] = exp2f(Ml[ti * 64 + u] - mf) * rd;
  }
}

// ---------------------------------------------------------------------------
// k_pass2p: PV only. block = (b, t-tile 64, h-half 256), 256 threads, grid 512.
// Per si (256 s): stage P' tile (64t x 256s) + sc row, scale Pl in place,
// then 8 V-steps (256h x 32s chunks, dbuf). acc over all si; fp32 store.
// LDS 65KB -> 2 blocks/CU.
// ---------------------------------------------------------------------------
__global__ __launch_bounds__(256, 2) void k_pass2p(const f16* __restrict__ Pp,
                                                   const f16* __restrict__ VT,
                                                   const float* __restrict__ SC,
                                                   float* __restrict__ out){
  const int gid = blockIdx.x;
  const int b = gid & 7;
  const int tt = (gid >> 3) & 31;
  const int hh = gid >> 8;
  const int t0 = tt * 64;
  const int ti = tt >> 2;
  const int u = threadIdx.x;
  const int w = u >> 6, l = u & 63, lr = l & 15, lq = l >> 4;

  __shared__ __align__(16) f16 Pl[64 * 256];     // 32KB, rows 512B, swizzled
  __shared__ __align__(16) f16 Vt[2][256 * 32];  // 2*16KB, rows 64B, swizzled
  __shared__ float scl[256];                      // 1KB

  f32x4 acc[4][4] = {};

  auto stagePl = [&](int si){
#pragma unroll
    for (int k = 0; k < 8; ++k){
      int i = w * 8 + k;
      int row = i * 2 + (l >> 5);
      int slot = l & 31;
      gld16((char*)Pl + i * 1024,
            Pp + ((size_t)(b * 2048 + t0 + row) * 2048 + si * 256 + ((slot ^ (row & 7)) * 8)));
    }
  };
  auto stageV = [&](int si, int sc_, int buf){
#pragma unroll
    for (int k = 0; k < 4; ++k){
      int i = w * 4 + k;
      int row = i * 16 + (l >> 2);
      gld16((char*)&Vt[buf][0] + i * 1024,
            VT + ((size_t)(b * 512 + hh * 256 + row) * 2048 + si * 256 + sc_ * 32 + (((l & 3) ^ (row & 3)) * 8)));
    }
  };

  for (int si = 0; si < 8; ++si){
    __syncthreads(); // prior PV reads of Pl done
    stagePl(si);
    if (w == 0) gld16(scl, SC + ti * 16384 + b * 2048 + si * 256 + l * 4);
    __syncthreads(); // Pl + scl landed (compiler drains vmcnt before barrier)
    { // scale Pl in place: thread owns row u>>2, slots (u&3)*8 .. +7
      int row = u >> 2;
#pragma unroll
      for (int k = 0; k < 8; ++k){
        int slot = (u & 3) * 8 + k;
        f16* p = (f16*)((char*)Pl + row * 512 + ((slot ^ (row & 7)) << 4));
        f16x8 v = *(f16x8*)p;
#pragma unroll
        for (int e = 0; e < 8; ++e)
          v[e] = (f16)((float)v[e] * scl[slot * 8 + e]);
        *(f16x8*)p = v;
      }
    }
    stageV(si, 0, 0);
    __syncthreads(); // scaled Pl visible + V chunk 0 landed
#pragma unroll
    for (int sc_ = 0; sc_ < 8; ++sc_){
      if (sc_ < 7) stageV(si, sc_ + 1, (sc_ + 1) & 1);
      const f16* V = &Vt[sc_ & 1][0];
      f16x8 vf[4], pf[4];
#pragma unroll
      for (int ht = 0; ht < 4; ++ht){
        int row = w * 64 + ht * 16 + lr;
        vf[ht] = *(const f16x8*)((const char*)V + row * 64 + ((lq ^ (row & 3)) << 4));
      }
#pragma unroll
      for (int nt = 0; nt < 4; ++nt){
        int row = nt * 16 + lr;
        pf[nt] = *(const f16x8*)((const char*)Pl + row * 512 + (((sc_ * 4 + lq) ^ (row & 7)) << 4));
      }
#pragma unroll
      for (int ht = 0; ht < 4; ++ht)
#pragma unroll
        for (int nt = 0; nt < 4; ++nt)
          acc[ht][nt] = mfma_f16(vf[ht], pf[nt], acc[ht][nt]);
      __syncthreads(); // V[buf^1] landed for next step; reads of V[buf] done
    }
  }
  // epilogue: h = hh*256 + w*64 + ht*16 + lq*4 (+j), t = t0 + nt*16 + lr
#pragma unroll
  for (int ht = 0; ht < 4; ++ht)
#pragma unroll
    for (int nt = 0; nt < 4; ++nt){
      int t = t0 + nt * 16 + lr;
      int h = hh * 256 + w * 64 + ht * 16 + lq * 4;
      float4 v;
      v.x = acc[ht][nt][0]; v.y = acc[ht][nt][1];
      v.z = acc[ht][nt][2]; v.w = acc[ht][nt][3];
      *(float4*)&out[(size_t)(b * 2048 + t) * 512 + h] = v;
    }
}

// ===========================================================================
// FALLBACK PATH (validated round-3 kernels) — used when ws is too small.
// ===========================================================================
__global__ __launch_bounds__(512, 2) void k_pass1(const f16* __restrict__ T16,
                                                  const f16* __restrict__ QG,
                                                  float2* __restrict__ MR){
  const int gid = blockIdx.x;
  const int b = gid & 7;
  const int sb = gid >> 3;
  const int s0 = sb * 64;
  const int u = threadIdx.x;
  const int w = u >> 6, l = u & 63, lr = l & 15, lq = l >> 4;
  const int lo8 = l & 7, hi8 = l >> 3;

  __shared__ __align__(16) f16 At[64 * 512];
  __shared__ __align__(16) f16 Bbuf[2][256 * 64];
  __shared__ float2 red[8 * 64];

  {
    const f16* src = T16 + (size_t)(b * 2048 + s0) * 512;
#pragma unroll
    for (int k = 0; k < 8; ++k){
      int row = w * 8 + k;
      gld16((char*)At + row * 1024, src + (size_t)row * 512 + ((l ^ (row & 7)) * 8));
    }
  }
  auto stageB = [&](int ti, int c, int buf){
    const f16* src = QG + ((size_t)(b * 2048 + ti * 256) * 512 + c * 64);
#pragma unroll
    for (int k = 0; k < 4; ++k){
      int i = w * 4 + k;
      int row = i * 8 + hi8;
      gld16((char*)&Bbuf[buf][0] + i * 1024, src + (size_t)row * 512 + ((lo8 ^ (row & 7)) * 8));
    }
  };
  stageB(0, 0, 0);

  float m_[4][4], d_[4][4];
#pragma unroll
  for (int i = 0; i < 4; ++i)
#pragma unroll
    for (int j = 0; j < 4; ++j){ m_[i][j] = -1e30f; d_[i][j] = 0.f; }

  for (int ti = 0; ti < 8; ++ti){
    f32x4 sacc[4][2] = {};
    for (int c = 0; c < 8; ++c){
      __syncthreads();
      int n = ti * 8 + c + 1;
      if (n < 64) stageB(n >> 3, n & 7, n & 1);
      const f16* B = &Bbuf[(ti * 8 + c) & 1][0];
#pragma unroll
      for (int es = 0; es < 2; ++es){
        f16x8 af[4], bf[2];
#pragma unroll
        for (int mt = 0; mt < 4; ++mt){
          int row = mt * 16 + lr;
          int slot = c * 8 + es * 4 + lq;
          af[mt] = *(const f16x8*)((const char*)At + row * 1024 + ((slot ^ (row & 7)) << 4));
        }
#pragma unroll
        for (int nt = 0; nt < 2; ++nt){
          int row = w * 32 + nt * 16 + lr;
          bf[nt] = *(const f16x8*)((const char*)B + row * 128 + (((es * 4 + lq) ^ (row & 7)) << 4));
        }
#pragma unroll
        for (int mt = 0; mt < 4; ++mt)
#pragma unroll
          for (int nt = 0; nt < 2; ++nt)
            sacc[mt][nt] = mfma_f16(af[mt], bf[nt], sacc[mt][nt]);
      }
    }
#pragma unroll
    for (int mt = 0; mt < 4; ++mt)
#pragma unroll
      for (int nt = 0; nt < 2; ++nt)
#pragma unroll
        for (int j = 0; j < 4; ++j){
          float x = sacc[mt][nt][j] * LOG2E;
          float nm = fmaxf(m_[mt][j], x);
          d_[mt][j] = d_[mt][j] * exp2f(m_[mt][j] - nm) + exp2f(x - nm);
          m_[mt][j] = nm;
        }
  }
#pragma unroll
  for (int mt = 0; mt < 4; ++mt)
#pragma unroll
    for (int j = 0; j < 4; ++j){
      float m = m_[mt][j], d = d_[mt][j];
#pragma unroll
      for (int off = 1; off <= 8; off <<= 1){
        float om = __shfl_xor(m, off, 64);
        float od = __shfl_xor(d, off, 64);
        float nm = fmaxf(m, om);
        d = d * exp2f(m - nm) + od * exp2f(om - nm);
        m = nm;
      }
      m_[mt][j] = m; d_[mt][j] = d;
    }
  __syncthreads();
  if (lr == 0){
#pragma unroll
    for (int mt = 0; mt < 4; ++mt)
#pragma unroll
      for (int j = 0; j < 4; ++j)
        red[w * 64 + mt * 16 + lq * 4 + j] = make_float2(m_[mt][j], d_[mt][j]);
  }
  __syncthreads();
  if (u < 64){
    float2 v = red[u];
    float m = v.x, d = v.y;
#pragma unroll
    for (int g = 1; g < 8; ++g){
      float2 o = red[g * 64 + u];
      float nm = fmaxf(m, o.x);
      d = d * exp2f(m - nm) + o.y * exp2f(o.x - nm);
      m = nm;
    }
    MR[b * 2048 + s0 + u] = make_float2(m, 1.0f / d);
  }
}

__global__ __launch_bounds__(512, 2) void k_pass2(const f16* __restrict__ T16,
                                                  const f16* __restrict__ QG,
                                                  const f16* __restrict__ VT,
                                                  const float2* __restrict__ MR,
                                                  float* __restrict__ out){
  const int gid = blockIdx.x;
  const int b = gid & 7;
  const int tb = gid >> 3;
  const int t0 = tb * 64;
  const int u = threadIdx.x;
  const int w = u >> 6, l = u & 63, lr = l & 15, lq = l >> 4;
  const int lo8 = l & 7, hi8 = l >> 3;
  const int ws = w >> 1, wt = w & 1;
  const int ph = w >> 1, pt = w & 1;

  __shared__ __align__(16) f16 Abuf[2][256 * 64];
  __shared__ __align__(16) f16 Bbuf[2][64 * 64];
  __shared__ __align__(16) f16 Pl[64 * 256];
  __shared__ __align__(16) f16 Vbuf[2][128 * 64];

  f32x4 acc[4][2][2] = {};

  auto stageA = [&](int si, int c, int buf){
    const f16* src = T16 + ((size_t)(b * 2048 + si * 256) * 512 + c * 64);
#pragma unroll
    for (int k = 0; k < 4; ++k){
      int i = w * 4 + k;
      int row = i * 8 + hi8;
      gld16((char*)&Abuf[buf][0] + i * 1024, src + (size_t)row * 512 + ((lo8 ^ (row & 7)) * 8));
    }
  };
  auto stageB = [&](int c, int buf){
    const f16* src = QG + ((size_t)(b * 2048 + t0) * 512 + c * 64);
    int row = w * 8 + hi8;
    gld16((char*)&Bbuf[buf][0] + w * 1024, src + (size_t)row * 512 + ((lo8 ^ (row & 7)) * 8));
  };
  auto stageV = [&](int si, int hc, int sc, int buf){
    const f16* src = VT + ((size_t)(b * 512 + hc * 128) * 2048 + si * 256 + sc * 64);
#pragma unroll
    for (int k = 0; k < 2; ++k){
      int i = w * 2 + k;
      int row = i * 8 + hi8;
      gld16((char*)&Vbuf[buf][0] + i * 1024, src + (size_t)row * 2048 + ((lo8 ^ (row & 7)) * 8));
    }
  };

  stageA(0, 0, 0);
  stageB(0, 0);

  for (int si = 0; si < 8; ++si){
    f32x4 sacc[4][2] = {};
    for (int c = 0; c < 8; ++c){
      __syncthreads();
      if (c < 7){
        stageA(si, c + 1, (c + 1) & 1);
        stageB(c + 1, (c + 1) & 1);
      } else {
        stageV(si, 0, 0, 0);
      }
      const f16* A = &Abuf[c & 1][0];
      const f16* B = &Bbuf[c & 1][0];
#pragma unroll
      for (int es = 0; es < 2; ++es){
        f16x8 af[4], bf[2];
#pragma unroll
        for (int mt = 0; mt < 4; ++mt){
          int row = ws * 64 + mt * 16 + lr;
          af[mt] = *(const f16x8*)((const char*)A + row * 128 + (((es * 4 + lq) ^ (row & 7)) << 4));
        }
#pragma unroll
        for (int nt = 0; nt < 2; ++nt){
          int row = wt * 32 + nt * 16 + lr;
          bf[nt] = *(const f16x8*)((const char*)B + row * 128 + (((es * 4 + lq) ^ (row & 7)) << 4));
        }
#pragma unroll
        for (int mt = 0; mt < 4; ++mt)
#pragma unroll
          for (int nt = 0; nt < 2; ++nt)
            sacc[mt][nt] = mfma_f16(af[mt], bf[nt], sacc[mt][nt]);
      }
    }
    {
      float2 mr[4][4];
#pragma unroll
      for (int mt = 0; mt < 4; ++mt)
#pragma unroll
        for (int j = 0; j < 4; ++j)
          mr[mt][j] = MR[b * 2048 + si * 256 + ws * 64 + mt * 16 + lq * 4 + j];
#pragma unroll
      for (int mt = 0; mt < 4; ++mt)
#pragma unroll
        for (int nt = 0; nt < 2; ++nt){
          int t = wt * 32 + nt * 16 + lr;
          f16x4 pv;
#pragma unroll
          for (int j = 0; j < 4; ++j){
            float x = fminf(sacc[mt][nt][j] * LOG2E - mr[mt][j].x, 0.0f);
            pv[j] = (f16)(exp2f(x) * mr[mt][j].y);
          }
          int slot = ws * 8 + mt * 2 + (lq >> 1);
          int off = t * 512 + ((slot ^ (t & 7)) << 4) + (lq & 1) * 8;
          *(f16x4*)((char*)Pl + off) = pv;
        }
    }
#pragma unroll
    for (int hc = 0; hc < 4; ++hc){
#pragma unroll
      for (int sc = 0; sc < 4; ++sc){
        const int step = hc * 4 + sc;
        __syncthreads();
        if (step < 15) stageV(si, (step + 1) >> 2, (step + 1) & 3, (step + 1) & 1);
        else if (si < 7){ stageA(si + 1, 0, 0); stageB(0, 0); }
        const f16* V = &Vbuf[step & 1][0];
#pragma unroll
        for (int es = 0; es < 2; ++es){
          f16x8 vf[2], pf[2];
#pragma unroll
          for (int ht = 0; ht < 2; ++ht){
            int row = ph * 32 + ht * 16 + lr;
            vf[ht] = *(const f16x8*)((const char*)V + row * 128 + (((es * 4 + lq) ^ (row & 7)) << 4));
          }
#pragma unroll
          for (int nt = 0; nt < 2; ++nt){
            int row = pt * 32 + nt * 16 + lr;
            int slot = sc * 8 + es * 4 + lq;
            pf[nt] = *(const f16x8*)((const char*)Pl + row * 512 + ((slot ^ (row & 7)) << 4));
          }
#pragma unroll
          for (int ht = 0; ht < 2; ++ht)
#pragma unroll
            for (int nt = 0; nt < 2; ++nt)
              acc[hc][ht][nt] = mfma_f16(vf[ht], pf[nt], acc[hc][ht][nt]);
        }
      }
    }
  }
#pragma unroll
  for (int hc = 0; hc < 4; ++hc)
#pragma unroll
    for (int ht = 0; ht < 2; ++ht)
#pragma unroll
      for (int nt = 0; nt < 2; ++nt){
        int t = t0 + pt * 32 + nt * 16 + lr;
        int h = hc * 128 + ph * 32 + ht * 16 + lq * 4;
        float4 v;
        v.x = acc[hc][ht][nt][0]; v.y = acc[hc][ht][nt][1];
        v.z = acc[hc][ht][nt][2]; v.w = acc[hc][ht][nt][3];
        *(float4*)&out[(size_t)(b * 2048 + t) * 512 + h] = v;
      }
}

// ---------------------------------------------------------------------------
extern "C" void kernel_launch(void* const* d_in, const int* in_sizes, int n_in,
                              void* d_out, int out_size, void* d_ws, size_t ws_size,
                              hipStream_t stream){
  (void)in_sizes; (void)n_in; (void)out_size;
  const float* tokens = (const float*)d_in[0];
  const float* Wq = (const float*)d_in[1];
  const float* Wk = (const float*)d_in[2];
  const float* Wv = (const float*)d_in[3];
  char* ws = (char*)d_ws;
  f16*    T16 = (f16*)(ws);                        // [0, 16M)
  f16*    QG  = (f16*)(ws + (16u << 20));          // [16M, 32M)
  f16*    VT  = (f16*)(ws + (32u << 20));          // [32M, 48M)
  f16*    B16 = (f16*)(ws + (48u << 20));          // [48M, 49M)
  float2* MR  = (float2*)(ws + (49u << 20));       // [49M, 49.2M)  (fallback)
  float*  SC  = (float*)(ws + (50u << 20));        // [50M, 50.5M)  (new)
  f16*    Pp  = (f16*)(ws + (54u << 20));          // [54M, 118M)   (new)
  float* out = (float*)d_out;

  const size_t NEED = (size_t)118u << 20;

  k_prep_g <<<dim3(16, 16), dim3(256), 0, stream>>>(Wq, Wk, B16);
  k_prep_wv<<<dim3(8, 8),   dim3(256), 0, stream>>>(Wv, B16);
  k_cast   <<<dim3(4096),   dim3(256), 0, stream>>>(tokens, T16);
  k_gemm   <<<dim3(128, 8), dim3(256), 0, stream>>>(T16, B16, QG, VT);
  if (ws_size >= NEED){
    k_pass1p<<<dim3(256), dim3(512), 0, stream>>>(T16, QG, Pp, SC);
    k_pass2p<<<dim3(512), dim3(256), 0, stream>>>(Pp, VT, SC, out);
  } else {
    k_pass1 <<<dim3(256), dim3(512), 0, stream>>>(T16, QG, MR);
    k_pass2 <<<dim3(256), dim3(512), 0, stream>>>(T16, QG, VT, MR, out);
  }
}

// Round 5
// 201.135 us; speedup vs baseline: 1.7745x; 1.1859x over previous
//
#include <hip/hip_runtime.h>

typedef _Float16 f16;
typedef _Float16 f16x8 __attribute__((ext_vector_type(8)));
typedef _Float16 f16x4 __attribute__((ext_vector_type(4)));
typedef float   f32x4 __attribute__((ext_vector_type(4)));

#define LOG2E 1.44269504088896340736f

__device__ __forceinline__ f32x4 mfma_f16(f16x8 a, f16x8 b, f32x4 c){
  return __builtin_amdgcn_mfma_f32_16x16x32_f16(a, b, c, 0, 0, 0);
}

// global -> LDS direct DMA, 16B per lane. lds must be wave-uniform base;
// HW writes base + lane*16. Source address is per-lane (pre-swizzled).
__device__ __forceinline__ void gld16(void* lds, const void* g){
  __builtin_amdgcn_global_load_lds(
      (const __attribute__((address_space(1))) unsigned int*)g,
      (__attribute__((address_space(3))) unsigned int*)lds,
      16, 0, 0);
}

// ---------------------------------------------------------------------------
// k_prep_g: B16[n][e] = sum_x Wk[n][x]*Wq[e][x]  (= (Wq Wk^T)^T), n<512.
// ---------------------------------------------------------------------------
__global__ __launch_bounds__(256) void k_prep_g(const float* __restrict__ Wq,
                                                const float* __restrict__ Wk,
                                                f16* __restrict__ B16){
  __shared__ float ak[32][36];
  __shared__ float aq[32][36];
  const int n0 = blockIdx.y * 32, e0 = blockIdx.x * 32;
  const int u = threadIdx.x;
  const int ty = u >> 4, tx = u & 15;
  float acc[2][2] = {};
  for (int x0 = 0; x0 < 512; x0 += 32){
    __syncthreads();
    {
      int r = u >> 3, c4 = (u & 7) * 4;
      *(float4*)&ak[r][c4] = *(const float4*)&Wk[(n0 + r) * 512 + x0 + c4];
      *(float4*)&aq[r][c4] = *(const float4*)&Wq[(e0 + r) * 512 + x0 + c4];
    }
    __syncthreads();
#pragma unroll 8
    for (int x = 0; x < 32; ++x){
      float k0 = ak[ty * 2 + 0][x], k1 = ak[ty * 2 + 1][x];
      float q0 = aq[tx * 2 + 0][x], q1 = aq[tx * 2 + 1][x];
      acc[0][0] += k0 * q0; acc[0][1] += k0 * q1;
      acc[1][0] += k1 * q0; acc[1][1] += k1 * q1;
    }
  }
#pragma unroll
  for (int i = 0; i < 2; ++i)
#pragma unroll
    for (int j = 0; j < 2; ++j)
      B16[(size_t)(n0 + ty * 2 + i) * 512 + e0 + tx * 2 + j] = (f16)acc[i][j];
}

// ---------------------------------------------------------------------------
// k_prep_wv: B16[512+d][e] = Wv[e][d]  (transpose + fp16 cast)
// ---------------------------------------------------------------------------
__global__ __launch_bounds__(256) void k_prep_wv(const float* __restrict__ Wv,
                                                 f16* __restrict__ B16){
  __shared__ float t[64][72];
  const int e0 = blockIdx.x * 64, h0 = blockIdx.y * 64;
  const int u = threadIdx.x;
#pragma unroll
  for (int k = 0; k < 4; ++k){
    int idx = u + k * 256; int r = idx >> 4, c4 = (idx & 15) * 4;
    *(float4*)&t[r][c4] = *(const float4*)&Wv[(e0 + r) * 512 + h0 + c4];
  }
  __syncthreads();
#pragma unroll
  for (int k = 0; k < 4; ++k){
    int idx = u + k * 256; int j = idx >> 4, i4 = (idx & 15) * 4;
#pragma unroll
    for (int c = 0; c < 4; ++c)
      B16[(size_t)(512 + h0 + j) * 512 + e0 + i4 + c] = (f16)t[i4 + c][j];
  }
}

// ---------------------------------------------------------------------------
// k_cast: tokens fp32 -> fp16, 8/thread.
// ---------------------------------------------------------------------------
__global__ __launch_bounds__(256) void k_cast(const float* __restrict__ tok,
                                              f16* __restrict__ T16){
  int i = blockIdx.x * 256 + threadIdx.x;
  const float4* p = (const float4*)tok + (size_t)i * 2;
  float4 a = p[0], b = p[1];
  f16x8 h;
  h[0] = (f16)a.x; h[1] = (f16)a.y; h[2] = (f16)a.z; h[3] = (f16)a.w;
  h[4] = (f16)b.x; h[5] = (f16)b.y; h[6] = (f16)b.z; h[7] = (f16)b.w;
  *((f16x8*)T16 + i) = h;
}

// ---------------------------------------------------------------------------
// k_gemm: C[t][n] = sum_e T16[t][e]*B16[n][e]; n<512 -> QG[t][n],
// n>=512 -> VT[b][d][s]. 128x128 tile, BK=64, dbuf, global_load_lds.
// ---------------------------------------------------------------------------
__global__ __launch_bounds__(256, 2) void k_gemm(const f16* __restrict__ T16,
                                                 const f16* __restrict__ B16,
                                                 f16* __restrict__ QG,
                                                 f16* __restrict__ VT){
  __shared__ __align__(16) f16 Abuf[2][128 * 64];
  __shared__ __align__(16) f16 Bbuf[2][128 * 64];
  const int tb = blockIdx.x, nb = blockIdx.y;
  const int u = threadIdx.x;
  const int w = u >> 6, l = u & 63, lr = l & 15, lq = l >> 4;
  const int lo8 = l & 7, hi8 = l >> 3;
  const int wm = (w & 1) * 64, wn = (w >> 1) * 64;
  f32x4 acc[4][4] = {};
  auto stage = [&](int c, int buf){
    const f16* sa = T16 + (size_t)tb * 128 * 512 + c * 64;
    const f16* sb = B16 + (size_t)nb * 128 * 512 + c * 64;
#pragma unroll
    for (int k = 0; k < 4; ++k){
      int i = w * 4 + k;
      int row = i * 8 + hi8;
      gld16((char*)&Abuf[buf][0] + i * 1024, sa + (size_t)row * 512 + ((lo8 ^ (row & 7)) * 8));
      gld16((char*)&Bbuf[buf][0] + i * 1024, sb + (size_t)row * 512 + ((lo8 ^ (row & 7)) * 8));
    }
  };
  stage(0, 0);
  for (int c = 0; c < 8; ++c){
    __syncthreads();
    if (c < 7) stage(c + 1, (c + 1) & 1);
    const f16* A = &Abuf[c & 1][0];
    const f16* B = &Bbuf[c & 1][0];
#pragma unroll
    for (int es = 0; es < 2; ++es){
      f16x8 af[4], bf[4];
#pragma unroll
      for (int mt = 0; mt < 4; ++mt){
        int row = wm + mt * 16 + lr;
        af[mt] = *(const f16x8*)((const char*)A + row * 128 + (((es * 4 + lq) ^ (row & 7)) << 4));
      }
#pragma unroll
      for (int nt = 0; nt < 4; ++nt){
        int row = wn + nt * 16 + lr;
        bf[nt] = *(const f16x8*)((const char*)B + row * 128 + (((es * 4 + lq) ^ (row & 7)) << 4));
      }
#pragma unroll
      for (int mt = 0; mt < 4; ++mt)
#pragma unroll
        for (int nt = 0; nt < 4; ++nt)
          acc[mt][nt] = mfma_f16(af[mt], bf[nt], acc[mt][nt]);
    }
  }
  if (nb < 4){
#pragma unroll
    for (int mt = 0; mt < 4; ++mt)
#pragma unroll
      for (int nt = 0; nt < 4; ++nt){
        int n = nb * 128 + wn + nt * 16 + lr;
        int r0 = tb * 128 + wm + mt * 16 + lq * 4;
#pragma unroll
        for (int j = 0; j < 4; ++j)
          QG[(size_t)(r0 + j) * 512 + n] = (f16)acc[mt][nt][j];
      }
  } else {
#pragma unroll
    for (int mt = 0; mt < 4; ++mt)
#pragma unroll
      for (int nt = 0; nt < 4; ++nt){
        int h = (nb - 4) * 128 + wn + nt * 16 + lr;
        int r0 = tb * 128 + wm + mt * 16 + lq * 4;
        int bq = r0 >> 11, s = r0 & 2047;
        f16x4 hv;
#pragma unroll
        for (int j = 0; j < 4; ++j) hv[j] = (f16)acc[mt][nt][j];
        *(f16x4*)&VT[(size_t)(bq * 512 + h) * 2048 + s] = hv;
      }
  }
}

// ---------------------------------------------------------------------------
// k_pass1p (v2): S-GEMM structured exactly like k_gemm (128s x 128t tile,
// BK=64, dbuf, 2 blocks/CU). Block = (b, sb 16, tb 16), grid 2048.
// After K-loop: tile-local column stats over the block's 128 t:
//   M[s,tb] (shuffle+LDS max), P' = exp2(x - M) -> fp16 Pp[b][t][s],
//   D[s,tb] = col-sum. Mp/Dp partials merged by k_scm.
// ---------------------------------------------------------------------------
__global__ __launch_bounds__(256, 2) void k_pass1p(const f16* __restrict__ T16,
                                                   const f16* __restrict__ QG,
                                                   f16* __restrict__ Pp,
                                                   float* __restrict__ Mp,
                                                   float* __restrict__ Dp){
  const int gid = blockIdx.x;
  const int b = gid & 7;
  const int sb = (gid >> 3) & 15;
  const int tb = gid >> 7;
  const int u = threadIdx.x;
  const int w = u >> 6, l = u & 63, lr = l & 15, lq = l >> 4;
  const int lo8 = l & 7, hi8 = l >> 3;
  const int wm = (w & 1) * 64, wn = (w >> 1) * 64;  // s, t within tile

  __shared__ __align__(16) f16 Abuf[2][128 * 64];  // T16 s-rows, 2*16KB
  __shared__ __align__(16) f16 Bbuf[2][128 * 64];  // QG  t-rows, 2*16KB
  __shared__ float redM[2][128];
  __shared__ float redD[2][128];

  f32x4 acc[4][4] = {};
  auto stage = [&](int c, int buf){
    const f16* sa = T16 + ((size_t)(b * 2048 + sb * 128) * 512 + c * 64);
    const f16* sb_ = QG + ((size_t)(b * 2048 + tb * 128) * 512 + c * 64);
#pragma unroll
    for (int k = 0; k < 4; ++k){
      int i = w * 4 + k;
      int row = i * 8 + hi8;
      gld16((char*)&Abuf[buf][0] + i * 1024, sa  + (size_t)row * 512 + ((lo8 ^ (row & 7)) * 8));
      gld16((char*)&Bbuf[buf][0] + i * 1024, sb_ + (size_t)row * 512 + ((lo8 ^ (row & 7)) * 8));
    }
  };
  stage(0, 0);
  for (int c = 0; c < 8; ++c){
    __syncthreads();
    if (c < 7) stage(c + 1, (c + 1) & 1);
    const f16* A = &Abuf[c & 1][0];
    const f16* B = &Bbuf[c & 1][0];
#pragma unroll
    for (int es = 0; es < 2; ++es){
      f16x8 af[4], bf[4];
#pragma unroll
      for (int mt = 0; mt < 4; ++mt){
        int row = wm + mt * 16 + lr;
        af[mt] = *(const f16x8*)((const char*)A + row * 128 + (((es * 4 + lq) ^ (row & 7)) << 4));
      }
#pragma unroll
      for (int nt = 0; nt < 4; ++nt){
        int row = wn + nt * 16 + lr;
        bf[nt] = *(const f16x8*)((const char*)B + row * 128 + (((es * 4 + lq) ^ (row & 7)) << 4));
      }
#pragma unroll
      for (int mt = 0; mt < 4; ++mt)
#pragma unroll
        for (int nt = 0; nt < 4; ++nt)
          acc[mt][nt] = mfma_f16(af[mt], bf[nt], acc[mt][nt]);
    }
  }
  // ---- epilogue: x = S*log2e; tile-local col max over the block's 128 t ----
#pragma unroll
  for (int mt = 0; mt < 4; ++mt)
#pragma unroll
    for (int nt = 0; nt < 4; ++nt)
#pragma unroll
      for (int j = 0; j < 4; ++j)
        acc[mt][nt][j] *= LOG2E;
#pragma unroll
  for (int mt = 0; mt < 4; ++mt)
#pragma unroll
    for (int j = 0; j < 4; ++j){
      float m2 = fmaxf(fmaxf(acc[mt][0][j], acc[mt][1][j]),
                       fmaxf(acc[mt][2][j], acc[mt][3][j]));
#pragma unroll
      for (int off = 1; off <= 8; off <<= 1)
        m2 = fmaxf(m2, __shfl_xor(m2, off, 64));
      if (lr == 0) redM[w >> 1][wm + mt * 16 + lq * 4 + j] = m2;
    }
  __syncthreads();
  float M[4][4];
#pragma unroll
  for (int mt = 0; mt < 4; ++mt)
#pragma unroll
    for (int j = 0; j < 4; ++j){
      int idx = wm + mt * 16 + lq * 4 + j;
      M[mt][j] = fmaxf(redM[0][idx], redM[1][idx]);
    }
  // ---- P' = exp2(x - M), store fp16, col sums ----
#pragma unroll
  for (int mt = 0; mt < 4; ++mt)
#pragma unroll
    for (int nt = 0; nt < 4; ++nt){
      int t = tb * 128 + wn + nt * 16 + lr;
      f16x4 h4;
#pragma unroll
      for (int j = 0; j < 4; ++j){
        float p = exp2f(acc[mt][nt][j] - M[mt][j]);
        acc[mt][nt][j] = p;
        h4[j] = (f16)p;
      }
      *(f16x4*)&Pp[(size_t)(b * 2048 + t) * 2048 + sb * 128 + wm + mt * 16 + lq * 4] = h4;
    }
#pragma unroll
  for (int mt = 0; mt < 4; ++mt)
#pragma unroll
    for (int j = 0; j < 4; ++j){
      float sd = acc[mt][0][j] + acc[mt][1][j] + acc[mt][2][j] + acc[mt][3][j];
#pragma unroll
      for (int off = 1; off <= 8; off <<= 1)
        sd += __shfl_xor(sd, off, 64);
      if (lr == 0) redD[w >> 1][wm + mt * 16 + lq * 4 + j] = sd;
    }
  __syncthreads();
  if (u < 128){
    int sg = b * 2048 + sb * 128 + u;
    Mp[tb * 16384 + sg] = fmaxf(redM[0][u], redM[1][u]);
    Dp[tb * 16384 + sg] = redD[0][u] + redD[1][u];
  }
}

// ---------------------------------------------------------------------------
// k_scm: merge the 16 per-tile partials -> SC[ti][s] = exp2(M-m)/denom.
// ---------------------------------------------------------------------------
__global__ __launch_bounds__(256) void k_scm(const float* __restrict__ Mp,
                                             const float* __restrict__ Dp,
                                             float* __restrict__ SC){
  int i = blockIdx.x * 256 + threadIdx.x;  // (b,s) flat, 16384
  float mv[16];
  float m = -1e30f;
#pragma unroll
  for (int ti = 0; ti < 16; ++ti){
    mv[ti] = Mp[ti * 16384 + i];
    m = fmaxf(m, mv[ti]);
  }
  float d = 0.f;
#pragma unroll
  for (int ti = 0; ti < 16; ++ti)
    d += Dp[ti * 16384 + i] * exp2f(mv[ti] - m);
  float rd = 1.0f / d;
#pragma unroll
  for (int ti = 0; ti < 16; ++ti)
    SC[ti * 16384 + i] = exp2f(mv[ti] - m) * rd;
}

// ---------------------------------------------------------------------------
// k_pass2p: PV only. block = (b, t-tile 64, h-half 256), 256 threads, grid 512.
// Per si (256 s): stage P' tile (64t x 256s) + sc row, scale Pl in place,
// then 8 V-steps (256h x 32s chunks, dbuf). acc over all si; fp32 store.
// LDS 65KB -> 2 blocks/CU.  (ti = tt>>1: stats tiles are 128 t wide now)
// ---------------------------------------------------------------------------
__global__ __launch_bounds__(256, 2) void k_pass2p(const f16* __restrict__ Pp,
                                                   const f16* __restrict__ VT,
                                                   const float* __restrict__ SC,
                                                   float* __restrict__ out){
  const int gid = blockIdx.x;
  const int b = gid & 7;
  const int tt = (gid >> 3) & 31;
  const int hh = gid >> 8;
  const int t0 = tt * 64;
  const int ti = tt >> 1;
  const int u = threadIdx.x;
  const int w = u >> 6, l = u & 63, lr = l & 15, lq = l >> 4;

  __shared__ __align__(16) f16 Pl[64 * 256];     // 32KB, rows 512B, swizzled
  __shared__ __align__(16) f16 Vt[2][256 * 32];  // 2*16KB, rows 64B, swizzled
  __shared__ float scl[256];                      // 1KB

  f32x4 acc[4][4] = {};

  auto stagePl = [&](int si){
#pragma unroll
    for (int k = 0; k < 8; ++k){
      int i = w * 8 + k;
      int row = i * 2 + (l >> 5);
      int slot = l & 31;
      gld16((char*)Pl + i * 1024,
            Pp + ((size_t)(b * 2048 + t0 + row) * 2048 + si * 256 + ((slot ^ (row & 7)) * 8)));
    }
  };
  auto stageV = [&](int si, int sc_, int buf){
#pragma unroll
    for (int k = 0; k < 4; ++k){
      int i = w * 4 + k;
      int row = i * 16 + (l >> 2);
      gld16((char*)&Vt[buf][0] + i * 1024,
            VT + ((size_t)(b * 512 + hh * 256 + row) * 2048 + si * 256 + sc_ * 32 + (((l & 3) ^ (row & 3)) * 8)));
    }
  };

  for (int si = 0; si < 8; ++si){
    __syncthreads(); // prior PV reads of Pl done
    stagePl(si);
    if (w == 0) gld16(scl, SC + ti * 16384 + b * 2048 + si * 256 + l * 4);
    __syncthreads(); // Pl + scl landed (compiler drains vmcnt before barrier)
    { // scale Pl in place: thread owns row u>>2, slots (u&3)*8 .. +7
      int row = u >> 2;
#pragma unroll
      for (int k = 0; k < 8; ++k){
        int slot = (u & 3) * 8 + k;
        f16* p = (f16*)((char*)Pl + row * 512 + ((slot ^ (row & 7)) << 4));
        f16x8 v = *(f16x8*)p;
#pragma unroll
        for (int e = 0; e < 8; ++e)
          v[e] = (f16)((float)v[e] * scl[slot * 8 + e]);
        *(f16x8*)p = v;
      }
    }
    stageV(si, 0, 0);
    __syncthreads(); // scaled Pl visible + V chunk 0 landed
#pragma unroll
    for (int sc_ = 0; sc_ < 8; ++sc_){
      if (sc_ < 7) stageV(si, sc_ + 1, (sc_ + 1) & 1);
      const f16* V = &Vt[sc_ & 1][0];
      f16x8 vf[4], pf[4];
#pragma unroll
      for (int ht = 0; ht < 4; ++ht){
        int row = w * 64 + ht * 16 + lr;
        vf[ht] = *(const f16x8*)((const char*)V + row * 64 + ((lq ^ (row & 3)) << 4));
      }
#pragma unroll
      for (int nt = 0; nt < 4; ++nt){
        int row = nt * 16 + lr;
        pf[nt] = *(const f16x8*)((const char*)Pl + row * 512 + (((sc_ * 4 + lq) ^ (row & 7)) << 4));
      }
#pragma unroll
      for (int ht = 0; ht < 4; ++ht)
#pragma unroll
        for (int nt = 0; nt < 4; ++nt)
          acc[ht][nt] = mfma_f16(vf[ht], pf[nt], acc[ht][nt]);
      __syncthreads(); // V[buf^1] landed for next step; reads of V[buf] done
    }
  }
  // epilogue: h = hh*256 + w*64 + ht*16 + lq*4 (+j), t = t0 + nt*16 + lr
#pragma unroll
  for (int ht = 0; ht < 4; ++ht)
#pragma unroll
    for (int nt = 0; nt < 4; ++nt){
      int t = t0 + nt * 16 + lr;
      int h = hh * 256 + w * 64 + ht * 16 + lq * 4;
      float4 v;
      v.x = acc[ht][nt][0]; v.y = acc[ht][nt][1];
      v.z = acc[ht][nt][2]; v.w = acc[ht][nt][3];
      *(float4*)&out[(size_t)(b * 2048 + t) * 512 + h] = v;
    }
}

// ===========================================================================
// FALLBACK PATH (validated round-3 kernels) — used when ws is too small.
// ===========================================================================
__global__ __launch_bounds__(512, 2) void k_pass1(const f16* __restrict__ T16,
                                                  const f16* __restrict__ QG,
                                                  float2* __restrict__ MR){
  const int gid = blockIdx.x;
  const int b = gid & 7;
  const int sb = gid >> 3;
  const int s0 = sb * 64;
  const int u = threadIdx.x;
  const int w = u >> 6, l = u & 63, lr = l & 15, lq = l >> 4;
  const int lo8 = l & 7, hi8 = l >> 3;

  __shared__ __align__(16) f16 At[64 * 512];
  __shared__ __align__(16) f16 Bbuf[2][256 * 64];
  __shared__ float2 red[8 * 64];

  {
    const f16* src = T16 + (size_t)(b * 2048 + s0) * 512;
#pragma unroll
    for (int k = 0; k < 8; ++k){
      int row = w * 8 + k;
      gld16((char*)At + row * 1024, src + (size_t)row * 512 + ((l ^ (row & 7)) * 8));
    }
  }
  auto stageB = [&](int ti, int c, int buf){
    const f16* src = QG + ((size_t)(b * 2048 + ti * 256) * 512 + c * 64);
#pragma unroll
    for (int k = 0; k < 4; ++k){
      int i = w * 4 + k;
      int row = i * 8 + hi8;
      gld16((char*)&Bbuf[buf][0] + i * 1024, src + (size_t)row * 512 + ((lo8 ^ (row & 7)) * 8));
    }
  };
  stageB(0, 0, 0);

  float m_[4][4], d_[4][4];
#pragma unroll
  for (int i = 0; i < 4; ++i)
#pragma unroll
    for (int j = 0; j < 4; ++j){ m_[i][j] = -1e30f; d_[i][j] = 0.f; }

  for (int ti = 0; ti < 8; ++ti){
    f32x4 sacc[4][2] = {};
    for (int c = 0; c < 8; ++c){
      __syncthreads();
      int n = ti * 8 + c + 1;
      if (n < 64) stageB(n >> 3, n & 7, n & 1);
      const f16* B = &Bbuf[(ti * 8 + c) & 1][0];
#pragma unroll
      for (int es = 0; es < 2; ++es){
        f16x8 af[4], bf[2];
#pragma unroll
        for (int mt = 0; mt < 4; ++mt){
          int row = mt * 16 + lr;
          int slot = c * 8 + es * 4 + lq;
          af[mt] = *(const f16x8*)((const char*)At + row * 1024 + ((slot ^ (row & 7)) << 4));
        }
#pragma unroll
        for (int nt = 0; nt < 2; ++nt){
          int row = w * 32 + nt * 16 + lr;
          bf[nt] = *(const f16x8*)((const char*)B + row * 128 + (((es * 4 + lq) ^ (row & 7)) << 4));
        }
#pragma unroll
        for (int mt = 0; mt < 4; ++mt)
#pragma unroll
          for (int nt = 0; nt < 2; ++nt)
            sacc[mt][nt] = mfma_f16(af[mt], bf[nt], sacc[mt][nt]);
      }
    }
#pragma unroll
    for (int mt = 0; mt < 4; ++mt)
#pragma unroll
      for (int nt = 0; nt < 2; ++nt)
#pragma unroll
        for (int j = 0; j < 4; ++j){
          float x = sacc[mt][nt][j] * LOG2E;
          float nm = fmaxf(m_[mt][j], x);
          d_[mt][j] = d_[mt][j] * exp2f(m_[mt][j] - nm) + exp2f(x - nm);
          m_[mt][j] = nm;
        }
  }
#pragma unroll
  for (int mt = 0; mt < 4; ++mt)
#pragma unroll
    for (int j = 0; j < 4; ++j){
      float m = m_[mt][j], d = d_[mt][j];
#pragma unroll
      for (int off = 1; off <= 8; off <<= 1){
        float om = __shfl_xor(m, off, 64);
        float od = __shfl_xor(d, off, 64);
        float nm = fmaxf(m, om);
        d = d * exp2f(m - nm) + od * exp2f(om - nm);
        m = nm;
      }
      m_[mt][j] = m; d_[mt][j] = d;
    }
  __syncthreads();
  if (lr == 0){
#pragma unroll
    for (int mt = 0; mt < 4; ++mt)
#pragma unroll
      for (int j = 0; j < 4; ++j)
        red[w * 64 + mt * 16 + lq * 4 + j] = make_float2(m_[mt][j], d_[mt][j]);
  }
  __syncthreads();
  if (u < 64){
    float2 v = red[u];
    float m = v.x, d = v.y;
#pragma unroll
    for (int g = 1; g < 8; ++g){
      float2 o = red[g * 64 + u];
      float nm = fmaxf(m, o.x);
      d = d * exp2f(m - nm) + o.y * exp2f(o.x - nm);
      m = nm;
    }
    MR[b * 2048 + s0 + u] = make_float2(m, 1.0f / d);
  }
}

__global__ __launch_bounds__(512, 2) void k_pass2(const f16* __restrict__ T16,
                                                  const f16* __restrict__ QG,
                                                  const f16* __restrict__ VT,
                                                  const float2* __restrict__ MR,
                                                  float* __restrict__ out){
  const int gid = blockIdx.x;
  const int b = gid & 7;
  const int tb = gid >> 3;
  const int t0 = tb * 64;
  const int u = threadIdx.x;
  const int w = u >> 6, l = u & 63, lr = l & 15, lq = l >> 4;
  const int lo8 = l & 7, hi8 = l >> 3;
  const int ws = w >> 1, wt = w & 1;
  const int ph = w >> 1, pt = w & 1;

  __shared__ __align__(16) f16 Abuf[2][256 * 64];
  __shared__ __align__(16) f16 Bbuf[2][64 * 64];
  __shared__ __align__(16) f16 Pl[64 * 256];
  __shared__ __align__(16) f16 Vbuf[2][128 * 64];

  f32x4 acc[4][2][2] = {};

  auto stageA = [&](int si, int c, int buf){
    const f16* src = T16 + ((size_t)(b * 2048 + si * 256) * 512 + c * 64);
#pragma unroll
    for (int k = 0; k < 4; ++k){
      int i = w * 4 + k;
      int row = i * 8 + hi8;
      gld16((char*)&Abuf[buf][0] + i * 1024, src + (size_t)row * 512 + ((lo8 ^ (row & 7)) * 8));
    }
  };
  auto stageB = [&](int c, int buf){
    const f16* src = QG + ((size_t)(b * 2048 + t0) * 512 + c * 64);
    int row = w * 8 + hi8;
    gld16((char*)&Bbuf[buf][0] + w * 1024, src + (size_t)row * 512 + ((lo8 ^ (row & 7)) * 8));
  };
  auto stageV = [&](int si, int hc, int sc, int buf){
    const f16* src = VT + ((size_t)(b * 512 + hc * 128) * 2048 + si * 256 + sc * 64);
#pragma unroll
    for (int k = 0; k < 2; ++k){
      int i = w * 2 + k;
      int row = i * 8 + hi8;
      gld16((char*)&Vbuf[buf][0] + i * 1024, src + (size_t)row * 2048 + ((lo8 ^ (row & 7)) * 8));
    }
  };

  stageA(0, 0, 0);
  stageB(0, 0);

  for (int si = 0; si < 8; ++si){
    f32x4 sacc[4][2] = {};
    for (int c = 0; c < 8; ++c){
      __syncthreads();
      if (c < 7){
        stageA(si, c + 1, (c + 1) & 1);
        stageB(c + 1, (c + 1) & 1);
      } else {
        stageV(si, 0, 0, 0);
      }
      const f16* A = &Abuf[c & 1][0];
      const f16* B = &Bbuf[c & 1][0];
#pragma unroll
      for (int es = 0; es < 2; ++es){
        f16x8 af[4], bf[2];
#pragma unroll
        for (int mt = 0; mt < 4; ++mt){
          int row = ws * 64 + mt * 16 + lr;
          af[mt] = *(const f16x8*)((const char*)A + row * 128 + (((es * 4 + lq) ^ (row & 7)) << 4));
        }
#pragma unroll
        for (int nt = 0; nt < 2; ++nt){
          int row = wt * 32 + nt * 16 + lr;
          bf[nt] = *(const f16x8*)((const char*)B + row * 128 + (((es * 4 + lq) ^ (row & 7)) << 4));
        }
#pragma unroll
        for (int mt = 0; mt < 4; ++mt)
#pragma unroll
          for (int nt = 0; nt < 2; ++nt)
            sacc[mt][nt] = mfma_f16(af[mt], bf[nt], sacc[mt][nt]);
      }
    }
    {
      float2 mr[4][4];
#pragma unroll
      for (int mt = 0; mt < 4; ++mt)
#pragma unroll
        for (int j = 0; j < 4; ++j)
          mr[mt][j] = MR[b * 2048 + si * 256 + ws * 64 + mt * 16 + lq * 4 + j];
#pragma unroll
      for (int mt = 0; mt < 4; ++mt)
#pragma unroll
        for (int nt = 0; nt < 2; ++nt){
          int t = wt * 32 + nt * 16 + lr;
          f16x4 pv;
#pragma unroll
          for (int j = 0; j < 4; ++j){
            float x = fminf(sacc[mt][nt][j] * LOG2E - mr[mt][j].x, 0.0f);
            pv[j] = (f16)(exp2f(x) * mr[mt][j].y);
          }
          int slot = ws * 8 + mt * 2 + (lq >> 1);
          int off = t * 512 + ((slot ^ (t & 7)) << 4) + (lq & 1) * 8;
          *(f16x4*)((char*)Pl + off) = pv;
        }
    }
#pragma unroll
    for (int hc = 0; hc < 4; ++hc){
#pragma unroll
      for (int sc = 0; sc < 4; ++sc){
        const int step = hc * 4 + sc;
        __syncthreads();
        if (step < 15) stageV(si, (step + 1) >> 2, (step + 1) & 3, (step + 1) & 1);
        else if (si < 7){ stageA(si + 1, 0, 0); stageB(0, 0); }
        const f16* V = &Vbuf[step & 1][0];
#pragma unroll
        for (int es = 0; es < 2; ++es){
          f16x8 vf[2], pf[2];
#pragma unroll
          for (int ht = 0; ht < 2; ++ht){
            int row = ph * 32 + ht * 16 + lr;
            vf[ht] = *(const f16x8*)((const char*)V + row * 128 + (((es * 4 + lq) ^ (row & 7)) << 4));
          }
#pragma unroll
          for (int nt = 0; nt < 2; ++nt){
            int row = pt * 32 + nt * 16 + lr;
            int slot = sc * 8 + es * 4 + lq;
            pf[nt] = *(const f16x8*)((const char*)Pl + row * 512 + ((slot ^ (row & 7)) << 4));
          }
#pragma unroll
          for (int ht = 0; ht < 2; ++ht)
#pragma unroll
            for (int nt = 0; nt < 2; ++nt)
              acc[hc][ht][nt] = mfma_f16(vf[ht], pf[nt], acc[hc][ht][nt]);
        }
      }
    }
  }
#pragma unroll
  for (int hc = 0; hc < 4; ++hc)
#pragma unroll
    for (int ht = 0; ht < 2; ++ht)
#pragma unroll
      for (int nt = 0; nt < 2; ++nt){
        int t = t0 + pt * 32 + nt * 16 + lr;
        int h = hc * 128 + ph * 32 + ht * 16 + lq * 4;
        float4 v;
        v.x = acc[hc][ht][nt][0]; v.y = acc[hc][ht][nt][1];
        v.z = acc[hc][ht][nt][2]; v.w = acc[hc][ht][nt][3];
        *(float4*)&out[(size_t)(b * 2048 + t) * 512 + h] = v;
      }
}

// ---------------------------------------------------------------------------
extern "C" void kernel_launch(void* const* d_in, const int* in_sizes, int n_in,
                              void* d_out, int out_size, void* d_ws, size_t ws_size,
                              hipStream_t stream){
  (void)in_sizes; (void)n_in; (void)out_size;
  const float* tokens = (const float*)d_in[0];
  const float* Wq = (const float*)d_in[1];
  const float* Wk = (const float*)d_in[2];
  const float* Wv = (const float*)d_in[3];
  char* ws = (char*)d_ws;
  f16*    T16 = (f16*)(ws);                        // [0, 16M)
  f16*    QG  = (f16*)(ws + (16u << 20));          // [16M, 32M)
  f16*    VT  = (f16*)(ws + (32u << 20));          // [32M, 48M)
  f16*    B16 = (f16*)(ws + (48u << 20));          // [48M, 49M)
  float2* MR  = (float2*)(ws + (49u << 20));       // [49M, 49.2M) (fallback)
  float*  SC  = (float*)(ws + (50u << 20));        // [50M, 51M)
  float*  Mp  = (float*)(ws + (51u << 20));        // [51M, 52M)
  float*  Dp  = (float*)(ws + (52u << 20));        // [52M, 53M)
  f16*    Pp  = (f16*)(ws + (54u << 20));          // [54M, 118M)
  float* out = (float*)d_out;

  const size_t NEED = (size_t)118u << 20;

  k_prep_g <<<dim3(16, 16), dim3(256), 0, stream>>>(Wq, Wk, B16);
  k_prep_wv<<<dim3(8, 8),   dim3(256), 0, stream>>>(Wv, B16);
  k_cast   <<<dim3(4096),   dim3(256), 0, stream>>>(tokens, T16);
  k_gemm   <<<dim3(128, 8), dim3(256), 0, stream>>>(T16, B16, QG, VT);
  if (ws_size >= NEED){
    k_pass1p<<<dim3(2048), dim3(256), 0, stream>>>(T16, QG, Pp, Mp, Dp);
    k_scm   <<<dim3(64),   dim3(256), 0, stream>>>(Mp, Dp, SC);
    k_pass2p<<<dim3(512),  dim3(256), 0, stream>>>(Pp, VT, SC, out);
  } else {
    k_pass1 <<<dim3(256), dim3(512), 0, stream>>>(T16, QG, MR);
    k_pass2 <<<dim3(256), dim3(512), 0, stream>>>(T16, QG, VT, MR, out);
  }
}

// Round 6
// 196.261 us; speedup vs baseline: 1.8186x; 1.0248x over previous
//
#include <hip/hip_runtime.h>

typedef _Float16 f16;
typedef _Float16 f16x8 __attribute__((ext_vector_type(8)));
typedef _Float16 f16x4 __attribute__((ext_vector_type(4)));
typedef float   f32x4 __attribute__((ext_vector_type(4)));

#define LOG2E 1.44269504088896340736f

__device__ __forceinline__ f32x4 mfma_f16(f16x8 a, f16x8 b, f32x4 c){
  return __builtin_amdgcn_mfma_f32_16x16x32_f16(a, b, c, 0, 0, 0);
}
__device__ __forceinline__ float fexp2(float x){ return __builtin_amdgcn_exp2f(x); }

// global -> LDS direct DMA, 16B per lane. lds must be wave-uniform base;
// HW writes base + lane*16. Source address is per-lane (pre-swizzled).
__device__ __forceinline__ void gld16(void* lds, const void* g){
  __builtin_amdgcn_global_load_lds(
      (const __attribute__((address_space(1))) unsigned int*)g,
      (__attribute__((address_space(3))) unsigned int*)lds,
      16, 0, 0);
}

// ---------------------------------------------------------------------------
// k_prep_g: B16[n][e] = sum_x Wk[n][x]*Wq[e][x]  (= (Wq Wk^T)^T), n<512.
// ---------------------------------------------------------------------------
__global__ __launch_bounds__(256) void k_prep_g(const float* __restrict__ Wq,
                                                const float* __restrict__ Wk,
                                                f16* __restrict__ B16){
  __shared__ float ak[32][36];
  __shared__ float aq[32][36];
  const int n0 = blockIdx.y * 32, e0 = blockIdx.x * 32;
  const int u = threadIdx.x;
  const int ty = u >> 4, tx = u & 15;
  float acc[2][2] = {};
  for (int x0 = 0; x0 < 512; x0 += 32){
    __syncthreads();
    {
      int r = u >> 3, c4 = (u & 7) * 4;
      *(float4*)&ak[r][c4] = *(const float4*)&Wk[(n0 + r) * 512 + x0 + c4];
      *(float4*)&aq[r][c4] = *(const float4*)&Wq[(e0 + r) * 512 + x0 + c4];
    }
    __syncthreads();
#pragma unroll 8
    for (int x = 0; x < 32; ++x){
      float k0 = ak[ty * 2 + 0][x], k1 = ak[ty * 2 + 1][x];
      float q0 = aq[tx * 2 + 0][x], q1 = aq[tx * 2 + 1][x];
      acc[0][0] += k0 * q0; acc[0][1] += k0 * q1;
      acc[1][0] += k1 * q0; acc[1][1] += k1 * q1;
    }
  }
#pragma unroll
  for (int i = 0; i < 2; ++i)
#pragma unroll
    for (int j = 0; j < 2; ++j)
      B16[(size_t)(n0 + ty * 2 + i) * 512 + e0 + tx * 2 + j] = (f16)acc[i][j];
}

// ---------------------------------------------------------------------------
// k_prep_wv: B16[512+d][e] = Wv[e][d]  (transpose + fp16 cast)
// ---------------------------------------------------------------------------
__global__ __launch_bounds__(256) void k_prep_wv(const float* __restrict__ Wv,
                                                 f16* __restrict__ B16){
  __shared__ float t[64][72];
  const int e0 = blockIdx.x * 64, h0 = blockIdx.y * 64;
  const int u = threadIdx.x;
#pragma unroll
  for (int k = 0; k < 4; ++k){
    int idx = u + k * 256; int r = idx >> 4, c4 = (idx & 15) * 4;
    *(float4*)&t[r][c4] = *(const float4*)&Wv[(e0 + r) * 512 + h0 + c4];
  }
  __syncthreads();
#pragma unroll
  for (int k = 0; k < 4; ++k){
    int idx = u + k * 256; int j = idx >> 4, i4 = (idx & 15) * 4;
#pragma unroll
    for (int c = 0; c < 4; ++c)
      B16[(size_t)(512 + h0 + j) * 512 + e0 + i4 + c] = (f16)t[i4 + c][j];
  }
}

// ---------------------------------------------------------------------------
// k_cast: tokens fp32 -> fp16, 8/thread.
// ---------------------------------------------------------------------------
__global__ __launch_bounds__(256) void k_cast(const float* __restrict__ tok,
                                              f16* __restrict__ T16){
  int i = blockIdx.x * 256 + threadIdx.x;
  const float4* p = (const float4*)tok + (size_t)i * 2;
  float4 a = p[0], b = p[1];
  f16x8 h;
  h[0] = (f16)a.x; h[1] = (f16)a.y; h[2] = (f16)a.z; h[3] = (f16)a.w;
  h[4] = (f16)b.x; h[5] = (f16)b.y; h[6] = (f16)b.z; h[7] = (f16)b.w;
  *((f16x8*)T16 + i) = h;
}

// ---------------------------------------------------------------------------
// k_gemm: C[t][n] = sum_e T16[t][e]*B16[n][e]; n<512 -> QG[t][n],
// n>=512 -> VT[b][d][s]. 128x128 tile, BK=32 (32KB LDS -> 4+ blocks/CU).
// ---------------------------------------------------------------------------
__global__ __launch_bounds__(256, 4) void k_gemm(const f16* __restrict__ T16,
                                                 const f16* __restrict__ B16,
                                                 f16* __restrict__ QG,
                                                 f16* __restrict__ VT){
  __shared__ __align__(16) f16 Abuf[2][128 * 32];  // 2*8KB
  __shared__ __align__(16) f16 Bbuf[2][128 * 32];  // 2*8KB
  const int tb = blockIdx.x, nb = blockIdx.y;
  const int u = threadIdx.x;
  const int w = u >> 6, l = u & 63, lr = l & 15, lq = l >> 4;
  const int l2 = l & 3, hi4 = l >> 2;
  const int wm = (w & 1) * 64, wn = (w >> 1) * 64;
  f32x4 acc[4][4] = {};
  auto stage = [&](int c, int buf){
    const f16* sa = T16 + (size_t)tb * 128 * 512 + c * 32;
    const f16* sb = B16 + (size_t)nb * 128 * 512 + c * 32;
#pragma unroll
    for (int k = 0; k < 2; ++k){
      int i = w * 2 + k;
      int row = i * 16 + hi4;
      gld16((char*)&Abuf[buf][0] + i * 1024, sa + (size_t)row * 512 + ((l2 ^ (row & 3)) * 8));
      gld16((char*)&Bbuf[buf][0] + i * 1024, sb + (size_t)row * 512 + ((l2 ^ (row & 3)) * 8));
    }
  };
  stage(0, 0);
  for (int c = 0; c < 16; ++c){
    __syncthreads();
    if (c < 15) stage(c + 1, (c + 1) & 1);
    const f16* A = &Abuf[c & 1][0];
    const f16* B = &Bbuf[c & 1][0];
    f16x8 af[4], bf[4];
#pragma unroll
    for (int mt = 0; mt < 4; ++mt){
      int row = wm + mt * 16 + lr;
      af[mt] = *(const f16x8*)((const char*)A + row * 64 + ((lq ^ (row & 3)) << 4));
    }
#pragma unroll
    for (int nt = 0; nt < 4; ++nt){
      int row = wn + nt * 16 + lr;
      bf[nt] = *(const f16x8*)((const char*)B + row * 64 + ((lq ^ (row & 3)) << 4));
    }
#pragma unroll
    for (int mt = 0; mt < 4; ++mt)
#pragma unroll
      for (int nt = 0; nt < 4; ++nt)
        acc[mt][nt] = mfma_f16(af[mt], bf[nt], acc[mt][nt]);
  }
  if (nb < 4){
#pragma unroll
    for (int mt = 0; mt < 4; ++mt)
#pragma unroll
      for (int nt = 0; nt < 4; ++nt){
        int n = nb * 128 + wn + nt * 16 + lr;
        int r0 = tb * 128 + wm + mt * 16 + lq * 4;
#pragma unroll
        for (int j = 0; j < 4; ++j)
          QG[(size_t)(r0 + j) * 512 + n] = (f16)acc[mt][nt][j];
      }
  } else {
#pragma unroll
    for (int mt = 0; mt < 4; ++mt)
#pragma unroll
      for (int nt = 0; nt < 4; ++nt){
        int h = (nb - 4) * 128 + wn + nt * 16 + lr;
        int r0 = tb * 128 + wm + mt * 16 + lq * 4;
        int bq = r0 >> 11, s = r0 & 2047;
        f16x4 hv;
#pragma unroll
        for (int j = 0; j < 4; ++j) hv[j] = (f16)acc[mt][nt][j];
        *(f16x4*)&VT[(size_t)(bq * 512 + h) * 2048 + s] = hv;
      }
  }
}

// ---------------------------------------------------------------------------
// k_pass1p: S-GEMM 128s x 128t tile, BK=32, dbuf (32KB LDS -> 4 blocks/CU).
// Block = (b, sb 16, tb 16), grid 2048. Epilogue: tile-local col stats over
// the block's 128 t: M -> P' = exp2(x-M) fp16 store, D = col-sum.
// ---------------------------------------------------------------------------
__global__ __launch_bounds__(256, 4) void k_pass1p(const f16* __restrict__ T16,
                                                   const f16* __restrict__ QG,
                                                   f16* __restrict__ Pp,
                                                   float* __restrict__ Mp,
                                                   float* __restrict__ Dp){
  const int gid = blockIdx.x;
  const int b = gid & 7;
  const int sb = (gid >> 3) & 15;
  const int tb = gid >> 7;
  const int u = threadIdx.x;
  const int w = u >> 6, l = u & 63, lr = l & 15, lq = l >> 4;
  const int l2 = l & 3, hi4 = l >> 2;
  const int wm = (w & 1) * 64, wn = (w >> 1) * 64;  // s, t within tile

  __shared__ __align__(16) f16 Abuf[2][128 * 32];  // T16 s-rows, 2*8KB
  __shared__ __align__(16) f16 Bbuf[2][128 * 32];  // QG  t-rows, 2*8KB
  __shared__ float redM[2][128];
  __shared__ float redD[2][128];

  f32x4 acc[4][4] = {};
  auto stage = [&](int c, int buf){
    const f16* sa = T16 + ((size_t)(b * 2048 + sb * 128) * 512 + c * 32);
    const f16* sb_ = QG + ((size_t)(b * 2048 + tb * 128) * 512 + c * 32);
#pragma unroll
    for (int k = 0; k < 2; ++k){
      int i = w * 2 + k;
      int row = i * 16 + hi4;
      gld16((char*)&Abuf[buf][0] + i * 1024, sa  + (size_t)row * 512 + ((l2 ^ (row & 3)) * 8));
      gld16((char*)&Bbuf[buf][0] + i * 1024, sb_ + (size_t)row * 512 + ((l2 ^ (row & 3)) * 8));
    }
  };
  stage(0, 0);
  for (int c = 0; c < 16; ++c){
    __syncthreads();
    if (c < 15) stage(c + 1, (c + 1) & 1);
    const f16* A = &Abuf[c & 1][0];
    const f16* B = &Bbuf[c & 1][0];
    f16x8 af[4], bf[4];
#pragma unroll
    for (int mt = 0; mt < 4; ++mt){
      int row = wm + mt * 16 + lr;
      af[mt] = *(const f16x8*)((const char*)A + row * 64 + ((lq ^ (row & 3)) << 4));
    }
#pragma unroll
    for (int nt = 0; nt < 4; ++nt){
      int row = wn + nt * 16 + lr;
      bf[nt] = *(const f16x8*)((const char*)B + row * 64 + ((lq ^ (row & 3)) << 4));
    }
#pragma unroll
    for (int mt = 0; mt < 4; ++mt)
#pragma unroll
      for (int nt = 0; nt < 4; ++nt)
        acc[mt][nt] = mfma_f16(af[mt], bf[nt], acc[mt][nt]);
  }
  // ---- epilogue: x = S*log2e; tile-local col max over the block's 128 t ----
#pragma unroll
  for (int mt = 0; mt < 4; ++mt)
#pragma unroll
    for (int nt = 0; nt < 4; ++nt)
#pragma unroll
      for (int j = 0; j < 4; ++j)
        acc[mt][nt][j] *= LOG2E;
#pragma unroll
  for (int mt = 0; mt < 4; ++mt)
#pragma unroll
    for (int j = 0; j < 4; ++j){
      float m2 = fmaxf(fmaxf(acc[mt][0][j], acc[mt][1][j]),
                       fmaxf(acc[mt][2][j], acc[mt][3][j]));
#pragma unroll
      for (int off = 1; off <= 8; off <<= 1)
        m2 = fmaxf(m2, __shfl_xor(m2, off, 64));
      if (lr == 0) redM[w >> 1][wm + mt * 16 + lq * 4 + j] = m2;
    }
  __syncthreads();
  float M[4][4];
#pragma unroll
  for (int mt = 0; mt < 4; ++mt)
#pragma unroll
    for (int j = 0; j < 4; ++j){
      int idx = wm + mt * 16 + lq * 4 + j;
      M[mt][j] = fmaxf(redM[0][idx], redM[1][idx]);
    }
  // ---- P' = exp2(x - M), store fp16, col sums ----
#pragma unroll
  for (int mt = 0; mt < 4; ++mt)
#pragma unroll
    for (int nt = 0; nt < 4; ++nt){
      int t = tb * 128 + wn + nt * 16 + lr;
      f16x4 h4;
#pragma unroll
      for (int j = 0; j < 4; ++j){
        float p = fexp2(acc[mt][nt][j] - M[mt][j]);
        acc[mt][nt][j] = p;
        h4[j] = (f16)p;
      }
      *(f16x4*)&Pp[(size_t)(b * 2048 + t) * 2048 + sb * 128 + wm + mt * 16 + lq * 4] = h4;
    }
#pragma unroll
  for (int mt = 0; mt < 4; ++mt)
#pragma unroll
    for (int j = 0; j < 4; ++j){
      float sd = acc[mt][0][j] + acc[mt][1][j] + acc[mt][2][j] + acc[mt][3][j];
#pragma unroll
      for (int off = 1; off <= 8; off <<= 1)
        sd += __shfl_xor(sd, off, 64);
      if (lr == 0) redD[w >> 1][wm + mt * 16 + lq * 4 + j] = sd;
    }
  __syncthreads();
  if (u < 128){
    int sg = b * 2048 + sb * 128 + u;
    Mp[tb * 16384 + sg] = fmaxf(redM[0][u], redM[1][u]);
    Dp[tb * 16384 + sg] = redD[0][u] + redD[1][u];
  }
}

// ---------------------------------------------------------------------------
// k_scm: merge the 16 per-tile partials -> SC[ti][s] = exp2(M-m)/denom.
// ---------------------------------------------------------------------------
__global__ __launch_bounds__(256) void k_scm(const float* __restrict__ Mp,
                                             const float* __restrict__ Dp,
                                             float* __restrict__ SC){
  int i = blockIdx.x * 256 + threadIdx.x;  // (b,s) flat, 16384
  float mv[16];
  float m = -1e30f;
#pragma unroll
  for (int ti = 0; ti < 16; ++ti){
    mv[ti] = Mp[ti * 16384 + i];
    m = fmaxf(m, mv[ti]);
  }
  float d = 0.f;
#pragma unroll
  for (int ti = 0; ti < 16; ++ti)
    d += Dp[ti * 16384 + i] * fexp2(mv[ti] - m);
  float rd = 1.0f / d;
#pragma unroll
  for (int ti = 0; ti < 16; ++ti)
    SC[ti * 16384 + i] = fexp2(mv[ti] - m) * rd;
}

// ---------------------------------------------------------------------------
// k_pass2p: PV only. block = (b, t-tile 64, h-half 256), 256 threads, grid 512.
// Per si (256 s): stage P' tile (64t x 256s) + sc row, scale Pl in place,
// then 8 V-steps (256h x 32s chunks, dbuf). acc over all si; fp32 store.
// LDS 65KB -> 2 blocks/CU.  (ti = tt>>1: stats tiles are 128 t wide)
// ---------------------------------------------------------------------------
__global__ __launch_bounds__(256, 2) void k_pass2p(const f16* __restrict__ Pp,
                                                   const f16* __restrict__ VT,
                                                   const float* __restrict__ SC,
                                                   float* __restrict__ out){
  const int gid = blockIdx.x;
  const int b = gid & 7;
  const int tt = (gid >> 3) & 31;
  const int hh = gid >> 8;
  const int t0 = tt * 64;
  const int ti = tt >> 1;
  const int u = threadIdx.x;
  const int w = u >> 6, l = u & 63, lr = l & 15, lq = l >> 4;

  __shared__ __align__(16) f16 Pl[64 * 256];     // 32KB, rows 512B, swizzled
  __shared__ __align__(16) f16 Vt[2][256 * 32];  // 2*16KB, rows 64B, swizzled
  __shared__ float scl[256];                      // 1KB

  f32x4 acc[4][4] = {};

  auto stagePl = [&](int si){
#pragma unroll
    for (int k = 0; k < 8; ++k){
      int i = w * 8 + k;
      int row = i * 2 + (l >> 5);
      int slot = l & 31;
      gld16((char*)Pl + i * 1024,
            Pp + ((size_t)(b * 2048 + t0 + row) * 2048 + si * 256 + ((slot ^ (row & 7)) * 8)));
    }
  };
  auto stageV = [&](int si, int sc_, int buf){
#pragma unroll
    for (int k = 0; k < 4; ++k){
      int i = w * 4 + k;
      int row = i * 16 + (l >> 2);
      gld16((char*)&Vt[buf][0] + i * 1024,
            VT + ((size_t)(b * 512 + hh * 256 + row) * 2048 + si * 256 + sc_ * 32 + (((l & 3) ^ (row & 3)) * 8)));
    }
  };

  for (int si = 0; si < 8; ++si){
    __syncthreads(); // prior PV reads of Pl done
    stagePl(si);
    if (w == 0) gld16(scl, SC + ti * 16384 + b * 2048 + si * 256 + l * 4);
    __syncthreads(); // Pl + scl landed (compiler drains vmcnt before barrier)
    { // scale Pl in place: thread owns row u>>2, slots (u&3)*8 .. +7
      int row = u >> 2;
#pragma unroll
      for (int k = 0; k < 8; ++k){
        int slot = (u & 3) * 8 + k;
        f16* p = (f16*)((char*)Pl + row * 512 + ((slot ^ (row & 7)) << 4));
        f16x8 v = *(f16x8*)p;
#pragma unroll
        for (int e = 0; e < 8; ++e)
          v[e] = (f16)((float)v[e] * scl[slot * 8 + e]);
        *(f16x8*)p = v;
      }
    }
    stageV(si, 0, 0);
    __syncthreads(); // scaled Pl visible + V chunk 0 landed
#pragma unroll
    for (int sc_ = 0; sc_ < 8; ++sc_){
      if (sc_ < 7) stageV(si, sc_ + 1, (sc_ + 1) & 1);
      const f16* V = &Vt[sc_ & 1][0];
      f16x8 vf[4], pf[4];
#pragma unroll
      for (int ht = 0; ht < 4; ++ht){
        int row = w * 64 + ht * 16 + lr;
        vf[ht] = *(const f16x8*)((const char*)V + row * 64 + ((lq ^ (row & 3)) << 4));
      }
#pragma unroll
      for (int nt = 0; nt < 4; ++nt){
        int row = nt * 16 + lr;
        pf[nt] = *(const f16x8*)((const char*)Pl + row * 512 + (((sc_ * 4 + lq) ^ (row & 7)) << 4));
      }
      __builtin_amdgcn_s_setprio(1);
#pragma unroll
      for (int ht = 0; ht < 4; ++ht)
#pragma unroll
        for (int nt = 0; nt < 4; ++nt)
          acc[ht][nt] = mfma_f16(vf[ht], pf[nt], acc[ht][nt]);
      __builtin_amdgcn_s_setprio(0);
      __syncthreads(); // V[buf^1] landed for next step; reads of V[buf] done
    }
  }
  // epilogue: h = hh*256 + w*64 + ht*16 + lq*4 (+j), t = t0 + nt*16 + lr
#pragma unroll
  for (int ht = 0; ht < 4; ++ht)
#pragma unroll
    for (int nt = 0; nt < 4; ++nt){
      int t = t0 + nt * 16 + lr;
      int h = hh * 256 + w * 64 + ht * 16 + lq * 4;
      float4 v;
      v.x = acc[ht][nt][0]; v.y = acc[ht][nt][1];
      v.z = acc[ht][nt][2]; v.w = acc[ht][nt][3];
      *(float4*)&out[(size_t)(b * 2048 + t) * 512 + h] = v;
    }
}

// ---------------------------------------------------------------------------
extern "C" void kernel_launch(void* const* d_in, const int* in_sizes, int n_in,
                              void* d_out, int out_size, void* d_ws, size_t ws_size,
                              hipStream_t stream){
  (void)in_sizes; (void)n_in; (void)out_size; (void)ws_size;
  const float* tokens = (const float*)d_in[0];
  const float* Wq = (const float*)d_in[1];
  const float* Wk = (const float*)d_in[2];
  const float* Wv = (const float*)d_in[3];
  char* ws = (char*)d_ws;
  f16*    T16 = (f16*)(ws);                        // [0, 16M)
  f16*    QG  = (f16*)(ws + (16u << 20));          // [16M, 32M)
  f16*    VT  = (f16*)(ws + (32u << 20));          // [32M, 48M)
  f16*    B16 = (f16*)(ws + (48u << 20));          // [48M, 49M)
  float*  SC  = (float*)(ws + (50u << 20));        // [50M, 51M)
  float*  Mp  = (float*)(ws + (51u << 20));        // [51M, 52M)
  float*  Dp  = (float*)(ws + (52u << 20));        // [52M, 53M)
  f16*    Pp  = (f16*)(ws + (54u << 20));          // [54M, 118M)
  float* out = (float*)d_out;

  k_prep_g <<<dim3(16, 16), dim3(256), 0, stream>>>(Wq, Wk, B16);
  k_prep_wv<<<dim3(8, 8),   dim3(256), 0, stream>>>(Wv, B16);
  k_cast   <<<dim3(4096),   dim3(256), 0, stream>>>(tokens, T16);
  k_gemm   <<<dim3(128, 8), dim3(256), 0, stream>>>(T16, B16, QG, VT);
  k_pass1p <<<dim3(2048),   dim3(256), 0, stream>>>(T16, QG, Pp, Mp, Dp);
  k_scm    <<<dim3(64),     dim3(256), 0, stream>>>(Mp, Dp, SC);
  k_pass2p <<<dim3(512),    dim3(256), 0, stream>>>(Pp, VT, SC, out);
}

// Round 7
// 178.727 us; speedup vs baseline: 1.9970x; 1.0981x over previous
//
#include <hip/hip_runtime.h>

typedef _Float16 f16;
typedef _Float16 f16x8 __attribute__((ext_vector_type(8)));
typedef _Float16 f16x4 __attribute__((ext_vector_type(4)));
typedef float   f32x4 __attribute__((ext_vector_type(4)));

#define LOG2E 1.44269504088896340736f

__device__ __forceinline__ f32x4 mfma_f16(f16x8 a, f16x8 b, f32x4 c){
  return __builtin_amdgcn_mfma_f32_16x16x32_f16(a, b, c, 0, 0, 0);
}
__device__ __forceinline__ float fexp2(float x){ return __builtin_amdgcn_exp2f(x); }

// global -> LDS direct DMA, 16B per lane. lds must be wave-uniform base;
// HW writes base + lane*16. Source address is per-lane (pre-swizzled).
__device__ __forceinline__ void gld16(void* lds, const void* g){
  __builtin_amdgcn_global_load_lds(
      (const __attribute__((address_space(1))) unsigned int*)g,
      (__attribute__((address_space(3))) unsigned int*)lds,
      16, 0, 0);
}

// ---------------------------------------------------------------------------
// k_prep_g: B16[n][e] = sum_x Wk[n][x]*Wq[e][x]  (= (Wq Wk^T)^T), n<512.
// ---------------------------------------------------------------------------
__global__ __launch_bounds__(256) void k_prep_g(const float* __restrict__ Wq,
                                                const float* __restrict__ Wk,
                                                f16* __restrict__ B16){
  __shared__ float ak[32][36];
  __shared__ float aq[32][36];
  const int n0 = blockIdx.y * 32, e0 = blockIdx.x * 32;
  const int u = threadIdx.x;
  const int ty = u >> 4, tx = u & 15;
  float acc[2][2] = {};
  for (int x0 = 0; x0 < 512; x0 += 32){
    __syncthreads();
    {
      int r = u >> 3, c4 = (u & 7) * 4;
      *(float4*)&ak[r][c4] = *(const float4*)&Wk[(n0 + r) * 512 + x0 + c4];
      *(float4*)&aq[r][c4] = *(const float4*)&Wq[(e0 + r) * 512 + x0 + c4];
    }
    __syncthreads();
#pragma unroll 8
    for (int x = 0; x < 32; ++x){
      float k0 = ak[ty * 2 + 0][x], k1 = ak[ty * 2 + 1][x];
      float q0 = aq[tx * 2 + 0][x], q1 = aq[tx * 2 + 1][x];
      acc[0][0] += k0 * q0; acc[0][1] += k0 * q1;
      acc[1][0] += k1 * q0; acc[1][1] += k1 * q1;
    }
  }
#pragma unroll
  for (int i = 0; i < 2; ++i)
#pragma unroll
    for (int j = 0; j < 2; ++j)
      B16[(size_t)(n0 + ty * 2 + i) * 512 + e0 + tx * 2 + j] = (f16)acc[i][j];
}

// ---------------------------------------------------------------------------
// k_prep_wv: B16[512+d][e] = Wv[e][d]  (transpose + fp16 cast)
// ---------------------------------------------------------------------------
__global__ __launch_bounds__(256) void k_prep_wv(const float* __restrict__ Wv,
                                                 f16* __restrict__ B16){
  __shared__ float t[64][72];
  const int e0 = blockIdx.x * 64, h0 = blockIdx.y * 64;
  const int u = threadIdx.x;
#pragma unroll
  for (int k = 0; k < 4; ++k){
    int idx = u + k * 256; int r = idx >> 4, c4 = (idx & 15) * 4;
    *(float4*)&t[r][c4] = *(const float4*)&Wv[(e0 + r) * 512 + h0 + c4];
  }
  __syncthreads();
#pragma unroll
  for (int k = 0; k < 4; ++k){
    int idx = u + k * 256; int j = idx >> 4, i4 = (idx & 15) * 4;
#pragma unroll
    for (int c = 0; c < 4; ++c)
      B16[(size_t)(512 + h0 + j) * 512 + e0 + i4 + c] = (f16)t[i4 + c][j];
  }
}

// ---------------------------------------------------------------------------
// k_cast: tokens fp32 -> fp16, 8/thread.
// ---------------------------------------------------------------------------
__global__ __launch_bounds__(256) void k_cast(const float* __restrict__ tok,
                                              f16* __restrict__ T16){
  int i = blockIdx.x * 256 + threadIdx.x;
  const float4* p = (const float4*)tok + (size_t)i * 2;
  float4 a = p[0], b = p[1];
  f16x8 h;
  h[0] = (f16)a.x; h[1] = (f16)a.y; h[2] = (f16)a.z; h[3] = (f16)a.w;
  h[4] = (f16)b.x; h[5] = (f16)b.y; h[6] = (f16)b.z; h[7] = (f16)b.w;
  *((f16x8*)T16 + i) = h;
}

// ---------------------------------------------------------------------------
// k_gemm: C[t][n] = sum_e T16[t][e]*B16[n][e]; n<512 -> QG[t][n],
// n>=512 -> VT[b][d][s]. 128x128 tile, BK=32 (32KB LDS -> 4+ blocks/CU).
// ---------------------------------------------------------------------------
__global__ __launch_bounds__(256, 4) void k_gemm(const f16* __restrict__ T16,
                                                 const f16* __restrict__ B16,
                                                 f16* __restrict__ QG,
                                                 f16* __restrict__ VT){
  __shared__ __align__(16) f16 Abuf[2][128 * 32];  // 2*8KB
  __shared__ __align__(16) f16 Bbuf[2][128 * 32];  // 2*8KB
  const int tb = blockIdx.x, nb = blockIdx.y;
  const int u = threadIdx.x;
  const int w = u >> 6, l = u & 63, lr = l & 15, lq = l >> 4;
  const int l2 = l & 3, hi4 = l >> 2;
  const int wm = (w & 1) * 64, wn = (w >> 1) * 64;
  f32x4 acc[4][4] = {};
  auto stage = [&](int c, int buf){
    const f16* sa = T16 + (size_t)tb * 128 * 512 + c * 32;
    const f16* sb = B16 + (size_t)nb * 128 * 512 + c * 32;
#pragma unroll
    for (int k = 0; k < 2; ++k){
      int i = w * 2 + k;
      int row = i * 16 + hi4;
      gld16((char*)&Abuf[buf][0] + i * 1024, sa + (size_t)row * 512 + ((l2 ^ (row & 3)) * 8));
      gld16((char*)&Bbuf[buf][0] + i * 1024, sb + (size_t)row * 512 + ((l2 ^ (row & 3)) * 8));
    }
  };
  stage(0, 0);
  for (int c = 0; c < 16; ++c){
    __syncthreads();
    if (c < 15) stage(c + 1, (c + 1) & 1);
    const f16* A = &Abuf[c & 1][0];
    const f16* B = &Bbuf[c & 1][0];
    f16x8 af[4], bf[4];
#pragma unroll
    for (int mt = 0; mt < 4; ++mt){
      int row = wm + mt * 16 + lr;
      af[mt] = *(const f16x8*)((const char*)A + row * 64 + ((lq ^ (row & 3)) << 4));
    }
#pragma unroll
    for (int nt = 0; nt < 4; ++nt){
      int row = wn + nt * 16 + lr;
      bf[nt] = *(const f16x8*)((const char*)B + row * 64 + ((lq ^ (row & 3)) << 4));
    }
#pragma unroll
    for (int mt = 0; mt < 4; ++mt)
#pragma unroll
      for (int nt = 0; nt < 4; ++nt)
        acc[mt][nt] = mfma_f16(af[mt], bf[nt], acc[mt][nt]);
  }
  if (nb < 4){
#pragma unroll
    for (int mt = 0; mt < 4; ++mt)
#pragma unroll
      for (int nt = 0; nt < 4; ++nt){
        int n = nb * 128 + wn + nt * 16 + lr;
        int r0 = tb * 128 + wm + mt * 16 + lq * 4;
#pragma unroll
        for (int j = 0; j < 4; ++j)
          QG[(size_t)(r0 + j) * 512 + n] = (f16)acc[mt][nt][j];
      }
  } else {
#pragma unroll
    for (int mt = 0; mt < 4; ++mt)
#pragma unroll
      for (int nt = 0; nt < 4; ++nt){
        int h = (nb - 4) * 128 + wn + nt * 16 + lr;
        int r0 = tb * 128 + wm + mt * 16 + lq * 4;
        int bq = r0 >> 11, s = r0 & 2047;
        f16x4 hv;
#pragma unroll
        for (int j = 0; j < 4; ++j) hv[j] = (f16)acc[mt][nt][j];
        *(f16x4*)&VT[(size_t)(bq * 512 + h) * 2048 + s] = hv;
      }
  }
}

// ---------------------------------------------------------------------------
// k_pass1p: S-GEMM 128s x 128t tile, BK=32, dbuf (32KB LDS -> 4 blocks/CU).
// Block = (b, sb 16, tb 16), grid 2048. Epilogue: tile-local col stats over
// the block's 128 t: M -> P' = exp2(x-M) fp16 store, D = col-sum.
// ---------------------------------------------------------------------------
__global__ __launch_bounds__(256, 4) void k_pass1p(const f16* __restrict__ T16,
                                                   const f16* __restrict__ QG,
                                                   f16* __restrict__ Pp,
                                                   float* __restrict__ Mp,
                                                   float* __restrict__ Dp){
  const int gid = blockIdx.x;
  const int b = gid & 7;
  const int sb = (gid >> 3) & 15;
  const int tb = gid >> 7;
  const int u = threadIdx.x;
  const int w = u >> 6, l = u & 63, lr = l & 15, lq = l >> 4;
  const int l2 = l & 3, hi4 = l >> 2;
  const int wm = (w & 1) * 64, wn = (w >> 1) * 64;  // s, t within tile

  __shared__ __align__(16) f16 Abuf[2][128 * 32];  // T16 s-rows, 2*8KB
  __shared__ __align__(16) f16 Bbuf[2][128 * 32];  // QG  t-rows, 2*8KB
  __shared__ float redM[2][128];
  __shared__ float redD[2][128];

  f32x4 acc[4][4] = {};
  auto stage = [&](int c, int buf){
    const f16* sa = T16 + ((size_t)(b * 2048 + sb * 128) * 512 + c * 32);
    const f16* sb_ = QG + ((size_t)(b * 2048 + tb * 128) * 512 + c * 32);
#pragma unroll
    for (int k = 0; k < 2; ++k){
      int i = w * 2 + k;
      int row = i * 16 + hi4;
      gld16((char*)&Abuf[buf][0] + i * 1024, sa  + (size_t)row * 512 + ((l2 ^ (row & 3)) * 8));
      gld16((char*)&Bbuf[buf][0] + i * 1024, sb_ + (size_t)row * 512 + ((l2 ^ (row & 3)) * 8));
    }
  };
  stage(0, 0);
  for (int c = 0; c < 16; ++c){
    __syncthreads();
    if (c < 15) stage(c + 1, (c + 1) & 1);
    const f16* A = &Abuf[c & 1][0];
    const f16* B = &Bbuf[c & 1][0];
    f16x8 af[4], bf[4];
#pragma unroll
    for (int mt = 0; mt < 4; ++mt){
      int row = wm + mt * 16 + lr;
      af[mt] = *(const f16x8*)((const char*)A + row * 64 + ((lq ^ (row & 3)) << 4));
    }
#pragma unroll
    for (int nt = 0; nt < 4; ++nt){
      int row = wn + nt * 16 + lr;
      bf[nt] = *(const f16x8*)((const char*)B + row * 64 + ((lq ^ (row & 3)) << 4));
    }
#pragma unroll
    for (int mt = 0; mt < 4; ++mt)
#pragma unroll
      for (int nt = 0; nt < 4; ++nt)
        acc[mt][nt] = mfma_f16(af[mt], bf[nt], acc[mt][nt]);
  }
  // ---- epilogue: x = S*log2e; tile-local col max over the block's 128 t ----
#pragma unroll
  for (int mt = 0; mt < 4; ++mt)
#pragma unroll
    for (int nt = 0; nt < 4; ++nt)
#pragma unroll
      for (int j = 0; j < 4; ++j)
        acc[mt][nt][j] *= LOG2E;
#pragma unroll
  for (int mt = 0; mt < 4; ++mt)
#pragma unroll
    for (int j = 0; j < 4; ++j){
      float m2 = fmaxf(fmaxf(acc[mt][0][j], acc[mt][1][j]),
                       fmaxf(acc[mt][2][j], acc[mt][3][j]));
#pragma unroll
      for (int off = 1; off <= 8; off <<= 1)
        m2 = fmaxf(m2, __shfl_xor(m2, off, 64));
      if (lr == 0) redM[w >> 1][wm + mt * 16 + lq * 4 + j] = m2;
    }
  __syncthreads();
  float M[4][4];
#pragma unroll
  for (int mt = 0; mt < 4; ++mt)
#pragma unroll
    for (int j = 0; j < 4; ++j){
      int idx = wm + mt * 16 + lq * 4 + j;
      M[mt][j] = fmaxf(redM[0][idx], redM[1][idx]);
    }
  // ---- P' = exp2(x - M), store fp16, col sums ----
#pragma unroll
  for (int mt = 0; mt < 4; ++mt)
#pragma unroll
    for (int nt = 0; nt < 4; ++nt){
      int t = tb * 128 + wn + nt * 16 + lr;
      f16x4 h4;
#pragma unroll
      for (int j = 0; j < 4; ++j){
        float p = fexp2(acc[mt][nt][j] - M[mt][j]);
        acc[mt][nt][j] = p;
        h4[j] = (f16)p;
      }
      *(f16x4*)&Pp[(size_t)(b * 2048 + t) * 2048 + sb * 128 + wm + mt * 16 + lq * 4] = h4;
    }
#pragma unroll
  for (int mt = 0; mt < 4; ++mt)
#pragma unroll
    for (int j = 0; j < 4; ++j){
      float sd = acc[mt][0][j] + acc[mt][1][j] + acc[mt][2][j] + acc[mt][3][j];
#pragma unroll
      for (int off = 1; off <= 8; off <<= 1)
        sd += __shfl_xor(sd, off, 64);
      if (lr == 0) redD[w >> 1][wm + mt * 16 + lq * 4 + j] = sd;
    }
  __syncthreads();
  if (u < 128){
    int sg = b * 2048 + sb * 128 + u;
    Mp[tb * 16384 + sg] = fmaxf(redM[0][u], redM[1][u]);
    Dp[tb * 16384 + sg] = redD[0][u] + redD[1][u];
  }
}

// ---------------------------------------------------------------------------
// k_scm: merge the 16 per-tile partials -> SC16[ti][s] = exp2(M-m)/denom (f16).
// ---------------------------------------------------------------------------
__global__ __launch_bounds__(256) void k_scm(const float* __restrict__ Mp,
                                             const float* __restrict__ Dp,
                                             f16* __restrict__ SC16){
  int i = blockIdx.x * 256 + threadIdx.x;  // (b,s) flat, 16384
  float mv[16];
  float m = -1e30f;
#pragma unroll
  for (int ti = 0; ti < 16; ++ti){
    mv[ti] = Mp[ti * 16384 + i];
    m = fmaxf(m, mv[ti]);
  }
  float d = 0.f;
#pragma unroll
  for (int ti = 0; ti < 16; ++ti)
    d += Dp[ti * 16384 + i] * fexp2(mv[ti] - m);
  float rd = 1.0f / d;
#pragma unroll
  for (int ti = 0; ti < 16; ++ti)
    SC16[ti * 16384 + i] = (f16)(fexp2(mv[ti] - m) * rd);
}

// ---------------------------------------------------------------------------
// k_pass2p (v2): pure GEMM over K=s=2048. Block = (b, tb 16, hb 4), grid 512.
// ctx^T[h][t] = sum_s V^T[h][s] * (P'[t][s]*sc[tb][s]). BK=32, dbuf,
// 36KB LDS -> 4 blocks/CU. Scale applied IN REGISTERS to the P fragments:
// all 4 bf share k-slot lq -> s = c*32 + lq*8 + e (gfx950 16x16x32 A/B
// k-mapping); sc row staged once as f16 (broadcast ds_read, conflict-free).
// ---------------------------------------------------------------------------
__global__ __launch_bounds__(256, 4) void k_pass2p(const f16* __restrict__ Pp,
                                                   const f16* __restrict__ VT,
                                                   const f16* __restrict__ SC16,
                                                   float* __restrict__ out){
  const int gid = blockIdx.x;
  const int b = gid & 7;
  const int tb = (gid >> 3) & 15;
  const int hb = gid >> 7;
  const int u = threadIdx.x;
  const int w = u >> 6, l = u & 63, lr = l & 15, lq = l >> 4;
  const int l2 = l & 3, hi4 = l >> 2;
  const int wm = (w & 1) * 64, wn = (w >> 1) * 64;  // h, t within tile

  __shared__ __align__(16) f16 Abuf[2][128 * 32];  // V^T h-rows, 2*8KB
  __shared__ __align__(16) f16 Bbuf[2][128 * 32];  // P' t-rows, 2*8KB
  __shared__ __align__(16) f16 scl[2048];          // 4KB, sc row for this tb

  { // stage scale row (one f16x8 per thread)
    f16x8 v = *(const f16x8*)&SC16[(size_t)tb * 16384 + b * 2048 + u * 8];
    *(f16x8*)&scl[u * 8] = v;
  }
  f32x4 acc[4][4] = {};
  auto stage = [&](int c, int buf){
    const f16* sa = VT + ((size_t)(b * 512 + hb * 128) * 2048 + c * 32);
    const f16* sb_ = Pp + ((size_t)(b * 2048 + tb * 128) * 2048 + c * 32);
#pragma unroll
    for (int k = 0; k < 2; ++k){
      int i = w * 2 + k;
      int row = i * 16 + hi4;
      gld16((char*)&Abuf[buf][0] + i * 1024, sa  + (size_t)row * 2048 + ((l2 ^ (row & 3)) * 8));
      gld16((char*)&Bbuf[buf][0] + i * 1024, sb_ + (size_t)row * 2048 + ((l2 ^ (row & 3)) * 8));
    }
  };
  stage(0, 0);
  for (int c = 0; c < 64; ++c){
    __syncthreads();   // drains gld16 (vmcnt) and scl ds_write (lgkmcnt) on c=0
    if (c < 63) stage(c + 1, (c + 1) & 1);
    const f16* A = &Abuf[c & 1][0];
    const f16* B = &Bbuf[c & 1][0];
    f16x8 sclv = *(const f16x8*)&scl[c * 32 + lq * 8];   // broadcast per lq
    f16x8 af[4], bf[4];
#pragma unroll
    for (int mt = 0; mt < 4; ++mt){
      int row = wm + mt * 16 + lr;
      af[mt] = *(const f16x8*)((const char*)A + row * 64 + ((lq ^ (row & 3)) << 4));
    }
#pragma unroll
    for (int nt = 0; nt < 4; ++nt){
      int row = wn + nt * 16 + lr;
      f16x8 p = *(const f16x8*)((const char*)B + row * 64 + ((lq ^ (row & 3)) << 4));
      bf[nt] = p * sclv;
    }
#pragma unroll
    for (int mt = 0; mt < 4; ++mt)
#pragma unroll
      for (int nt = 0; nt < 4; ++nt)
        acc[mt][nt] = mfma_f16(af[mt], bf[nt], acc[mt][nt]);
  }
  // epilogue: h = hb*128 + wm + mt*16 + lq*4 (+j), t = tb*128 + wn + nt*16 + lr
#pragma unroll
  for (int mt = 0; mt < 4; ++mt)
#pragma unroll
    for (int nt = 0; nt < 4; ++nt){
      int t = tb * 128 + wn + nt * 16 + lr;
      int h = hb * 128 + wm + mt * 16 + lq * 4;
      float4 v;
      v.x = acc[mt][nt][0]; v.y = acc[mt][nt][1];
      v.z = acc[mt][nt][2]; v.w = acc[mt][nt][3];
      *(float4*)&out[(size_t)(b * 2048 + t) * 512 + h] = v;
    }
}

// ---------------------------------------------------------------------------
extern "C" void kernel_launch(void* const* d_in, const int* in_sizes, int n_in,
                              void* d_out, int out_size, void* d_ws, size_t ws_size,
                              hipStream_t stream){
  (void)in_sizes; (void)n_in; (void)out_size; (void)ws_size;
  const float* tokens = (const float*)d_in[0];
  const float* Wq = (const float*)d_in[1];
  const float* Wk = (const float*)d_in[2];
  const float* Wv = (const float*)d_in[3];
  char* ws = (char*)d_ws;
  f16*    T16 = (f16*)(ws);                        // [0, 16M)
  f16*    QG  = (f16*)(ws + (16u << 20));          // [16M, 32M)
  f16*    VT  = (f16*)(ws + (32u << 20));          // [32M, 48M)
  f16*    B16 = (f16*)(ws + (48u << 20));          // [48M, 49M)
  f16*    SC16= (f16*)(ws + (50u << 20));          // [50M, 50.5M)
  float*  Mp  = (float*)(ws + (51u << 20));        // [51M, 52M)
  float*  Dp  = (float*)(ws + (52u << 20));        // [52M, 53M)
  f16*    Pp  = (f16*)(ws + (54u << 20));          // [54M, 118M)
  float* out = (float*)d_out;

  k_prep_g <<<dim3(16, 16), dim3(256), 0, stream>>>(Wq, Wk, B16);
  k_prep_wv<<<dim3(8, 8),   dim3(256), 0, stream>>>(Wv, B16);
  k_cast   <<<dim3(4096),   dim3(256), 0, stream>>>(tokens, T16);
  k_gemm   <<<dim3(128, 8), dim3(256), 0, stream>>>(T16, B16, QG, VT);
  k_pass1p <<<dim3(2048),   dim3(256), 0, stream>>>(T16, QG, Pp, Mp, Dp);
  k_scm    <<<dim3(64),     dim3(256), 0, stream>>>(Mp, Dp, SC16);
  k_pass2p <<<dim3(512),    dim3(256), 0, stream>>>(Pp, VT, SC16, out);
}

// Round 9
// 176.685 us; speedup vs baseline: 2.0201x; 1.0116x over previous
//
#include <hip/hip_runtime.h>

typedef _Float16 f16;
typedef _Float16 f16x8 __attribute__((ext_vector_type(8)));
typedef _Float16 f16x4 __attribute__((ext_vector_type(4)));
typedef float   f32x4 __attribute__((ext_vector_type(4)));

#define LOG2E 1.44269504088896340736f

__device__ __forceinline__ f32x4 mfma_f16(f16x8 a, f16x8 b, f32x4 c){
  return __builtin_amdgcn_mfma_f32_16x16x32_f16(a, b, c, 0, 0, 0);
}
__device__ __forceinline__ float fexp2(float x){ return __builtin_amdgcn_exp2f(x); }

// global -> LDS direct DMA, 16B per lane. lds must be wave-uniform base;
// HW writes base + lane*16. Source address is per-lane (pre-swizzled).
__device__ __forceinline__ void gld16(void* lds, const void* g){
  __builtin_amdgcn_global_load_lds(
      (const __attribute__((address_space(1))) unsigned int*)g,
      (__attribute__((address_space(3))) unsigned int*)lds,
      16, 0, 0);
}

// BK=32 conflict-free swizzle: LDS(row, pos) holds global k-word
// (pos ^ ((row>>1)&3)). Read slot for k-word lq: lq ^ ((row>>1)&3).
// Banks: (16*row + 4*slot) mod 32 -> each bank-group hit exactly 2x per
// quarter-wave (2-way aliasing = free). Staging XOR: (l&3) ^ ((l>>3)&3).

// ---------------------------------------------------------------------------
// k_prep_g: B16[n][e] = sum_x Wk[n][x]*Wq[e][x]  (= (Wq Wk^T)^T), n<512.
// ---------------------------------------------------------------------------
__global__ __launch_bounds__(256) void k_prep_g(const float* __restrict__ Wq,
                                                const float* __restrict__ Wk,
                                                f16* __restrict__ B16){
  __shared__ float ak[32][36];
  __shared__ float aq[32][36];
  const int n0 = blockIdx.y * 32, e0 = blockIdx.x * 32;
  const int u = threadIdx.x;
  const int ty = u >> 4, tx = u & 15;
  float acc[2][2] = {};
  for (int x0 = 0; x0 < 512; x0 += 32){
    __syncthreads();
    {
      int r = u >> 3, c4 = (u & 7) * 4;
      *(float4*)&ak[r][c4] = *(const float4*)&Wk[(n0 + r) * 512 + x0 + c4];
      *(float4*)&aq[r][c4] = *(const float4*)&Wq[(e0 + r) * 512 + x0 + c4];
    }
    __syncthreads();
#pragma unroll 8
    for (int x = 0; x < 32; ++x){
      float k0 = ak[ty * 2 + 0][x], k1 = ak[ty * 2 + 1][x];
      float q0 = aq[tx * 2 + 0][x], q1 = aq[tx * 2 + 1][x];
      acc[0][0] += k0 * q0; acc[0][1] += k0 * q1;
      acc[1][0] += k1 * q0; acc[1][1] += k1 * q1;
    }
  }
#pragma unroll
  for (int i = 0; i < 2; ++i)
#pragma unroll
    for (int j = 0; j < 2; ++j)
      B16[(size_t)(n0 + ty * 2 + i) * 512 + e0 + tx * 2 + j] = (f16)acc[i][j];
}

// ---------------------------------------------------------------------------
// k_prep_wv: B16[512+d][e] = Wv[e][d]  (transpose + fp16 cast)
// ---------------------------------------------------------------------------
__global__ __launch_bounds__(256) void k_prep_wv(const float* __restrict__ Wv,
                                                 f16* __restrict__ B16){
  __shared__ float t[64][72];
  const int e0 = blockIdx.x * 64, h0 = blockIdx.y * 64;
  const int u = threadIdx.x;
#pragma unroll
  for (int k = 0; k < 4; ++k){
    int idx = u + k * 256; int r = idx >> 4, c4 = (idx & 15) * 4;
    *(float4*)&t[r][c4] = *(const float4*)&Wv[(e0 + r) * 512 + h0 + c4];
  }
  __syncthreads();
#pragma unroll
  for (int k = 0; k < 4; ++k){
    int idx = u + k * 256; int j = idx >> 4, i4 = (idx & 15) * 4;
#pragma unroll
    for (int c = 0; c < 4; ++c)
      B16[(size_t)(512 + h0 + j) * 512 + e0 + i4 + c] = (f16)t[i4 + c][j];
  }
}

// ---------------------------------------------------------------------------
// k_cast: tokens fp32 -> fp16, 8/thread.
// ---------------------------------------------------------------------------
__global__ __launch_bounds__(256) void k_cast(const float* __restrict__ tok,
                                              f16* __restrict__ T16){
  int i = blockIdx.x * 256 + threadIdx.x;
  const float4* p = (const float4*)tok + (size_t)i * 2;
  float4 a = p[0], b = p[1];
  f16x8 h;
  h[0] = (f16)a.x; h[1] = (f16)a.y; h[2] = (f16)a.z; h[3] = (f16)a.w;
  h[4] = (f16)b.x; h[5] = (f16)b.y; h[6] = (f16)b.z; h[7] = (f16)b.w;
  *((f16x8*)T16 + i) = h;
}

// ---------------------------------------------------------------------------
// k_gemm: C[t][n] = sum_e T16[t][e]*B16[n][e]; n<512 -> QG[t][n],
// n>=512 -> VT[b][d][s]. 128x128 tile, BK=32, dbuf, conflict-free swizzle.
// ---------------------------------------------------------------------------
__global__ __launch_bounds__(256, 4) void k_gemm(const f16* __restrict__ T16,
                                                 const f16* __restrict__ B16,
                                                 f16* __restrict__ QG,
                                                 f16* __restrict__ VT){
  __shared__ __align__(16) f16 Abuf[2][128 * 32];  // 2*8KB
  __shared__ __align__(16) f16 Bbuf[2][128 * 32];  // 2*8KB
  const int tb = blockIdx.x, nb = blockIdx.y;
  const int u = threadIdx.x;
  const int w = u >> 6, l = u & 63, lr = l & 15, lq = l >> 4;
  const int sxor = (l & 3) ^ ((l >> 3) & 3), hi4 = l >> 2;
  const int wm = (w & 1) * 64, wn = (w >> 1) * 64;
  f32x4 acc[4][4] = {};
  auto stage = [&](int c, int buf){
    const f16* sa = T16 + (size_t)tb * 128 * 512 + c * 32;
    const f16* sb = B16 + (size_t)nb * 128 * 512 + c * 32;
#pragma unroll
    for (int k = 0; k < 2; ++k){
      int i = w * 2 + k;
      int row = i * 16 + hi4;
      gld16((char*)&Abuf[buf][0] + i * 1024, sa + (size_t)row * 512 + sxor * 8);
      gld16((char*)&Bbuf[buf][0] + i * 1024, sb + (size_t)row * 512 + sxor * 8);
    }
  };
  stage(0, 0);
  for (int c = 0; c < 16; ++c){
    __syncthreads();
    if (c < 15) stage(c + 1, (c + 1) & 1);
    const f16* A = &Abuf[c & 1][0];
    const f16* B = &Bbuf[c & 1][0];
    f16x8 af[4], bf[4];
#pragma unroll
    for (int mt = 0; mt < 4; ++mt){
      int row = wm + mt * 16 + lr;
      af[mt] = *(const f16x8*)((const char*)A + row * 64 + (((lq ^ ((row >> 1) & 3))) << 4));
    }
#pragma unroll
    for (int nt = 0; nt < 4; ++nt){
      int row = wn + nt * 16 + lr;
      bf[nt] = *(const f16x8*)((const char*)B + row * 64 + (((lq ^ ((row >> 1) & 3))) << 4));
    }
#pragma unroll
    for (int mt = 0; mt < 4; ++mt)
#pragma unroll
      for (int nt = 0; nt < 4; ++nt)
        acc[mt][nt] = mfma_f16(af[mt], bf[nt], acc[mt][nt]);
  }
  if (nb < 4){
#pragma unroll
    for (int mt = 0; mt < 4; ++mt)
#pragma unroll
      for (int nt = 0; nt < 4; ++nt){
        int n = nb * 128 + wn + nt * 16 + lr;
        int r0 = tb * 128 + wm + mt * 16 + lq * 4;
#pragma unroll
        for (int j = 0; j < 4; ++j)
          QG[(size_t)(r0 + j) * 512 + n] = (f16)acc[mt][nt][j];
      }
  } else {
#pragma unroll
    for (int mt = 0; mt < 4; ++mt)
#pragma unroll
      for (int nt = 0; nt < 4; ++nt){
        int h = (nb - 4) * 128 + wn + nt * 16 + lr;
        int r0 = tb * 128 + wm + mt * 16 + lq * 4;
        int bq = r0 >> 11, s = r0 & 2047;
        f16x4 hv;
#pragma unroll
        for (int j = 0; j < 4; ++j) hv[j] = (f16)acc[mt][nt][j];
        *(f16x4*)&VT[(size_t)(bq * 512 + h) * 2048 + s] = hv;
      }
  }
}

// ---------------------------------------------------------------------------
// k_pass1p: S-GEMM 128s x 128t, BK=32, 3-buffer depth-2 pipeline with
// counted vmcnt. FIX vs r8: the barrier asm also waits lgkmcnt(0) so every
// wave's ds_reads of the buffer being recycled have completed into registers
// BEFORE it crosses the barrier (compiler may sink the dependent MFMAs —
// register-only — below the asm, so without lgkmcnt(0) a wave could cross
// with reads still queued while another wave's gld16 overwrites the buffer).
// ---------------------------------------------------------------------------
__global__ __launch_bounds__(256, 3) void k_pass1p(const f16* __restrict__ T16,
                                                   const f16* __restrict__ QG,
                                                   f16* __restrict__ Pp,
                                                   float* __restrict__ Mp,
                                                   float* __restrict__ Dp){
  const int gid = blockIdx.x;
  const int b = gid & 7;
  const int sb = (gid >> 3) & 15;
  const int tb = gid >> 7;
  const int u = threadIdx.x;
  const int w = u >> 6, l = u & 63, lr = l & 15, lq = l >> 4;
  const int sxor = (l & 3) ^ ((l >> 3) & 3), hi4 = l >> 2;
  const int wm = (w & 1) * 64, wn = (w >> 1) * 64;  // s, t within tile

  __shared__ __align__(16) f16 Abuf[3][128 * 32];  // T16 s-rows, 3*8KB
  __shared__ __align__(16) f16 Bbuf[3][128 * 32];  // QG  t-rows, 3*8KB
  __shared__ float redM[2][128];
  __shared__ float redD[2][128];

  f32x4 acc[4][4] = {};
  const f16* sa0 = T16 + ((size_t)(b * 2048 + sb * 128) * 512);
  const f16* sb0 = QG + ((size_t)(b * 2048 + tb * 128) * 512);
  auto stage = [&](int c, int buf){
    const f16* sa = sa0 + c * 32;
    const f16* sb_ = sb0 + c * 32;
#pragma unroll
    for (int k = 0; k < 2; ++k){
      int i = w * 2 + k;
      int row = i * 16 + hi4;
      gld16((char*)&Abuf[buf][0] + i * 1024, sa  + (size_t)row * 512 + sxor * 8);
      gld16((char*)&Bbuf[buf][0] + i * 1024, sb_ + (size_t)row * 512 + sxor * 8);
    }
  };
  stage(0, 0);
  stage(1, 1);
#pragma unroll
  for (int c = 0; c < 16; ++c){
    // counted wait: stage(c)'s 4 loads landed (stage(c+1)'s stay in flight);
    // lgkmcnt(0): this wave's prior ds_reads are in registers (WAR safety).
    if (c < 15) asm volatile("s_waitcnt vmcnt(4) lgkmcnt(0)\n\ts_barrier" ::: "memory");
    else        asm volatile("s_waitcnt vmcnt(0) lgkmcnt(0)\n\ts_barrier" ::: "memory");
    if (c + 2 < 16) stage(c + 2, (c + 2) % 3);
    const f16* A = &Abuf[c % 3][0];
    const f16* B = &Bbuf[c % 3][0];
    f16x8 af[4], bf[4];
#pragma unroll
    for (int mt = 0; mt < 4; ++mt){
      int row = wm + mt * 16 + lr;
      af[mt] = *(const f16x8*)((const char*)A + row * 64 + (((lq ^ ((row >> 1) & 3))) << 4));
    }
#pragma unroll
    for (int nt = 0; nt < 4; ++nt){
      int row = wn + nt * 16 + lr;
      bf[nt] = *(const f16x8*)((const char*)B + row * 64 + (((lq ^ ((row >> 1) & 3))) << 4));
    }
#pragma unroll
    for (int mt = 0; mt < 4; ++mt)
#pragma unroll
      for (int nt = 0; nt < 4; ++nt)
        acc[mt][nt] = mfma_f16(af[mt], bf[nt], acc[mt][nt]);
  }
  // ---- epilogue: x = S*log2e; tile-local col max over the block's 128 t ----
#pragma unroll
  for (int mt = 0; mt < 4; ++mt)
#pragma unroll
    for (int nt = 0; nt < 4; ++nt)
#pragma unroll
      for (int j = 0; j < 4; ++j)
        acc[mt][nt][j] *= LOG2E;
#pragma unroll
  for (int mt = 0; mt < 4; ++mt)
#pragma unroll
    for (int j = 0; j < 4; ++j){
      float m2 = fmaxf(fmaxf(acc[mt][0][j], acc[mt][1][j]),
                       fmaxf(acc[mt][2][j], acc[mt][3][j]));
#pragma unroll
      for (int off = 1; off <= 8; off <<= 1)
        m2 = fmaxf(m2, __shfl_xor(m2, off, 64));
      if (lr == 0) redM[w >> 1][wm + mt * 16 + lq * 4 + j] = m2;
    }
  __syncthreads();
  float M[4][4];
#pragma unroll
  for (int mt = 0; mt < 4; ++mt)
#pragma unroll
    for (int j = 0; j < 4; ++j){
      int idx = wm + mt * 16 + lq * 4 + j;
      M[mt][j] = fmaxf(redM[0][idx], redM[1][idx]);
    }
  // ---- P' = exp2(x - M), store fp16, col sums ----
#pragma unroll
  for (int mt = 0; mt < 4; ++mt)
#pragma unroll
    for (int nt = 0; nt < 4; ++nt){
      int t = tb * 128 + wn + nt * 16 + lr;
      f16x4 h4;
#pragma unroll
      for (int j = 0; j < 4; ++j){
        float p = fexp2(acc[mt][nt][j] - M[mt][j]);
        acc[mt][nt][j] = p;
        h4[j] = (f16)p;
      }
      *(f16x4*)&Pp[(size_t)(b * 2048 + t) * 2048 + sb * 128 + wm + mt * 16 + lq * 4] = h4;
    }
#pragma unroll
  for (int mt = 0; mt < 4; ++mt)
#pragma unroll
    for (int j = 0; j < 4; ++j){
      float sd = acc[mt][0][j] + acc[mt][1][j] + acc[mt][2][j] + acc[mt][3][j];
#pragma unroll
      for (int off = 1; off <= 8; off <<= 1)
        sd += __shfl_xor(sd, off, 64);
      if (lr == 0) redD[w >> 1][wm + mt * 16 + lq * 4 + j] = sd;
    }
  __syncthreads();
  if (u < 128){
    int sg = b * 2048 + sb * 128 + u;
    Mp[tb * 16384 + sg] = fmaxf(redM[0][u], redM[1][u]);
    Dp[tb * 16384 + sg] = redD[0][u] + redD[1][u];
  }
}

// ---------------------------------------------------------------------------
// k_scm: merge the 16 per-tile partials -> SC16[ti][s] = exp2(M-m)/denom (f16).
// ---------------------------------------------------------------------------
__global__ __launch_bounds__(256) void k_scm(const float* __restrict__ Mp,
                                             const float* __restrict__ Dp,
                                             f16* __restrict__ SC16){
  int i = blockIdx.x * 256 + threadIdx.x;  // (b,s) flat, 16384
  float mv[16];
  float m = -1e30f;
#pragma unroll
  for (int ti = 0; ti < 16; ++ti){
    mv[ti] = Mp[ti * 16384 + i];
    m = fmaxf(m, mv[ti]);
  }
  float d = 0.f;
#pragma unroll
  for (int ti = 0; ti < 16; ++ti)
    d += Dp[ti * 16384 + i] * fexp2(mv[ti] - m);
  float rd = 1.0f / d;
#pragma unroll
  for (int ti = 0; ti < 16; ++ti)
    SC16[ti * 16384 + i] = (f16)(fexp2(mv[ti] - m) * rd);
}

// ---------------------------------------------------------------------------
// k_pass2p: pure GEMM over K=s=2048. Block = (b, tb 16, hb 4), grid 512.
// ctx^T[h][t] = sum_s V^T[h][s] * (P'[t][s]*sc[tb][s]). BK=32, dbuf,
// scale applied in registers (all bf share k-slot lq -> s = c*32+lq*8+e).
// ---------------------------------------------------------------------------
__global__ __launch_bounds__(256, 4) void k_pass2p(const f16* __restrict__ Pp,
                                                   const f16* __restrict__ VT,
                                                   const f16* __restrict__ SC16,
                                                   float* __restrict__ out){
  const int gid = blockIdx.x;
  const int b = gid & 7;
  const int tb = (gid >> 3) & 15;
  const int hb = gid >> 7;
  const int u = threadIdx.x;
  const int w = u >> 6, l = u & 63, lr = l & 15, lq = l >> 4;
  const int sxor = (l & 3) ^ ((l >> 3) & 3), hi4 = l >> 2;
  const int wm = (w & 1) * 64, wn = (w >> 1) * 64;  // h, t within tile

  __shared__ __align__(16) f16 Abuf[2][128 * 32];  // V^T h-rows, 2*8KB
  __shared__ __align__(16) f16 Bbuf[2][128 * 32];  // P' t-rows, 2*8KB
  __shared__ __align__(16) f16 scl[2048];          // 4KB, sc row for this tb

  { // stage scale row (one f16x8 per thread)
    f16x8 v = *(const f16x8*)&SC16[(size_t)tb * 16384 + b * 2048 + u * 8];
    *(f16x8*)&scl[u * 8] = v;
  }
  f32x4 acc[4][4] = {};
  auto stage = [&](int c, int buf){
    const f16* sa = VT + ((size_t)(b * 512 + hb * 128) * 2048 + c * 32);
    const f16* sb_ = Pp + ((size_t)(b * 2048 + tb * 128) * 2048 + c * 32);
#pragma unroll
    for (int k = 0; k < 2; ++k){
      int i = w * 2 + k;
      int row = i * 16 + hi4;
      gld16((char*)&Abuf[buf][0] + i * 1024, sa  + (size_t)row * 2048 + sxor * 8);
      gld16((char*)&Bbuf[buf][0] + i * 1024, sb_ + (size_t)row * 2048 + sxor * 8);
    }
  };
  stage(0, 0);
  for (int c = 0; c < 64; ++c){
    __syncthreads();   // drains gld16 (vmcnt) and scl ds_write (lgkmcnt) on c=0
    if (c < 63) stage(c + 1, (c + 1) & 1);
    const f16* A = &Abuf[c & 1][0];
    const f16* B = &Bbuf[c & 1][0];
    f16x8 sclv = *(const f16x8*)&scl[c * 32 + lq * 8];   // broadcast per lq
    f16x8 af[4], bf[4];
#pragma unroll
    for (int mt = 0; mt < 4; ++mt){
      int row = wm + mt * 16 + lr;
      af[mt] = *(const f16x8*)((const char*)A + row * 64 + (((lq ^ ((row >> 1) & 3))) << 4));
    }
#pragma unroll
    for (int nt = 0; nt < 4; ++nt){
      int row = wn + nt * 16 + lr;
      f16x8 p = *(const f16x8*)((const char*)B + row * 64 + (((lq ^ ((row >> 1) & 3))) << 4));
      bf[nt] = p * sclv;
    }
#pragma unroll
    for (int mt = 0; mt < 4; ++mt)
#pragma unroll
      for (int nt = 0; nt < 4; ++nt)
        acc[mt][nt] = mfma_f16(af[mt], bf[nt], acc[mt][nt]);
  }
  // epilogue: h = hb*128 + wm + mt*16 + lq*4 (+j), t = tb*128 + wn + nt*16 + lr
#pragma unroll
  for (int mt = 0; mt < 4; ++mt)
#pragma unroll
    for (int nt = 0; nt < 4; ++nt){
      int t = tb * 128 + wn + nt * 16 + lr;
      int h = hb * 128 + wm + mt * 16 + lq * 4;
      float4 v;
      v.x = acc[mt][nt][0]; v.y = acc[mt][nt][1];
      v.z = acc[mt][nt][2]; v.w = acc[mt][nt][3];
      *(float4*)&out[(size_t)(b * 2048 + t) * 512 + h] = v;
    }
}

// ---------------------------------------------------------------------------
extern "C" void kernel_launch(void* const* d_in, const int* in_sizes, int n_in,
                              void* d_out, int out_size, void* d_ws, size_t ws_size,
                              hipStream_t stream){
  (void)in_sizes; (void)n_in; (void)out_size; (void)ws_size;
  const float* tokens = (const float*)d_in[0];
  const float* Wq = (const float*)d_in[1];
  const float* Wk = (const float*)d_in[2];
  const float* Wv = (const float*)d_in[3];
  char* ws = (char*)d_ws;
  f16*    T16 = (f16*)(ws);                        // [0, 16M)
  f16*    QG  = (f16*)(ws + (16u << 20));          // [16M, 32M)
  f16*    VT  = (f16*)(ws + (32u << 20));          // [32M, 48M)
  f16*    B16 = (f16*)(ws + (48u << 20));          // [48M, 49M)
  f16*    SC16= (f16*)(ws + (50u << 20));          // [50M, 50.5M)
  float*  Mp  = (float*)(ws + (51u << 20));        // [51M, 52M)
  float*  Dp  = (float*)(ws + (52u << 20));        // [52M, 53M)
  f16*    Pp  = (f16*)(ws + (54u << 20));          // [54M, 118M)
  float* out = (float*)d_out;

  k_prep_g <<<dim3(16, 16), dim3(256), 0, stream>>>(Wq, Wk, B16);
  k_prep_wv<<<dim3(8, 8),   dim3(256), 0, stream>>>(Wv, B16);
  k_cast   <<<dim3(4096),   dim3(256), 0, stream>>>(tokens, T16);
  k_gemm   <<<dim3(128, 8), dim3(256), 0, stream>>>(T16, B16, QG, VT);
  k_pass1p <<<dim3(2048),   dim3(256), 0, stream>>>(T16, QG, Pp, Mp, Dp);
  k_scm    <<<dim3(64),     dim3(256), 0, stream>>>(Mp, Dp, SC16);
  k_pass2p <<<dim3(512),    dim3(256), 0, stream>>>(Pp, VT, SC16, out);
}

// Round 10
// 168.152 us; speedup vs baseline: 2.1226x; 1.0507x over previous
//
#include <hip/hip_runtime.h>

typedef _Float16 f16;
typedef _Float16 f16x8 __attribute__((ext_vector_type(8)));
typedef _Float16 f16x4 __attribute__((ext_vector_type(4)));
typedef float   f32x4 __attribute__((ext_vector_type(4)));

#define LOG2E 1.44269504088896340736f

__device__ __forceinline__ f32x4 mfma_f16(f16x8 a, f16x8 b, f32x4 c){
  return __builtin_amdgcn_mfma_f32_16x16x32_f16(a, b, c, 0, 0, 0);
}
__device__ __forceinline__ float fexp2(float x){ return __builtin_amdgcn_exp2f(x); }

// global -> LDS direct DMA, 16B per lane. lds must be wave-uniform base;
// HW writes base + lane*16. Source address is per-lane (pre-swizzled).
__device__ __forceinline__ void gld16(void* lds, const void* g){
  __builtin_amdgcn_global_load_lds(
      (const __attribute__((address_space(1))) unsigned int*)g,
      (__attribute__((address_space(3))) unsigned int*)lds,
      16, 0, 0);
}

// BK=32 swizzle (64B rows): pos holds k-word (pos ^ ((row>>1)&3));
//   staging XOR (l&3)^((l>>3)&3); 2-way bank aliasing = free.
// BK=64 swizzle (128B rows): pos holds k-word (pos ^ (row&7));
//   staging XOR (l&7)^(l>>3); 2-way aliasing = free (r5/r6: 0 conflicts).

// ---------------------------------------------------------------------------
// k_prep_g: B16[n][e] = sum_x Wk[n][x]*Wq[e][x]  (= (Wq Wk^T)^T), n<512.
// ---------------------------------------------------------------------------
__global__ __launch_bounds__(256) void k_prep_g(const float* __restrict__ Wq,
                                                const float* __restrict__ Wk,
                                                f16* __restrict__ B16){
  __shared__ float ak[32][36];
  __shared__ float aq[32][36];
  const int n0 = blockIdx.y * 32, e0 = blockIdx.x * 32;
  const int u = threadIdx.x;
  const int ty = u >> 4, tx = u & 15;
  float acc[2][2] = {};
  for (int x0 = 0; x0 < 512; x0 += 32){
    __syncthreads();
    {
      int r = u >> 3, c4 = (u & 7) * 4;
      *(float4*)&ak[r][c4] = *(const float4*)&Wk[(n0 + r) * 512 + x0 + c4];
      *(float4*)&aq[r][c4] = *(const float4*)&Wq[(e0 + r) * 512 + x0 + c4];
    }
    __syncthreads();
#pragma unroll 8
    for (int x = 0; x < 32; ++x){
      float k0 = ak[ty * 2 + 0][x], k1 = ak[ty * 2 + 1][x];
      float q0 = aq[tx * 2 + 0][x], q1 = aq[tx * 2 + 1][x];
      acc[0][0] += k0 * q0; acc[0][1] += k0 * q1;
      acc[1][0] += k1 * q0; acc[1][1] += k1 * q1;
    }
  }
#pragma unroll
  for (int i = 0; i < 2; ++i)
#pragma unroll
    for (int j = 0; j < 2; ++j)
      B16[(size_t)(n0 + ty * 2 + i) * 512 + e0 + tx * 2 + j] = (f16)acc[i][j];
}

// ---------------------------------------------------------------------------
// k_prep_wv: B16[512+d][e] = Wv[e][d]  (transpose + fp16 cast)
// ---------------------------------------------------------------------------
__global__ __launch_bounds__(256) void k_prep_wv(const float* __restrict__ Wv,
                                                 f16* __restrict__ B16){
  __shared__ float t[64][72];
  const int e0 = blockIdx.x * 64, h0 = blockIdx.y * 64;
  const int u = threadIdx.x;
#pragma unroll
  for (int k = 0; k < 4; ++k){
    int idx = u + k * 256; int r = idx >> 4, c4 = (idx & 15) * 4;
    *(float4*)&t[r][c4] = *(const float4*)&Wv[(e0 + r) * 512 + h0 + c4];
  }
  __syncthreads();
#pragma unroll
  for (int k = 0; k < 4; ++k){
    int idx = u + k * 256; int j = idx >> 4, i4 = (idx & 15) * 4;
#pragma unroll
    for (int c = 0; c < 4; ++c)
      B16[(size_t)(512 + h0 + j) * 512 + e0 + i4 + c] = (f16)t[i4 + c][j];
  }
}

// ---------------------------------------------------------------------------
// k_cast: tokens fp32 -> fp16, 8/thread.
// ---------------------------------------------------------------------------
__global__ __launch_bounds__(256) void k_cast(const float* __restrict__ tok,
                                              f16* __restrict__ T16){
  int i = blockIdx.x * 256 + threadIdx.x;
  const float4* p = (const float4*)tok + (size_t)i * 2;
  float4 a = p[0], b = p[1];
  f16x8 h;
  h[0] = (f16)a.x; h[1] = (f16)a.y; h[2] = (f16)a.z; h[3] = (f16)a.w;
  h[4] = (f16)b.x; h[5] = (f16)b.y; h[6] = (f16)b.z; h[7] = (f16)b.w;
  *((f16x8*)T16 + i) = h;
}

// ---------------------------------------------------------------------------
// k_gemm: C[t][n] = sum_e T16[t][e]*B16[n][e]; n<512 -> QG[t][n],
// n>=512 -> VT[b][d][s]. 128x128 tile, BK=32, dbuf, conflict-free swizzle.
// ---------------------------------------------------------------------------
__global__ __launch_bounds__(256, 4) void k_gemm(const f16* __restrict__ T16,
                                                 const f16* __restrict__ B16,
                                                 f16* __restrict__ QG,
                                                 f16* __restrict__ VT){
  __shared__ __align__(16) f16 Abuf[2][128 * 32];  // 2*8KB
  __shared__ __align__(16) f16 Bbuf[2][128 * 32];  // 2*8KB
  const int tb = blockIdx.x, nb = blockIdx.y;
  const int u = threadIdx.x;
  const int w = u >> 6, l = u & 63, lr = l & 15, lq = l >> 4;
  const int sxor = (l & 3) ^ ((l >> 3) & 3), hi4 = l >> 2;
  const int wm = (w & 1) * 64, wn = (w >> 1) * 64;
  f32x4 acc[4][4] = {};
  auto stage = [&](int c, int buf){
    const f16* sa = T16 + (size_t)tb * 128 * 512 + c * 32;
    const f16* sb = B16 + (size_t)nb * 128 * 512 + c * 32;
#pragma unroll
    for (int k = 0; k < 2; ++k){
      int i = w * 2 + k;
      int row = i * 16 + hi4;
      gld16((char*)&Abuf[buf][0] + i * 1024, sa + (size_t)row * 512 + sxor * 8);
      gld16((char*)&Bbuf[buf][0] + i * 1024, sb + (size_t)row * 512 + sxor * 8);
    }
  };
  stage(0, 0);
  for (int c = 0; c < 16; ++c){
    __syncthreads();
    if (c < 15) stage(c + 1, (c + 1) & 1);
    const f16* A = &Abuf[c & 1][0];
    const f16* B = &Bbuf[c & 1][0];
    f16x8 af[4], bf[4];
#pragma unroll
    for (int mt = 0; mt < 4; ++mt){
      int row = wm + mt * 16 + lr;
      af[mt] = *(const f16x8*)((const char*)A + row * 64 + (((lq ^ ((row >> 1) & 3))) << 4));
    }
#pragma unroll
    for (int nt = 0; nt < 4; ++nt){
      int row = wn + nt * 16 + lr;
      bf[nt] = *(const f16x8*)((const char*)B + row * 64 + (((lq ^ ((row >> 1) & 3))) << 4));
    }
#pragma unroll
    for (int mt = 0; mt < 4; ++mt)
#pragma unroll
      for (int nt = 0; nt < 4; ++nt)
        acc[mt][nt] = mfma_f16(af[mt], bf[nt], acc[mt][nt]);
  }
  if (nb < 4){
#pragma unroll
    for (int mt = 0; mt < 4; ++mt)
#pragma unroll
      for (int nt = 0; nt < 4; ++nt){
        int n = nb * 128 + wn + nt * 16 + lr;
        int r0 = tb * 128 + wm + mt * 16 + lq * 4;
#pragma unroll
        for (int j = 0; j < 4; ++j)
          QG[(size_t)(r0 + j) * 512 + n] = (f16)acc[mt][nt][j];
      }
  } else {
#pragma unroll
    for (int mt = 0; mt < 4; ++mt)
#pragma unroll
      for (int nt = 0; nt < 4; ++nt){
        int h = (nb - 4) * 128 + wn + nt * 16 + lr;
        int r0 = tb * 128 + wm + mt * 16 + lq * 4;
        int bq = r0 >> 11, s = r0 & 2047;
        f16x4 hv;
#pragma unroll
        for (int j = 0; j < 4; ++j) hv[j] = (f16)acc[mt][nt][j];
        *(f16x4*)&VT[(size_t)(bq * 512 + h) * 2048 + s] = hv;
      }
  }
}

// ---------------------------------------------------------------------------
// k_pass1p: S-GEMM 128s x 128t, BK=32, 2-buffer dbuf + plain __syncthreads
// (the validated k_gemm structure) + conflict-free swizzle. 34KB LDS ->
// 4 blocks/CU. Epilogue: tile-local col stats -> P' = exp2(x-M), D = col-sum.
// ---------------------------------------------------------------------------
__global__ __launch_bounds__(256, 4) void k_pass1p(const f16* __restrict__ T16,
                                                   const f16* __restrict__ QG,
                                                   f16* __restrict__ Pp,
                                                   float* __restrict__ Mp,
                                                   float* __restrict__ Dp){
  const int gid = blockIdx.x;
  const int b = gid & 7;
  const int sb = (gid >> 3) & 15;
  const int tb = gid >> 7;
  const int u = threadIdx.x;
  const int w = u >> 6, l = u & 63, lr = l & 15, lq = l >> 4;
  const int sxor = (l & 3) ^ ((l >> 3) & 3), hi4 = l >> 2;
  const int wm = (w & 1) * 64, wn = (w >> 1) * 64;  // s, t within tile

  __shared__ __align__(16) f16 Abuf[2][128 * 32];  // T16 s-rows, 2*8KB
  __shared__ __align__(16) f16 Bbuf[2][128 * 32];  // QG  t-rows, 2*8KB
  __shared__ float redM[2][128];
  __shared__ float redD[2][128];

  f32x4 acc[4][4] = {};
  const f16* sa0 = T16 + ((size_t)(b * 2048 + sb * 128) * 512);
  const f16* sb0 = QG + ((size_t)(b * 2048 + tb * 128) * 512);
  auto stage = [&](int c, int buf){
    const f16* sa = sa0 + c * 32;
    const f16* sb_ = sb0 + c * 32;
#pragma unroll
    for (int k = 0; k < 2; ++k){
      int i = w * 2 + k;
      int row = i * 16 + hi4;
      gld16((char*)&Abuf[buf][0] + i * 1024, sa  + (size_t)row * 512 + sxor * 8);
      gld16((char*)&Bbuf[buf][0] + i * 1024, sb_ + (size_t)row * 512 + sxor * 8);
    }
  };
  stage(0, 0);
  for (int c = 0; c < 16; ++c){
    __syncthreads();
    if (c < 15) stage(c + 1, (c + 1) & 1);
    const f16* A = &Abuf[c & 1][0];
    const f16* B = &Bbuf[c & 1][0];
    f16x8 af[4], bf[4];
#pragma unroll
    for (int mt = 0; mt < 4; ++mt){
      int row = wm + mt * 16 + lr;
      af[mt] = *(const f16x8*)((const char*)A + row * 64 + (((lq ^ ((row >> 1) & 3))) << 4));
    }
#pragma unroll
    for (int nt = 0; nt < 4; ++nt){
      int row = wn + nt * 16 + lr;
      bf[nt] = *(const f16x8*)((const char*)B + row * 64 + (((lq ^ ((row >> 1) & 3))) << 4));
    }
#pragma unroll
    for (int mt = 0; mt < 4; ++mt)
#pragma unroll
      for (int nt = 0; nt < 4; ++nt)
        acc[mt][nt] = mfma_f16(af[mt], bf[nt], acc[mt][nt]);
  }
  // ---- epilogue: x = S*log2e; tile-local col max over the block's 128 t ----
#pragma unroll
  for (int mt = 0; mt < 4; ++mt)
#pragma unroll
    for (int nt = 0; nt < 4; ++nt)
#pragma unroll
      for (int j = 0; j < 4; ++j)
        acc[mt][nt][j] *= LOG2E;
#pragma unroll
  for (int mt = 0; mt < 4; ++mt)
#pragma unroll
    for (int j = 0; j < 4; ++j){
      float m2 = fmaxf(fmaxf(acc[mt][0][j], acc[mt][1][j]),
                       fmaxf(acc[mt][2][j], acc[mt][3][j]));
#pragma unroll
      for (int off = 1; off <= 8; off <<= 1)
        m2 = fmaxf(m2, __shfl_xor(m2, off, 64));
      if (lr == 0) redM[w >> 1][wm + mt * 16 + lq * 4 + j] = m2;
    }
  __syncthreads();
  float M[4][4];
#pragma unroll
  for (int mt = 0; mt < 4; ++mt)
#pragma unroll
    for (int j = 0; j < 4; ++j){
      int idx = wm + mt * 16 + lq * 4 + j;
      M[mt][j] = fmaxf(redM[0][idx], redM[1][idx]);
    }
  // ---- P' = exp2(x - M), store fp16, col sums ----
#pragma unroll
  for (int mt = 0; mt < 4; ++mt)
#pragma unroll
    for (int nt = 0; nt < 4; ++nt){
      int t = tb * 128 + wn + nt * 16 + lr;
      f16x4 h4;
#pragma unroll
      for (int j = 0; j < 4; ++j){
        float p = fexp2(acc[mt][nt][j] - M[mt][j]);
        acc[mt][nt][j] = p;
        h4[j] = (f16)p;
      }
      *(f16x4*)&Pp[(size_t)(b * 2048 + t) * 2048 + sb * 128 + wm + mt * 16 + lq * 4] = h4;
    }
#pragma unroll
  for (int mt = 0; mt < 4; ++mt)
#pragma unroll
    for (int j = 0; j < 4; ++j){
      float sd = acc[mt][0][j] + acc[mt][1][j] + acc[mt][2][j] + acc[mt][3][j];
#pragma unroll
      for (int off = 1; off <= 8; off <<= 1)
        sd += __shfl_xor(sd, off, 64);
      if (lr == 0) redD[w >> 1][wm + mt * 16 + lq * 4 + j] = sd;
    }
  __syncthreads();
  if (u < 128){
    int sg = b * 2048 + sb * 128 + u;
    Mp[tb * 16384 + sg] = fmaxf(redM[0][u], redM[1][u]);
    Dp[tb * 16384 + sg] = redD[0][u] + redD[1][u];
  }
}

// ---------------------------------------------------------------------------
// k_scm: merge the 16 per-tile partials -> SC16[ti][s] = exp2(M-m)/denom (f16).
// ---------------------------------------------------------------------------
__global__ __launch_bounds__(256) void k_scm(const float* __restrict__ Mp,
                                             const float* __restrict__ Dp,
                                             f16* __restrict__ SC16){
  int i = blockIdx.x * 256 + threadIdx.x;  // (b,s) flat, 16384
  float mv[16];
  float m = -1e30f;
#pragma unroll
  for (int ti = 0; ti < 16; ++ti){
    mv[ti] = Mp[ti * 16384 + i];
    m = fmaxf(m, mv[ti]);
  }
  float d = 0.f;
#pragma unroll
  for (int ti = 0; ti < 16; ++ti)
    d += Dp[ti * 16384 + i] * fexp2(mv[ti] - m);
  float rd = 1.0f / d;
#pragma unroll
  for (int ti = 0; ti < 16; ++ti)
    SC16[ti * 16384 + i] = (f16)(fexp2(mv[ti] - m) * rd);
}

// ---------------------------------------------------------------------------
// k_pass2p: pure GEMM over K=s=2048. Block = (b, tb 16, hb 4), grid 512
// (grid-limited to 2 blocks/CU -> spend LDS on BK=64: 32 K-steps, 32 MFMA
// per wave per step, 68KB LDS). Swizzle: 128B rows, pos ^= (row&7)
// (r5/r6-validated, 0 conflicts). Scale in registers: s = c*64+es*32+lq*8+e.
// ---------------------------------------------------------------------------
__global__ __launch_bounds__(256, 2) void k_pass2p(const f16* __restrict__ Pp,
                                                   const f16* __restrict__ VT,
                                                   const f16* __restrict__ SC16,
                                                   float* __restrict__ out){
  const int gid = blockIdx.x;
  const int b = gid & 7;
  const int tb = (gid >> 3) & 15;
  const int hb = gid >> 7;
  const int u = threadIdx.x;
  const int w = u >> 6, l = u & 63, lr = l & 15, lq = l >> 4;
  const int sx8 = (l & 7) ^ (l >> 3), hi8 = l >> 3;
  const int wm = (w & 1) * 64, wn = (w >> 1) * 64;  // h, t within tile

  __shared__ __align__(16) f16 Abuf[2][128 * 64];  // V^T h-rows, 2*16KB
  __shared__ __align__(16) f16 Bbuf[2][128 * 64];  // P' t-rows, 2*16KB
  __shared__ __align__(16) f16 scl[2048];          // 4KB, sc row for this tb

  { // stage scale row (one f16x8 per thread)
    f16x8 v = *(const f16x8*)&SC16[(size_t)tb * 16384 + b * 2048 + u * 8];
    *(f16x8*)&scl[u * 8] = v;
  }
  f32x4 acc[4][4] = {};
  auto stage = [&](int c, int buf){
    const f16* sa = VT + ((size_t)(b * 512 + hb * 128) * 2048 + c * 64);
    const f16* sb_ = Pp + ((size_t)(b * 2048 + tb * 128) * 2048 + c * 64);
#pragma unroll
    for (int k = 0; k < 4; ++k){
      int i = w * 4 + k;            // 0..15
      int row = i * 8 + hi8;        // 0..127
      gld16((char*)&Abuf[buf][0] + i * 1024, sa  + (size_t)row * 2048 + sx8 * 8);
      gld16((char*)&Bbuf[buf][0] + i * 1024, sb_ + (size_t)row * 2048 + sx8 * 8);
    }
  };
  stage(0, 0);
  for (int c = 0; c < 32; ++c){
    __syncthreads();   // drains gld16 (vmcnt) and scl ds_write (lgkmcnt) on c=0
    if (c < 31) stage(c + 1, (c + 1) & 1);
    const f16* A = &Abuf[c & 1][0];
    const f16* B = &Bbuf[c & 1][0];
#pragma unroll
    for (int es = 0; es < 2; ++es){
      f16x8 sclv = *(const f16x8*)&scl[c * 64 + es * 32 + lq * 8]; // broadcast
      f16x8 af[4], bf[4];
#pragma unroll
      for (int mt = 0; mt < 4; ++mt){
        int row = wm + mt * 16 + lr;
        af[mt] = *(const f16x8*)((const char*)A + row * 128 + (((es * 4 + lq) ^ (row & 7)) << 4));
      }
#pragma unroll
      for (int nt = 0; nt < 4; ++nt){
        int row = wn + nt * 16 + lr;
        f16x8 p = *(const f16x8*)((const char*)B + row * 128 + (((es * 4 + lq) ^ (row & 7)) << 4));
        bf[nt] = p * sclv;
      }
#pragma unroll
      for (int mt = 0; mt < 4; ++mt)
#pragma unroll
        for (int nt = 0; nt < 4; ++nt)
          acc[mt][nt] = mfma_f16(af[mt], bf[nt], acc[mt][nt]);
    }
  }
  // epilogue: h = hb*128 + wm + mt*16 + lq*4 (+j), t = tb*128 + wn + nt*16 + lr
#pragma unroll
  for (int mt = 0; mt < 4; ++mt)
#pragma unroll
    for (int nt = 0; nt < 4; ++nt){
      int t = tb * 128 + wn + nt * 16 + lr;
      int h = hb * 128 + wm + mt * 16 + lq * 4;
      float4 v;
      v.x = acc[mt][nt][0]; v.y = acc[mt][nt][1];
      v.z = acc[mt][nt][2]; v.w = acc[mt][nt][3];
      *(float4*)&out[(size_t)(b * 2048 + t) * 512 + h] = v;
    }
}

// ---------------------------------------------------------------------------
extern "C" void kernel_launch(void* const* d_in, const int* in_sizes, int n_in,
                              void* d_out, int out_size, void* d_ws, size_t ws_size,
                              hipStream_t stream){
  (void)in_sizes; (void)n_in; (void)out_size; (void)ws_size;
  const float* tokens = (const float*)d_in[0];
  const float* Wq = (const float*)d_in[1];
  const float* Wk = (const float*)d_in[2];
  const float* Wv = (const float*)d_in[3];
  char* ws = (char*)d_ws;
  f16*    T16 = (f16*)(ws);                        // [0, 16M)
  f16*    QG  = (f16*)(ws + (16u << 20));          // [16M, 32M)
  f16*    VT  = (f16*)(ws + (32u << 20));          // [32M, 48M)
  f16*    B16 = (f16*)(ws + (48u << 20));          // [48M, 49M)
  f16*    SC16= (f16*)(ws + (50u << 20));          // [50M, 50.5M)
  float*  Mp  = (float*)(ws + (51u << 20));        // [51M, 52M)
  float*  Dp  = (float*)(ws + (52u << 20));        // [52M, 53M)
  f16*    Pp  = (f16*)(ws + (54u << 20));          // [54M, 118M)
  float* out = (float*)d_out;

  k_prep_g <<<dim3(16, 16), dim3(256), 0, stream>>>(Wq, Wk, B16);
  k_prep_wv<<<dim3(8, 8),   dim3(256), 0, stream>>>(Wv, B16);
  k_cast   <<<dim3(4096),   dim3(256), 0, stream>>>(tokens, T16);
  k_gemm   <<<dim3(128, 8), dim3(256), 0, stream>>>(T16, B16, QG, VT);
  k_pass1p <<<dim3(2048),   dim3(256), 0, stream>>>(T16, QG, Pp, Mp, Dp);
  k_scm    <<<dim3(64),     dim3(256), 0, stream>>>(Mp, Dp, SC16);
  k_pass2p <<<dim3(512),    dim3(256), 0, stream>>>(Pp, VT, SC16, out);
}